// Round 1
// baseline (439.659 us; speedup 1.0000x reference)
//
#include <hip/hip_runtime.h>
#include <hip/hip_cooperative_groups.h>
#include <cfloat>

namespace cg = cooperative_groups;

#define BB 32
#define AA 8400
#define GG 40
#define NC 80
#define NO 85
#define CAP 2048    // >= geometric bound ~27 anchors/gt * 40 gts = 1080
#define CAPW 13312  // >= 1280 gts * dk_max 10 = 12800
#define POISON 0xAAAAAAAAu
#define K4GRID 104  // kept for exact phase-4 partial-sum grouping

typedef unsigned long long ull;
#define U64MAX 0xFFFFFFFFFFFFFFFFull

// ---------- deterministic helpers: explicit _rn ops (no FMA contraction) so every
// call site produces bitwise-identical values ----------

__device__ inline bool dev_in(float gx, float gy, float xc, float yc, float r)
{
    float dl = __fsub_rn(xc, __fsub_rn(gx, r));
    float dr = __fsub_rn(__fadd_rn(gx, r), xc);
    float dt = __fsub_rn(yc, __fsub_rn(gy, r));
    float db = __fsub_rn(__fadd_rn(gy, r), yc);
    return fminf(fminf(dl, dr), fminf(dt, db)) > 0.0f;
}

__device__ inline float2 cost_iou(float gx, float gy, float gw, float gh,
                                  float px, float py, float pw, float ph,
                                  float xc, float yc, float r,
                                  float ct, float fg)
{
    bool in = dev_in(gx, gy, xc, yc, r);
    float gw2 = __fmul_rn(gw, 0.5f), gh2 = __fmul_rn(gh, 0.5f);
    float pw2 = __fmul_rn(pw, 0.5f), ph2 = __fmul_rn(ph, 0.5f);
    float tlx = fmaxf(__fsub_rn(gx, gw2), __fsub_rn(px, pw2));
    float tly = fmaxf(__fsub_rn(gy, gh2), __fsub_rn(py, ph2));
    float brx = fminf(__fadd_rn(gx, gw2), __fadd_rn(px, pw2));
    float bry = fminf(__fadd_rn(gy, gh2), __fadd_rn(py, ph2));
    float en = (tlx < brx && tly < bry) ? 1.0f : 0.0f;
    float ai = __fmul_rn(__fmul_rn(__fsub_rn(brx, tlx), __fsub_rn(bry, tly)), en);
    float ag = __fmul_rn(gw, gh);
    float ap = __fmul_rn(pw, ph);
    float iou = ai / __fsub_rn(__fadd_rn(ag, ap), ai);
    iou = (fg != 0.0f) ? iou : 0.0f;
    float icost = -__logf(__fadd_rn(iou, 1e-8f));
    float cost = __fadd_rn(__fadd_rn(ct, __fmul_rn(3.0f, icost)), in ? 0.0f : 1000000.0f);
    cost = (fg != 0.0f) ? cost : 1000000000.0f;
    return make_float2(cost, iou);
}

__device__ inline float softplus_bce(float x)
{
    return fmaxf(x, 0.0f) + __logf(1.0f + __expf(-fabsf(x)));
}

__device__ inline float wave_sum(float v)
{
#pragma unroll
    for (int o = 32; o > 0; o >>= 1) v += __shfl_down(v, o, 64);
    return v;
}

__device__ inline ull wave_min_u64(ull v)
{
#pragma unroll
    for (int o = 1; o < 64; o <<= 1) {
        ull w = (ull)__shfl_xor((long long)v, o, 64);
        v = w < v ? w : v;
    }
    return v;
}

__device__ inline float wave_max_f(float v)
{
#pragma unroll
    for (int o = 1; o < 64; o <<= 1) v = fmaxf(v, __shfl_xor(v, o, 64));
    return v;
}

// ctrl layout (ints): [0..7]=acc(float), [8..39]=cnt[32], [40]=wlcnt, [41]=fin

// =====================================================================
// FUSED cooperative kernel: 4 phases, 3 grid syncs, math identical to
// the 4-kernel pipeline (k1a / k1b / k2 / k4).
// =====================================================================
__global__ __launch_bounds__(256, 3) void fused(
    const float* __restrict__ outputs, const float* __restrict__ origin,
    const float* __restrict__ labels,
    const float* __restrict__ xs_, const float* __restrict__ ys_, const float* __restrict__ st_,
    int* __restrict__ ctrl, int* __restrict__ matchcnt, int* __restrict__ alist,
    float4* __restrict__ blist, float4* __restrict__ glist,
    float2* __restrict__ misc, float* __restrict__ clsterm,
    int2* __restrict__ wl, float* __restrict__ out)
{
    cg::grid_group grid = cg::this_grid();

    __shared__ float  s_rows[64 * NO];      // 21.8 KB (phase 2; aliased in 1 & 4)
    __shared__ float  s_lgt[GG * 5];
    __shared__ int    s_arow[64];
    __shared__ float2 s_red2[4][64];
    __shared__ int    s_cnt[2];             // lcnt, sbase

    int tid = threadIdx.x;
    int w = tid >> 6, ln = tid & 63;
    int* cnt = ctrl + 8;
    int* wlcnt = ctrl + 40;
    int* fin   = ctrl + 41;
    float* acc = (float*)ctrl;
    int nblk = gridDim.x;

    // ---------------- phase 1: ctrl init + matchcnt zero + fg compaction ----------
    if (blockIdx.x == 0 && tid < 48) atomicCAS((unsigned*)&ctrl[tid], POISON, 0u);
    for (int i = blockIdx.x * 256 + tid; i < BB * AA; i += nblk * 256) matchcnt[i] = 0;

    const int GX1 = (AA + 255) / 256;       // 33
    int* lloc = (int*)s_rows;               // alias: phase-1 scratch
    for (int vb = blockIdx.x; vb < GX1 * BB; vb += nblk) {
        int bx = vb % GX1, b = vb / GX1;
        if (tid == 0) { atomicCAS((unsigned*)&cnt[b], POISON, 0u); s_cnt[0] = 0; }
        for (int i = tid; i < GG * 5; i += 256) s_lgt[i] = labels[b * GG * 5 + i];
        __syncthreads();

        int a = bx * 256 + tid;
        bool fg = false;
        if (a < AA) {
            float stv = st_[a];
            float xc = __fmul_rn(__fadd_rn(xs_[a], 0.5f), stv);
            float yc = __fmul_rn(__fadd_rn(ys_[a], 0.5f), stv);
            float r  = __fmul_rn(1.5f, stv);
            for (int g = 0; g < GG && !fg; g++)
                fg = dev_in(s_lgt[g * 5 + 1], s_lgt[g * 5 + 2], xc, yc, r);
        }
        ull mk = __ballot(fg);
        int cw = __popcll(mk);
        int wbase = 0;
        if (ln == 0 && cw) wbase = atomicAdd(&s_cnt[0], cw);
        wbase = __shfl(wbase, 0, 64);
        if (fg) lloc[wbase + __popcll(mk & ((1ull << ln) - 1ull))] = a;
        __syncthreads();
        if (tid == 0) s_cnt[1] = atomicAdd(&cnt[b], s_cnt[0]);
        __syncthreads();
        int m = s_cnt[0], base = s_cnt[1];
        for (int j = tid; j < m; j += 256)
            if (base + j < CAP) alist[b * CAP + base + j] = lloc[j];
        __syncthreads();   // protect shared reuse next virtual block
    }

    grid.sync();

    // ---------------- phase 2: fg rows -> class terms / compacted lists ----------
    const int GX2 = CAP / 64;               // 32
    for (int vb = blockIdx.x; vb < GX2 * BB; vb += nblk) {
        int bx = vb % GX2, b = vb / GX2;
        int i0 = bx * 64;
        int n = __hip_atomic_load(&cnt[b], __ATOMIC_RELAXED, __HIP_MEMORY_SCOPE_AGENT);
        n = n > CAP ? CAP : n;
        if (i0 < n) {                       // block-uniform predicate
            for (int t = tid; t < GG * 5; t += 256) s_lgt[t] = labels[b * GG * 5 + t];
            for (int rr = 0; rr < 16; rr++) {
                int row = i0 + w * 16 + rr;
                if (row < n) {
                    int a = alist[b * CAP + row];
                    const float* src = outputs + ((size_t)b * AA + a) * NO;
                    int rl = w * 16 + rr;
                    s_rows[rl * NO + ln] = src[ln];
                    if (ln < NO - 64) s_rows[rl * NO + 64 + ln] = src[64 + ln];
                    if (ln == 0) s_arow[rl] = a;
                }
            }
            __syncthreads();

            int il = ln;
            int i = i0 + il;
            bool valid = i < n;
            const float* R = s_rows + il * NO;
            float obj = R[4];

            float s1 = 0.0f, s2 = 0.0f;
            if (valid) {
                int c0 = w * 20;
#pragma unroll 4
                for (int j = 0; j < 20; j++) {
                    float x = R[5 + c0 + j];
                    float m = __fmul_rn(x, obj);
                    float p = __fsqrt_rn(m);
                    s1 += __logf(__fsub_rn(1.0f, p));
                    s2 += softplus_bce(x);
                }
            }
            s_red2[w][il] = make_float2(s1, s2);
            __syncthreads();

            if (valid) {
                float s1t = s_red2[0][il].x + s_red2[1][il].x + s_red2[2][il].x + s_red2[3][il].x;
                float s2t = s_red2[0][il].y + s_red2[1][il].y + s_red2[2][il].y + s_red2[3][il].y;
                float nsl = -s1t;

                if (w == 0) {
                    int a = s_arow[il];
                    float stv = st_[a];
                    float xc = __fmul_rn(__fadd_rn(xs_[a], 0.5f), stv);
                    float yc = __fmul_rn(__fadd_rn(ys_[a], 0.5f), stv);
                    float r  = __fmul_rn(1.5f, stv);
                    blist[b * CAP + i] = make_float4(R[0], R[1], R[2], R[3]);
                    glist[b * CAP + i] = make_float4(xc, yc, r, stv);
                    misc[b * CAP + i]  = make_float2(s2t, obj);
                }
#pragma unroll
                for (int gi = 0; gi < 10; gi++) {
                    int g = w * 10 + gi;
                    int gc = (int)s_lgt[g * 5];
                    float m = __fmul_rn(R[5 + gc], obj);
                    float p = __fsqrt_rn(m);
                    float term = __fsub_rn(__fmul_rn(0.5f, __logf(m)), __logf(__fsub_rn(1.0f, p)));
                    clsterm[((size_t)b * GG + g) * CAP + i] = __fsub_rn(nsl, term);
                }
            }
        }
        __syncthreads();   // protect shared reuse next virtual block
    }

    grid.sync();

    // ---------------- phase 3: per-(b,g) SimOTA top-10 assignment -----------------
    for (int vb = blockIdx.x; vb < (BB * GG) / 4; vb += nblk) {
        int pair = vb * 4 + w;
        int b = pair / GG, g = pair - b * GG;

        const float* L = labels + (b * GG + g) * 5;
        float gx = L[1], gy = L[2], gw = L[3], gh = L[4];
        int n = __hip_atomic_load(&cnt[b], __ATOMIC_RELAXED, __HIP_MEMORY_SCOPE_AGENT);
        n = n > CAP ? CAP : n;

        const float*  ctp = clsterm + ((size_t)b * GG + g) * CAP;
        const float4* bp  = blist + b * CAP;
        const float4* gp  = glist + b * CAP;
        const int*    ap  = alist + b * CAP;

        ull t[10]; float tv[10];
#pragma unroll
        for (int k = 0; k < 10; k++) { t[k] = U64MAX; tv[k] = 0.0f; }

        for (int i = ln; i < n; i += 64) {
            float4 pb = bp[i];
            float4 gm = gp[i];
            float2 ci = cost_iou(gx, gy, gw, gh, pb.x, pb.y, pb.z, pb.w,
                                 gm.x, gm.y, gm.z, ctp[i], 1.0f);
            unsigned u = __float_as_uint(ci.x);
            u ^= (u & 0x80000000u) ? 0xFFFFFFFFu : 0x80000000u;
            ull key = ((ull)u << 32) | (unsigned)((ap[i] << 11) | i);
            if (key < t[9]) {
                int p = 0;
#pragma unroll
                for (int k = 0; k < 10; k++) p += (t[k] < key) ? 1 : 0;
#pragma unroll
                for (int k = 9; k >= 1; k--) t[k] = (k > p) ? t[k - 1] : t[k];
#pragma unroll
                for (int k = 0; k < 10; k++) if (k == p) t[k] = key;
            }
            float v = ci.y;
            if (v > tv[9]) {
                int p = 0;
#pragma unroll
                for (int k = 0; k < 10; k++) p += (tv[k] > v) ? 1 : 0;
#pragma unroll
                for (int k = 9; k >= 1; k--) tv[k] = (k > p) ? tv[k - 1] : tv[k];
#pragma unroll
                for (int k = 0; k < 10; k++) if (k == p) tv[k] = v;
            }
        }

        ull mykey = U64MAX;
#pragma unroll
        for (int r = 0; r < 10; r++) {
            ull mn = wave_min_u64(t[0]);
            if (ln == r) mykey = mn;
            bool own = (t[0] == mn);
#pragma unroll
            for (int k = 0; k < 9; k++) t[k] = own ? t[k + 1] : t[k];
            t[9] = own ? U64MAX : t[9];
        }
        float isum = 0.0f;
#pragma unroll
        for (int r = 0; r < 10; r++) {
            float mv = wave_max_f(tv[0]);
            isum += mv;
            ull bal = __ballot(tv[0] == mv);
            int first = (int)__ffsll((long long)bal) - 1;
            bool own = (ln == first);
#pragma unroll
            for (int k = 0; k < 9; k++) tv[k] = own ? tv[k + 1] : tv[k];
            tv[9] = own ? 0.0f : tv[9];
        }

        int dk = (int)isum;
        dk = dk < 1 ? 1 : (dk > 10 ? 10 : dk);
        if (ln < dk && mykey != U64MAX) {
            unsigned low = (unsigned)mykey;
            int a = (int)(low >> 11);
            int i2 = (int)(low & 2047);
            int idx = b * AA + a;
            if (atomicAdd(&matchcnt[idx], 1) == 0) {
                int wp = atomicAdd(wlcnt, 1);
                if (wp < CAPW) wl[wp] = make_int2(idx, (g << 16) | i2);
            }
        }
    }

    grid.sync();

    // ---------------- phase 4: worklist loss + all-anchor obj BCE + finalize ------
    float t_fg = 0.0f, t_iou = 0.0f, t_obj = 0.0f, t_cls = 0.0f, t_l1 = 0.0f;

    if (blockIdx.x < K4GRID) {               // keep exact original partial grouping
        int gid = blockIdx.x * 256 + tid;
        int nw = __hip_atomic_load(wlcnt, __ATOMIC_RELAXED, __HIP_MEMORY_SCOPE_AGENT);
        nw = nw > CAPW ? CAPW : nw;

        for (int i = gid; i < BB * AA; i += K4GRID * 256)
            t_obj += softplus_bce(outputs[(size_t)i * NO + 4]);

        if (gid < nw) {
            int2 e = wl[gid];
            int idx = e.x;
            int b = idx / AA;
            int a = idx - b * AA;
            int ci = e.y & 0xFFFF;
            int g1 = e.y >> 16;
            int mcnt = matchcnt[idx];

            float4 pb = blist[b * CAP + ci];
            float4 gm = glist[b * CAP + ci];
            float2 mo = misc[b * CAP + ci];
            const float* Lb = labels + b * GG * 5;

            int mg;
            if (mcnt == 1) {
                mg = g1;
            } else {
                mg = 0; float best = FLT_MAX;
                for (int g = 0; g < GG; g++) {
                    float ct = clsterm[((size_t)b * GG + g) * CAP + ci];
                    float2 r = cost_iou(Lb[g * 5 + 1], Lb[g * 5 + 2], Lb[g * 5 + 3], Lb[g * 5 + 4],
                                        pb.x, pb.y, pb.z, pb.w, gm.x, gm.y, gm.z, ct, 1.0f);
                    if (r.x < best) { best = r.x; mg = g; }
                }
            }
            t_fg = 1.0f;
            t_obj += -mo.y;
            float gx = Lb[mg * 5 + 1], gy = Lb[mg * 5 + 2], gw = Lb[mg * 5 + 3], gh = Lb[mg * 5 + 4];
            int mcls = (int)Lb[mg * 5];
            float ctm = clsterm[((size_t)b * GG + mg) * CAP + ci];
            float2 r = cost_iou(gx, gy, gw, gh, pb.x, pb.y, pb.z, pb.w, gm.x, gm.y, gm.z, ctm, 1.0f);
            float pred_iou = r.y;
            float tlx = fmaxf(pb.x - pb.z * 0.5f, gx - gw * 0.5f);
            float tly = fmaxf(pb.y - pb.w * 0.5f, gy - gh * 0.5f);
            float brx = fminf(pb.x + pb.z * 0.5f, gx + gw * 0.5f);
            float bry = fminf(pb.y + pb.w * 0.5f, gy + gh * 0.5f);
            float en = (tlx < brx && tly < bry) ? 1.0f : 0.0f;
            float ai = (brx - tlx) * (bry - tly) * en;
            float iou = ai / (pb.z * pb.w + gw * gh - ai + 1e-16f);
            t_iou = 1.0f - iou * iou;
            const float* op = origin + (size_t)idx * 4;
            float stv = st_[a], xsv = xs_[a], ysv = ys_[a];
            t_l1 = fabsf(op[0] - (gx / stv - xsv)) + fabsf(op[1] - (gy / stv - ysv))
                 + fabsf(op[2] - logf(gw / stv + 1e-8f)) + fabsf(op[3] - logf(gh / stv + 1e-8f));
            t_cls = mo.x - outputs[(size_t)idx * NO + 5 + mcls] * pred_iou;
        }
    }

    t_fg = wave_sum(t_fg); t_iou = wave_sum(t_iou); t_obj = wave_sum(t_obj);
    t_cls = wave_sum(t_cls); t_l1 = wave_sum(t_l1);
    float (*red)[4] = reinterpret_cast<float(*)[4]>(s_red2);   // 80 B alias
    if (ln == 0) { red[0][w] = t_fg; red[1][w] = t_iou; red[2][w] = t_obj; red[3][w] = t_cls; red[4][w] = t_l1; }
    __syncthreads();
    if (tid == 0) {
        atomicAdd(&acc[0], red[0][0] + red[0][1] + red[0][2] + red[0][3]);
        atomicAdd(&acc[1], red[1][0] + red[1][1] + red[1][2] + red[1][3]);
        atomicAdd(&acc[2], red[2][0] + red[2][1] + red[2][2] + red[2][3]);
        atomicAdd(&acc[3], red[3][0] + red[3][1] + red[3][2] + red[3][3]);
        atomicAdd(&acc[4], red[4][0] + red[4][1] + red[4][2] + red[4][3]);
        __threadfence();
        int tkt = atomicAdd(fin, 1);
        if (tkt == nblk - 1) {
            float a0 = atomicAdd(&acc[0], 0.0f);
            float a1 = atomicAdd(&acc[1], 0.0f);
            float a2 = atomicAdd(&acc[2], 0.0f);
            float a3 = atomicAdd(&acc[3], 0.0f);
            float a4 = atomicAdd(&acc[4], 0.0f);
            float nfg = fmaxf(a0, 1.0f);
            float li = 5.0f * a1 / nfg;
            float lo = a2 / nfg;
            float lc = a3 / nfg;
            float ll = a4 / nfg;
            out[0] = li + lo + lc + ll;
            out[1] = li;
            out[2] = lo;
            out[3] = lc;
            out[4] = ll;
            out[5] = nfg / (float)(BB * GG);
        }
    }
}

// =====================================================================
// Legacy 4-kernel path (fallback if cooperative launch is unavailable)
// =====================================================================

__global__ __launch_bounds__(256) void k1a_fg(
    const float* __restrict__ labels,
    const float* __restrict__ xs_, const float* __restrict__ ys_, const float* __restrict__ st_,
    int* __restrict__ ctrl, int* __restrict__ matchcnt, int* __restrict__ alist)
{
    __shared__ float lgt[GG * 5];
    __shared__ int   lloc[256];
    __shared__ int   lcnt, sbase;

    int b = blockIdx.y;
    int tid = threadIdx.x, ln = tid & 63;
    int* cnt = ctrl + 8;

    if (tid == 0) atomicCAS((unsigned*)&cnt[b], POISON, 0u);
    if (blockIdx.x == 0 && b == 0 && tid < 48) atomicCAS((unsigned*)&ctrl[tid], POISON, 0u);
    if (tid == 0) lcnt = 0;

    int nb  = gridDim.x * gridDim.y;
    int bid = b * gridDim.x + blockIdx.x;
    for (int i = bid * 256 + tid; i < BB * AA; i += nb * 256) matchcnt[i] = 0;

    for (int i = tid; i < GG * 5; i += 256) lgt[i] = labels[b * GG * 5 + i];
    __syncthreads();

    int a = blockIdx.x * 256 + tid;
    bool fg = false;
    if (a < AA) {
        float stv = st_[a];
        float xc = __fmul_rn(__fadd_rn(xs_[a], 0.5f), stv);
        float yc = __fmul_rn(__fadd_rn(ys_[a], 0.5f), stv);
        float r  = __fmul_rn(1.5f, stv);
        for (int g = 0; g < GG && !fg; g++)
            fg = dev_in(lgt[g * 5 + 1], lgt[g * 5 + 2], xc, yc, r);
    }
    ull mk = __ballot(fg);
    int cw = __popcll(mk);
    int wbase = 0;
    if (ln == 0 && cw) wbase = atomicAdd(&lcnt, cw);
    wbase = __shfl(wbase, 0, 64);
    if (fg) lloc[wbase + __popcll(mk & ((1ull << ln) - 1ull))] = a;
    __syncthreads();
    if (tid == 0) sbase = atomicAdd(&cnt[b], lcnt);
    __syncthreads();
    int m = lcnt, base = sbase;
    for (int j = tid; j < m; j += 256)
        if (base + j < CAP) alist[b * CAP + base + j] = lloc[j];
}

__global__ __launch_bounds__(256) void k1b_cls(
    const float* __restrict__ outputs, const float* __restrict__ labels,
    const float* __restrict__ xs_, const float* __restrict__ ys_, const float* __restrict__ st_,
    const int* __restrict__ ctrl, const int* __restrict__ alist,
    float4* __restrict__ blist, float4* __restrict__ glist,
    float2* __restrict__ misc, float* __restrict__ clsterm)
{
    int b = blockIdx.y;
    int i0 = blockIdx.x * 64;
    int n = ctrl[8 + b]; n = n > CAP ? CAP : n;
    if (i0 >= n) return;

    __shared__ float rows[64 * NO];
    __shared__ float lgt[GG * 5];
    __shared__ int   arow[64];
    __shared__ float2 red2[4][64];

    int tid = threadIdx.x;
    int w = tid >> 6, ln = tid & 63;
    for (int t = tid; t < GG * 5; t += 256) lgt[t] = labels[b * GG * 5 + t];

    for (int rr = 0; rr < 16; rr++) {
        int row = i0 + w * 16 + rr;
        if (row < n) {
            int a = alist[b * CAP + row];
            const float* src = outputs + ((size_t)b * AA + a) * NO;
            int rl = w * 16 + rr;
            rows[rl * NO + ln] = src[ln];
            if (ln < NO - 64) rows[rl * NO + 64 + ln] = src[64 + ln];
            if (ln == 0) arow[rl] = a;
        }
    }
    __syncthreads();

    int il = ln;
    int i = i0 + il;
    bool valid = i < n;
    const float* R = rows + il * NO;
    float obj = R[4];

    float s1 = 0.0f, s2 = 0.0f;
    if (valid) {
        int c0 = w * 20;
#pragma unroll 4
        for (int j = 0; j < 20; j++) {
            float x = R[5 + c0 + j];
            float m = __fmul_rn(x, obj);
            float p = __fsqrt_rn(m);
            s1 += __logf(__fsub_rn(1.0f, p));
            s2 += softplus_bce(x);
        }
    }
    red2[w][il] = make_float2(s1, s2);
    __syncthreads();

    if (!valid) return;
    float s1t = red2[0][il].x + red2[1][il].x + red2[2][il].x + red2[3][il].x;
    float s2t = red2[0][il].y + red2[1][il].y + red2[2][il].y + red2[3][il].y;
    float nsl = -s1t;

    if (w == 0) {
        int a = arow[il];
        float stv = st_[a];
        float xc = __fmul_rn(__fadd_rn(xs_[a], 0.5f), stv);
        float yc = __fmul_rn(__fadd_rn(ys_[a], 0.5f), stv);
        float r  = __fmul_rn(1.5f, stv);
        blist[b * CAP + i] = make_float4(R[0], R[1], R[2], R[3]);
        glist[b * CAP + i] = make_float4(xc, yc, r, stv);
        misc[b * CAP + i]  = make_float2(s2t, obj);
    }
#pragma unroll
    for (int gi = 0; gi < 10; gi++) {
        int g = w * 10 + gi;
        int gc = (int)lgt[g * 5];
        float m = __fmul_rn(R[5 + gc], obj);
        float p = __fsqrt_rn(m);
        float term = __fsub_rn(__fmul_rn(0.5f, __logf(m)), __logf(__fsub_rn(1.0f, p)));
        clsterm[((size_t)b * GG + g) * CAP + i] = __fsub_rn(nsl, term);
    }
}

__global__ __launch_bounds__(256) void k2_assign(
    const float* __restrict__ labels,
    int* __restrict__ ctrl,
    const int* __restrict__ alist,
    const float4* __restrict__ blist, const float4* __restrict__ glist,
    const float* __restrict__ clsterm,
    int* __restrict__ matchcnt, int2* __restrict__ wl)
{
    int w = threadIdx.x >> 6, ln = threadIdx.x & 63;
    int pair = blockIdx.x * 4 + w;
    int b = pair / GG, g = pair - b * GG;
    int* cnt   = ctrl + 8;
    int* wlcnt = ctrl + 40;

    const float* L = labels + (b * GG + g) * 5;
    float gx = L[1], gy = L[2], gw = L[3], gh = L[4];
    int n = cnt[b]; n = n > CAP ? CAP : n;

    const float*  ctp = clsterm + ((size_t)b * GG + g) * CAP;
    const float4* bp  = blist + b * CAP;
    const float4* gp  = glist + b * CAP;
    const int*    ap  = alist + b * CAP;

    ull t[10]; float tv[10];
#pragma unroll
    for (int k = 0; k < 10; k++) { t[k] = U64MAX; tv[k] = 0.0f; }

    for (int i = ln; i < n; i += 64) {
        float4 pb = bp[i];
        float4 gm = gp[i];
        float2 ci = cost_iou(gx, gy, gw, gh, pb.x, pb.y, pb.z, pb.w,
                             gm.x, gm.y, gm.z, ctp[i], 1.0f);
        unsigned u = __float_as_uint(ci.x);
        u ^= (u & 0x80000000u) ? 0xFFFFFFFFu : 0x80000000u;
        ull key = ((ull)u << 32) | (unsigned)((ap[i] << 11) | i);
        if (key < t[9]) {
            int p = 0;
#pragma unroll
            for (int k = 0; k < 10; k++) p += (t[k] < key) ? 1 : 0;
#pragma unroll
            for (int k = 9; k >= 1; k--) t[k] = (k > p) ? t[k - 1] : t[k];
#pragma unroll
            for (int k = 0; k < 10; k++) if (k == p) t[k] = key;
        }
        float v = ci.y;
        if (v > tv[9]) {
            int p = 0;
#pragma unroll
            for (int k = 0; k < 10; k++) p += (tv[k] > v) ? 1 : 0;
#pragma unroll
            for (int k = 9; k >= 1; k--) tv[k] = (k > p) ? tv[k - 1] : tv[k];
#pragma unroll
            for (int k = 0; k < 10; k++) if (k == p) tv[k] = v;
        }
    }

    ull mykey = U64MAX;
#pragma unroll
    for (int r = 0; r < 10; r++) {
        ull mn = wave_min_u64(t[0]);
        if (ln == r) mykey = mn;
        bool own = (t[0] == mn);
#pragma unroll
        for (int k = 0; k < 9; k++) t[k] = own ? t[k + 1] : t[k];
        t[9] = own ? U64MAX : t[9];
    }
    float isum = 0.0f;
#pragma unroll
    for (int r = 0; r < 10; r++) {
        float mv = wave_max_f(tv[0]);
        isum += mv;
        ull bal = __ballot(tv[0] == mv);
        int first = (int)__ffsll((long long)bal) - 1;
        bool own = (ln == first);
#pragma unroll
        for (int k = 0; k < 9; k++) tv[k] = own ? tv[k + 1] : tv[k];
        tv[9] = own ? 0.0f : tv[9];
    }

    int dk = (int)isum;
    dk = dk < 1 ? 1 : (dk > 10 ? 10 : dk);
    if (ln < dk && mykey != U64MAX) {
        unsigned low = (unsigned)mykey;
        int a = (int)(low >> 11);
        int i2 = (int)(low & 2047);
        int idx = b * AA + a;
        if (atomicAdd(&matchcnt[idx], 1) == 0) {
            int wp = atomicAdd(wlcnt, 1);
            if (wp < CAPW) wl[wp] = make_int2(idx, (g << 16) | i2);
        }
    }
}

__global__ __launch_bounds__(256) void k4_loss(
    const float* __restrict__ outputs, const float* __restrict__ origin,
    const float* __restrict__ labels,
    const float* __restrict__ xs_, const float* __restrict__ ys_, const float* __restrict__ st_,
    const float4* __restrict__ blist, const float4* __restrict__ glist,
    const float2* __restrict__ misc, const float* __restrict__ clsterm,
    const int* __restrict__ matchcnt,
    const int2* __restrict__ wl, int* __restrict__ ctrl,
    float* __restrict__ out)
{
    float* acc = (float*)ctrl;
    int* wlcnt = ctrl + 40;
    int* fin   = ctrl + 41;

    int tid = threadIdx.x;
    int gid = blockIdx.x * 256 + tid;
    int nw = *wlcnt; nw = nw > CAPW ? CAPW : nw;

    float t_fg = 0.0f, t_iou = 0.0f, t_obj = 0.0f, t_cls = 0.0f, t_l1 = 0.0f;

    for (int i = gid; i < BB * AA; i += K4GRID * 256)
        t_obj += softplus_bce(outputs[(size_t)i * NO + 4]);

    if (gid < nw) {
        int2 e = wl[gid];
        int idx = e.x;
        int b = idx / AA;
        int a = idx - b * AA;
        int ci = e.y & 0xFFFF;
        int g1 = e.y >> 16;
        int mcnt = matchcnt[idx];

        float4 pb = blist[b * CAP + ci];
        float4 gm = glist[b * CAP + ci];
        float2 mo = misc[b * CAP + ci];
        const float* Lb = labels + b * GG * 5;

        int mg;
        if (mcnt == 1) {
            mg = g1;
        } else {
            mg = 0; float best = FLT_MAX;
            for (int g = 0; g < GG; g++) {
                float ct = clsterm[((size_t)b * GG + g) * CAP + ci];
                float2 r = cost_iou(Lb[g * 5 + 1], Lb[g * 5 + 2], Lb[g * 5 + 3], Lb[g * 5 + 4],
                                    pb.x, pb.y, pb.z, pb.w, gm.x, gm.y, gm.z, ct, 1.0f);
                if (r.x < best) { best = r.x; mg = g; }
            }
        }
        t_fg = 1.0f;
        t_obj += -mo.y;
        float gx = Lb[mg * 5 + 1], gy = Lb[mg * 5 + 2], gw = Lb[mg * 5 + 3], gh = Lb[mg * 5 + 4];
        int mcls = (int)Lb[mg * 5];
        float ctm = clsterm[((size_t)b * GG + mg) * CAP + ci];
        float2 r = cost_iou(gx, gy, gw, gh, pb.x, pb.y, pb.z, pb.w, gm.x, gm.y, gm.z, ctm, 1.0f);
        float pred_iou = r.y;
        float tlx = fmaxf(pb.x - pb.z * 0.5f, gx - gw * 0.5f);
        float tly = fmaxf(pb.y - pb.w * 0.5f, gy - gh * 0.5f);
        float brx = fminf(pb.x + pb.z * 0.5f, gx + gw * 0.5f);
        float bry = fminf(pb.y + pb.w * 0.5f, gy + gh * 0.5f);
        float en = (tlx < brx && tly < bry) ? 1.0f : 0.0f;
        float ai = (brx - tlx) * (bry - tly) * en;
        float iou = ai / (pb.z * pb.w + gw * gh - ai + 1e-16f);
        t_iou = 1.0f - iou * iou;
        const float* op = origin + (size_t)idx * 4;
        float stv = st_[a], xsv = xs_[a], ysv = ys_[a];
        t_l1 = fabsf(op[0] - (gx / stv - xsv)) + fabsf(op[1] - (gy / stv - ysv))
             + fabsf(op[2] - logf(gw / stv + 1e-8f)) + fabsf(op[3] - logf(gh / stv + 1e-8f));
        t_cls = mo.x - outputs[(size_t)idx * NO + 5 + mcls] * pred_iou;
    }

    t_fg = wave_sum(t_fg); t_iou = wave_sum(t_iou); t_obj = wave_sum(t_obj);
    t_cls = wave_sum(t_cls); t_l1 = wave_sum(t_l1);
    __shared__ float red[5][4];
    int wv = threadIdx.x >> 6, ln = threadIdx.x & 63;
    if (ln == 0) { red[0][wv] = t_fg; red[1][wv] = t_iou; red[2][wv] = t_obj; red[3][wv] = t_cls; red[4][wv] = t_l1; }
    __syncthreads();
    if (threadIdx.x == 0) {
        atomicAdd(&acc[0], red[0][0] + red[0][1] + red[0][2] + red[0][3]);
        atomicAdd(&acc[1], red[1][0] + red[1][1] + red[1][2] + red[1][3]);
        atomicAdd(&acc[2], red[2][0] + red[2][1] + red[2][2] + red[2][3]);
        atomicAdd(&acc[3], red[3][0] + red[3][1] + red[3][2] + red[3][3]);
        atomicAdd(&acc[4], red[4][0] + red[4][1] + red[4][2] + red[4][3]);
        __threadfence();
        int tkt = atomicAdd(fin, 1);
        if (tkt == (int)gridDim.x - 1) {
            float a0 = atomicAdd(&acc[0], 0.0f);
            float a1 = atomicAdd(&acc[1], 0.0f);
            float a2 = atomicAdd(&acc[2], 0.0f);
            float a3 = atomicAdd(&acc[3], 0.0f);
            float a4 = atomicAdd(&acc[4], 0.0f);
            float nfg = fmaxf(a0, 1.0f);
            float li = 5.0f * a1 / nfg;
            float lo = a2 / nfg;
            float lc = a3 / nfg;
            float ll = a4 / nfg;
            out[0] = li + lo + lc + ll;
            out[1] = li;
            out[2] = lo;
            out[3] = lc;
            out[4] = ll;
            out[5] = nfg / (float)(BB * GG);
        }
    }
}

// ---------- workspace layout (16B-aligned blocks) ----------
static constexpr size_t NBA       = (size_t)BB * AA;
static constexpr size_t OFF_MC    = 256;
static constexpr size_t OFF_ALIST = OFF_MC + NBA * 4;
static constexpr size_t OFF_BL    = OFF_ALIST + (size_t)BB * CAP * 4;
static constexpr size_t OFF_GL    = OFF_BL + (size_t)BB * CAP * 16;
static constexpr size_t OFF_MISC  = OFF_GL + (size_t)BB * CAP * 16;
static constexpr size_t OFF_CT    = OFF_MISC + (size_t)BB * CAP * 8;
static constexpr size_t OFF_WL    = OFF_CT + (size_t)BB * GG * CAP * 4;

extern "C" void kernel_launch(void* const* d_in, const int* in_sizes, int n_in,
                              void* d_out, int out_size, void* d_ws, size_t ws_size,
                              hipStream_t stream)
{
    (void)in_sizes; (void)n_in; (void)out_size; (void)ws_size;
    const float* outputs = (const float*)d_in[0];
    const float* origin  = (const float*)d_in[1];
    const float* labels  = (const float*)d_in[2];
    const float* xs_     = (const float*)d_in[3];
    const float* ys_     = (const float*)d_in[4];
    const float* st_     = (const float*)d_in[5];
    float* out = (float*)d_out;
    char* ws = (char*)d_ws;

    int*    ctrl     = (int*)(ws);
    int*    matchcnt = (int*)(ws + OFF_MC);
    int*    alist    = (int*)(ws + OFF_ALIST);
    float4* blist    = (float4*)(ws + OFF_BL);
    float4* glist    = (float4*)(ws + OFF_GL);
    float2* misc     = (float2*)(ws + OFF_MISC);
    float*  clsterm  = (float*)(ws + OFF_CT);
    int2*   wl       = (int2*)(ws + OFF_WL);

    // co-residency-safe cooperative grid size (cached across calls)
    static int nblk = 0;
    if (nblk == 0) {
        int per_cu = 0;
        hipError_t oe = hipOccupancyMaxActiveBlocksPerMultiprocessor(&per_cu, fused, 256, 0);
        if (oe != hipSuccess || per_cu < 1) per_cu = 1;
        long n = (long)per_cu * 256;       // 256 CUs on MI355X
        if (n > 768) n = 768;              // phases need no more; keeps margin
        if (n < K4GRID) n = K4GRID;        // phase-4 mapping requires >= 104 blocks
        nblk = (int)n;
    }

    void* args[] = {
        (void*)&outputs, (void*)&origin, (void*)&labels,
        (void*)&xs_, (void*)&ys_, (void*)&st_,
        (void*)&ctrl, (void*)&matchcnt, (void*)&alist,
        (void*)&blist, (void*)&glist, (void*)&misc, (void*)&clsterm,
        (void*)&wl, (void*)&out
    };
    hipError_t err = hipLaunchCooperativeKernel(fused, dim3(nblk), dim3(256), args, 0, stream);

    if (err != hipSuccess) {
        // legacy 4-kernel fallback (identical math)
        dim3 grid1((AA + 255) / 256, BB);
        k1a_fg<<<grid1, 256, 0, stream>>>(labels, xs_, ys_, st_, ctrl, matchcnt, alist);

        dim3 grid1b(CAP / 64, BB);
        k1b_cls<<<grid1b, 256, 0, stream>>>(outputs, labels, xs_, ys_, st_, ctrl, alist,
                                            blist, glist, misc, clsterm);

        k2_assign<<<BB * GG / 4, 256, 0, stream>>>(labels, ctrl, alist, blist, glist, clsterm,
                                                   matchcnt, wl);

        k4_loss<<<K4GRID, 256, 0, stream>>>(outputs, origin, labels, xs_, ys_, st_,
                                            blist, glist, misc, clsterm, matchcnt, wl,
                                            ctrl, out);
    }
}

// Round 2
// 389.940 us; speedup vs baseline: 1.1275x; 1.1275x over previous
//
#include <hip/hip_runtime.h>
#include <cfloat>

#define BB 32
#define AA 8400
#define GG 40
#define NC 80
#define NO 85
#define CAP 2048    // >= geometric bound ~27 anchors/gt * 40 gts = 1080
#define CAPW 13312  // >= 1280 gts * dk_max 10 = 12800
#define POISON 0xAAAAAAAAu
#define K4GRID 104  // kept for exact phase-4 partial-sum grouping
#define NBLK 320    // fused grid: == phase-3 width; >= K4GRID; barrier stays cheap

typedef unsigned long long ull;
#define U64MAX 0xFFFFFFFFFFFFFFFFull

// ---------- deterministic helpers: explicit _rn ops (no FMA contraction) so every
// call site produces bitwise-identical values ----------

__device__ inline bool dev_in(float gx, float gy, float xc, float yc, float r)
{
    float dl = __fsub_rn(xc, __fsub_rn(gx, r));
    float dr = __fsub_rn(__fadd_rn(gx, r), xc);
    float dt = __fsub_rn(yc, __fsub_rn(gy, r));
    float db = __fsub_rn(__fadd_rn(gy, r), yc);
    return fminf(fminf(dl, dr), fminf(dt, db)) > 0.0f;
}

__device__ inline float2 cost_iou(float gx, float gy, float gw, float gh,
                                  float px, float py, float pw, float ph,
                                  float xc, float yc, float r,
                                  float ct, float fg)
{
    bool in = dev_in(gx, gy, xc, yc, r);
    float gw2 = __fmul_rn(gw, 0.5f), gh2 = __fmul_rn(gh, 0.5f);
    float pw2 = __fmul_rn(pw, 0.5f), ph2 = __fmul_rn(ph, 0.5f);
    float tlx = fmaxf(__fsub_rn(gx, gw2), __fsub_rn(px, pw2));
    float tly = fmaxf(__fsub_rn(gy, gh2), __fsub_rn(py, ph2));
    float brx = fminf(__fadd_rn(gx, gw2), __fadd_rn(px, pw2));
    float bry = fminf(__fadd_rn(gy, gh2), __fadd_rn(py, ph2));
    float en = (tlx < brx && tly < bry) ? 1.0f : 0.0f;
    float ai = __fmul_rn(__fmul_rn(__fsub_rn(brx, tlx), __fsub_rn(bry, tly)), en);
    float ag = __fmul_rn(gw, gh);
    float ap = __fmul_rn(pw, ph);
    float iou = ai / __fsub_rn(__fadd_rn(ag, ap), ai);
    iou = (fg != 0.0f) ? iou : 0.0f;
    float icost = -__logf(__fadd_rn(iou, 1e-8f));
    float cost = __fadd_rn(__fadd_rn(ct, __fmul_rn(3.0f, icost)), in ? 0.0f : 1000000.0f);
    cost = (fg != 0.0f) ? cost : 1000000000.0f;
    return make_float2(cost, iou);
}

__device__ inline float softplus_bce(float x)
{
    return fmaxf(x, 0.0f) + __logf(1.0f + __expf(-fabsf(x)));
}

__device__ inline float wave_sum(float v)
{
#pragma unroll
    for (int o = 32; o > 0; o >>= 1) v += __shfl_down(v, o, 64);
    return v;
}

__device__ inline ull wave_min_u64(ull v)
{
#pragma unroll
    for (int o = 1; o < 64; o <<= 1) {
        ull w = (ull)__shfl_xor((long long)v, o, 64);
        v = w < v ? w : v;
    }
    return v;
}

__device__ inline float wave_max_f(float v)
{
#pragma unroll
    for (int o = 1; o < 64; o <<= 1) v = fmaxf(v, __shfl_xor(v, o, 64));
    return v;
}

// ---------- lightweight grid barrier (replaces cg::grid.sync, which cost ~130us/sync)
// Monotonic arrive counter at ctrl[56]; target = phase_idx * nblk (no generation reset,
// poison-safe via per-block CAS before first use). Leader-only arrive+poll; RELAXED
// agent-scope atomic loads bypass L1/L2 (scope flag) so they observe the coherence
// point; periodic ACQUIRE poll as self-healing fallback; one acquire fence on exit.
__device__ inline void gbar(int* arr, int target)
{
    __syncthreads();
    if (threadIdx.x == 0) {
        __hip_atomic_fetch_add(arr, 1, __ATOMIC_RELEASE, __HIP_MEMORY_SCOPE_AGENT);
        int guard = 0;
        for (;;) {
            int v = __hip_atomic_load(arr, __ATOMIC_RELAXED, __HIP_MEMORY_SCOPE_AGENT);
            if (v >= target) break;
            __builtin_amdgcn_s_sleep(8);
            if ((++guard & 255) == 0) {
                v = __hip_atomic_load(arr, __ATOMIC_ACQUIRE, __HIP_MEMORY_SCOPE_AGENT);
                if (v >= target) break;
            }
            if (guard > (1 << 22)) break;   // ~0.4s safety valve: fail visibly, not hang
        }
        __builtin_amdgcn_fence(__ATOMIC_ACQUIRE, "agent");
    }
    __syncthreads();
}

// ctrl layout (ints): [0..7]=acc(float), [8..39]=cnt[32], [40]=wlcnt, [41]=fin, [56]=bar

// =====================================================================
// FUSED kernel: 4 phases, 3 custom grid barriers, math identical to
// the 4-kernel pipeline (k1a / k1b / k2 / k4).
// =====================================================================
__global__ __launch_bounds__(256, 3) void fused(
    const float* __restrict__ outputs, const float* __restrict__ origin,
    const float* __restrict__ labels,
    const float* __restrict__ xs_, const float* __restrict__ ys_, const float* __restrict__ st_,
    int* __restrict__ ctrl, int* __restrict__ matchcnt, int* __restrict__ alist,
    float4* __restrict__ blist, float4* __restrict__ glist,
    float2* __restrict__ misc, float* __restrict__ clsterm,
    int2* __restrict__ wl, float* __restrict__ out)
{
    __shared__ float  s_rows[64 * NO];      // 21.8 KB (phase 2; aliased in 1 & 4)
    __shared__ float  s_lgt[GG * 5];
    __shared__ int    s_arow[64];
    __shared__ float2 s_red2[4][64];
    __shared__ int    s_cnt[2];             // lcnt, sbase

    int tid = threadIdx.x;
    int w = tid >> 6, ln = tid & 63;
    int* cnt = ctrl + 8;
    int* wlcnt = ctrl + 40;
    int* fin   = ctrl + 41;
    int* bar   = ctrl + 56;
    float* acc = (float*)ctrl;
    int nblk = gridDim.x;

    // poison-safe barrier init: EVERY block CASes before its first arrive
    if (tid == 0) atomicCAS((unsigned*)bar, POISON, 0u);

    // ---------------- phase 1: ctrl init + matchcnt zero + fg compaction ----------
    if (blockIdx.x == 0 && tid < 48) atomicCAS((unsigned*)&ctrl[tid], POISON, 0u);
    for (int i = blockIdx.x * 256 + tid; i < BB * AA; i += nblk * 256) matchcnt[i] = 0;

    const int GX1 = (AA + 255) / 256;       // 33
    int* lloc = (int*)s_rows;               // alias: phase-1 scratch
    for (int vb = blockIdx.x; vb < GX1 * BB; vb += nblk) {
        int bx = vb % GX1, b = vb / GX1;
        if (tid == 0) { atomicCAS((unsigned*)&cnt[b], POISON, 0u); s_cnt[0] = 0; }
        for (int i = tid; i < GG * 5; i += 256) s_lgt[i] = labels[b * GG * 5 + i];
        __syncthreads();

        int a = bx * 256 + tid;
        bool fg = false;
        if (a < AA) {
            float stv = st_[a];
            float xc = __fmul_rn(__fadd_rn(xs_[a], 0.5f), stv);
            float yc = __fmul_rn(__fadd_rn(ys_[a], 0.5f), stv);
            float r  = __fmul_rn(1.5f, stv);
            for (int g = 0; g < GG && !fg; g++)
                fg = dev_in(s_lgt[g * 5 + 1], s_lgt[g * 5 + 2], xc, yc, r);
        }
        ull mk = __ballot(fg);
        int cw = __popcll(mk);
        int wbase = 0;
        if (ln == 0 && cw) wbase = atomicAdd(&s_cnt[0], cw);
        wbase = __shfl(wbase, 0, 64);
        if (fg) lloc[wbase + __popcll(mk & ((1ull << ln) - 1ull))] = a;
        __syncthreads();
        if (tid == 0) s_cnt[1] = atomicAdd(&cnt[b], s_cnt[0]);
        __syncthreads();
        int m = s_cnt[0], base = s_cnt[1];
        for (int j = tid; j < m; j += 256)
            if (base + j < CAP) alist[b * CAP + base + j] = lloc[j];
        __syncthreads();   // protect shared reuse next virtual block
    }

    gbar(bar, 1 * nblk);

    // ---------------- phase 2: fg rows -> class terms / compacted lists ----------
    const int GX2 = CAP / 64;               // 32
    for (int vb = blockIdx.x; vb < GX2 * BB; vb += nblk) {
        int bx = vb % GX2, b = vb / GX2;
        int i0 = bx * 64;
        int n = __hip_atomic_load(&cnt[b], __ATOMIC_RELAXED, __HIP_MEMORY_SCOPE_AGENT);
        n = n > CAP ? CAP : n;
        if (i0 < n) {                       // block-uniform predicate
            for (int t = tid; t < GG * 5; t += 256) s_lgt[t] = labels[b * GG * 5 + t];
            for (int rr = 0; rr < 16; rr++) {
                int row = i0 + w * 16 + rr;
                if (row < n) {
                    int a = alist[b * CAP + row];
                    const float* src = outputs + ((size_t)b * AA + a) * NO;
                    int rl = w * 16 + rr;
                    s_rows[rl * NO + ln] = src[ln];
                    if (ln < NO - 64) s_rows[rl * NO + 64 + ln] = src[64 + ln];
                    if (ln == 0) s_arow[rl] = a;
                }
            }
            __syncthreads();

            int il = ln;
            int i = i0 + il;
            bool valid = i < n;
            const float* R = s_rows + il * NO;
            float obj = R[4];

            float s1 = 0.0f, s2 = 0.0f;
            if (valid) {
                int c0 = w * 20;
#pragma unroll 4
                for (int j = 0; j < 20; j++) {
                    float x = R[5 + c0 + j];
                    float m = __fmul_rn(x, obj);
                    float p = __fsqrt_rn(m);
                    s1 += __logf(__fsub_rn(1.0f, p));
                    s2 += softplus_bce(x);
                }
            }
            s_red2[w][il] = make_float2(s1, s2);
            __syncthreads();

            if (valid) {
                float s1t = s_red2[0][il].x + s_red2[1][il].x + s_red2[2][il].x + s_red2[3][il].x;
                float s2t = s_red2[0][il].y + s_red2[1][il].y + s_red2[2][il].y + s_red2[3][il].y;
                float nsl = -s1t;

                if (w == 0) {
                    int a = s_arow[il];
                    float stv = st_[a];
                    float xc = __fmul_rn(__fadd_rn(xs_[a], 0.5f), stv);
                    float yc = __fmul_rn(__fadd_rn(ys_[a], 0.5f), stv);
                    float r  = __fmul_rn(1.5f, stv);
                    blist[b * CAP + i] = make_float4(R[0], R[1], R[2], R[3]);
                    glist[b * CAP + i] = make_float4(xc, yc, r, stv);
                    misc[b * CAP + i]  = make_float2(s2t, obj);
                }
#pragma unroll
                for (int gi = 0; gi < 10; gi++) {
                    int g = w * 10 + gi;
                    int gc = (int)s_lgt[g * 5];
                    float m = __fmul_rn(R[5 + gc], obj);
                    float p = __fsqrt_rn(m);
                    float term = __fsub_rn(__fmul_rn(0.5f, __logf(m)), __logf(__fsub_rn(1.0f, p)));
                    clsterm[((size_t)b * GG + g) * CAP + i] = __fsub_rn(nsl, term);
                }
            }
        }
        __syncthreads();   // protect shared reuse next virtual block
    }

    gbar(bar, 2 * nblk);

    // ---------------- phase 3: per-(b,g) SimOTA top-10 assignment -----------------
    for (int vb = blockIdx.x; vb < (BB * GG) / 4; vb += nblk) {
        int pair = vb * 4 + w;
        int b = pair / GG, g = pair - b * GG;

        const float* L = labels + (b * GG + g) * 5;
        float gx = L[1], gy = L[2], gw = L[3], gh = L[4];
        int n = __hip_atomic_load(&cnt[b], __ATOMIC_RELAXED, __HIP_MEMORY_SCOPE_AGENT);
        n = n > CAP ? CAP : n;

        const float*  ctp = clsterm + ((size_t)b * GG + g) * CAP;
        const float4* bp  = blist + b * CAP;
        const float4* gp  = glist + b * CAP;
        const int*    ap  = alist + b * CAP;

        ull t[10]; float tv[10];
#pragma unroll
        for (int k = 0; k < 10; k++) { t[k] = U64MAX; tv[k] = 0.0f; }

        for (int i = ln; i < n; i += 64) {
            float4 pb = bp[i];
            float4 gm = gp[i];
            float2 ci = cost_iou(gx, gy, gw, gh, pb.x, pb.y, pb.z, pb.w,
                                 gm.x, gm.y, gm.z, ctp[i], 1.0f);
            unsigned u = __float_as_uint(ci.x);
            u ^= (u & 0x80000000u) ? 0xFFFFFFFFu : 0x80000000u;
            ull key = ((ull)u << 32) | (unsigned)((ap[i] << 11) | i);
            if (key < t[9]) {
                int p = 0;
#pragma unroll
                for (int k = 0; k < 10; k++) p += (t[k] < key) ? 1 : 0;
#pragma unroll
                for (int k = 9; k >= 1; k--) t[k] = (k > p) ? t[k - 1] : t[k];
#pragma unroll
                for (int k = 0; k < 10; k++) if (k == p) t[k] = key;
            }
            float v = ci.y;
            if (v > tv[9]) {
                int p = 0;
#pragma unroll
                for (int k = 0; k < 10; k++) p += (tv[k] > v) ? 1 : 0;
#pragma unroll
                for (int k = 9; k >= 1; k--) tv[k] = (k > p) ? tv[k - 1] : tv[k];
#pragma unroll
                for (int k = 0; k < 10; k++) if (k == p) tv[k] = v;
            }
        }

        ull mykey = U64MAX;
#pragma unroll
        for (int r = 0; r < 10; r++) {
            ull mn = wave_min_u64(t[0]);
            if (ln == r) mykey = mn;
            bool own = (t[0] == mn);
#pragma unroll
            for (int k = 0; k < 9; k++) t[k] = own ? t[k + 1] : t[k];
            t[9] = own ? U64MAX : t[9];
        }
        float isum = 0.0f;
#pragma unroll
        for (int r = 0; r < 10; r++) {
            float mv = wave_max_f(tv[0]);
            isum += mv;
            ull bal = __ballot(tv[0] == mv);
            int first = (int)__ffsll((long long)bal) - 1;
            bool own = (ln == first);
#pragma unroll
            for (int k = 0; k < 9; k++) tv[k] = own ? tv[k + 1] : tv[k];
            tv[9] = own ? 0.0f : tv[9];
        }

        int dk = (int)isum;
        dk = dk < 1 ? 1 : (dk > 10 ? 10 : dk);
        if (ln < dk && mykey != U64MAX) {
            unsigned low = (unsigned)mykey;
            int a = (int)(low >> 11);
            int i2 = (int)(low & 2047);
            int idx = b * AA + a;
            if (atomicAdd(&matchcnt[idx], 1) == 0) {
                int wp = atomicAdd(wlcnt, 1);
                if (wp < CAPW) wl[wp] = make_int2(idx, (g << 16) | i2);
            }
        }
    }

    gbar(bar, 3 * nblk);

    // ---------------- phase 4: worklist loss + all-anchor obj BCE + finalize ------
    float t_fg = 0.0f, t_iou = 0.0f, t_obj = 0.0f, t_cls = 0.0f, t_l1 = 0.0f;

    if (blockIdx.x < K4GRID) {               // keep exact original partial grouping
        int gid = blockIdx.x * 256 + tid;
        int nw = __hip_atomic_load(wlcnt, __ATOMIC_RELAXED, __HIP_MEMORY_SCOPE_AGENT);
        nw = nw > CAPW ? CAPW : nw;

        for (int i = gid; i < BB * AA; i += K4GRID * 256)
            t_obj += softplus_bce(outputs[(size_t)i * NO + 4]);

        if (gid < nw) {
            int2 e = wl[gid];
            int idx = e.x;
            int b = idx / AA;
            int a = idx - b * AA;
            int ci = e.y & 0xFFFF;
            int g1 = e.y >> 16;
            int mcnt = matchcnt[idx];

            float4 pb = blist[b * CAP + ci];
            float4 gm = glist[b * CAP + ci];
            float2 mo = misc[b * CAP + ci];
            const float* Lb = labels + b * GG * 5;

            int mg;
            if (mcnt == 1) {
                mg = g1;
            } else {
                mg = 0; float best = FLT_MAX;
                for (int g = 0; g < GG; g++) {
                    float ct = clsterm[((size_t)b * GG + g) * CAP + ci];
                    float2 r = cost_iou(Lb[g * 5 + 1], Lb[g * 5 + 2], Lb[g * 5 + 3], Lb[g * 5 + 4],
                                        pb.x, pb.y, pb.z, pb.w, gm.x, gm.y, gm.z, ct, 1.0f);
                    if (r.x < best) { best = r.x; mg = g; }
                }
            }
            t_fg = 1.0f;
            t_obj += -mo.y;
            float gx = Lb[mg * 5 + 1], gy = Lb[mg * 5 + 2], gw = Lb[mg * 5 + 3], gh = Lb[mg * 5 + 4];
            int mcls = (int)Lb[mg * 5];
            float ctm = clsterm[((size_t)b * GG + mg) * CAP + ci];
            float2 r = cost_iou(gx, gy, gw, gh, pb.x, pb.y, pb.z, pb.w, gm.x, gm.y, gm.z, ctm, 1.0f);
            float pred_iou = r.y;
            float tlx = fmaxf(pb.x - pb.z * 0.5f, gx - gw * 0.5f);
            float tly = fmaxf(pb.y - pb.w * 0.5f, gy - gh * 0.5f);
            float brx = fminf(pb.x + pb.z * 0.5f, gx + gw * 0.5f);
            float bry = fminf(pb.y + pb.w * 0.5f, gy + gh * 0.5f);
            float en = (tlx < brx && tly < bry) ? 1.0f : 0.0f;
            float ai = (brx - tlx) * (bry - tly) * en;
            float iou = ai / (pb.z * pb.w + gw * gh - ai + 1e-16f);
            t_iou = 1.0f - iou * iou;
            const float* op = origin + (size_t)idx * 4;
            float stv = st_[a], xsv = xs_[a], ysv = ys_[a];
            t_l1 = fabsf(op[0] - (gx / stv - xsv)) + fabsf(op[1] - (gy / stv - ysv))
                 + fabsf(op[2] - logf(gw / stv + 1e-8f)) + fabsf(op[3] - logf(gh / stv + 1e-8f));
            t_cls = mo.x - outputs[(size_t)idx * NO + 5 + mcls] * pred_iou;
        }
    }

    t_fg = wave_sum(t_fg); t_iou = wave_sum(t_iou); t_obj = wave_sum(t_obj);
    t_cls = wave_sum(t_cls); t_l1 = wave_sum(t_l1);
    float (*red)[4] = reinterpret_cast<float(*)[4]>(s_red2);   // 80 B alias
    if (ln == 0) { red[0][w] = t_fg; red[1][w] = t_iou; red[2][w] = t_obj; red[3][w] = t_cls; red[4][w] = t_l1; }
    __syncthreads();
    if (tid == 0) {
        atomicAdd(&acc[0], red[0][0] + red[0][1] + red[0][2] + red[0][3]);
        atomicAdd(&acc[1], red[1][0] + red[1][1] + red[1][2] + red[1][3]);
        atomicAdd(&acc[2], red[2][0] + red[2][1] + red[2][2] + red[2][3]);
        atomicAdd(&acc[3], red[3][0] + red[3][1] + red[3][2] + red[3][3]);
        atomicAdd(&acc[4], red[4][0] + red[4][1] + red[4][2] + red[4][3]);
        __threadfence();
        int tkt = atomicAdd(fin, 1);
        if (tkt == nblk - 1) {
            float a0 = atomicAdd(&acc[0], 0.0f);
            float a1 = atomicAdd(&acc[1], 0.0f);
            float a2 = atomicAdd(&acc[2], 0.0f);
            float a3 = atomicAdd(&acc[3], 0.0f);
            float a4 = atomicAdd(&acc[4], 0.0f);
            float nfg = fmaxf(a0, 1.0f);
            float li = 5.0f * a1 / nfg;
            float lo = a2 / nfg;
            float lc = a3 / nfg;
            float ll = a4 / nfg;
            out[0] = li + lo + lc + ll;
            out[1] = li;
            out[2] = lo;
            out[3] = lc;
            out[4] = ll;
            out[5] = nfg / (float)(BB * GG);
        }
    }
}

// =====================================================================
// Legacy 4-kernel path (fallback if cooperative launch is unavailable)
// =====================================================================

__global__ __launch_bounds__(256) void k1a_fg(
    const float* __restrict__ labels,
    const float* __restrict__ xs_, const float* __restrict__ ys_, const float* __restrict__ st_,
    int* __restrict__ ctrl, int* __restrict__ matchcnt, int* __restrict__ alist)
{
    __shared__ float lgt[GG * 5];
    __shared__ int   lloc[256];
    __shared__ int   lcnt, sbase;

    int b = blockIdx.y;
    int tid = threadIdx.x, ln = tid & 63;
    int* cnt = ctrl + 8;

    if (tid == 0) atomicCAS((unsigned*)&cnt[b], POISON, 0u);
    if (blockIdx.x == 0 && b == 0 && tid < 48) atomicCAS((unsigned*)&ctrl[tid], POISON, 0u);
    if (tid == 0) lcnt = 0;

    int nb  = gridDim.x * gridDim.y;
    int bid = b * gridDim.x + blockIdx.x;
    for (int i = bid * 256 + tid; i < BB * AA; i += nb * 256) matchcnt[i] = 0;

    for (int i = tid; i < GG * 5; i += 256) lgt[i] = labels[b * GG * 5 + i];
    __syncthreads();

    int a = blockIdx.x * 256 + tid;
    bool fg = false;
    if (a < AA) {
        float stv = st_[a];
        float xc = __fmul_rn(__fadd_rn(xs_[a], 0.5f), stv);
        float yc = __fmul_rn(__fadd_rn(ys_[a], 0.5f), stv);
        float r  = __fmul_rn(1.5f, stv);
        for (int g = 0; g < GG && !fg; g++)
            fg = dev_in(lgt[g * 5 + 1], lgt[g * 5 + 2], xc, yc, r);
    }
    ull mk = __ballot(fg);
    int cw = __popcll(mk);
    int wbase = 0;
    if (ln == 0 && cw) wbase = atomicAdd(&lcnt, cw);
    wbase = __shfl(wbase, 0, 64);
    if (fg) lloc[wbase + __popcll(mk & ((1ull << ln) - 1ull))] = a;
    __syncthreads();
    if (tid == 0) sbase = atomicAdd(&cnt[b], lcnt);
    __syncthreads();
    int m = lcnt, base = sbase;
    for (int j = tid; j < m; j += 256)
        if (base + j < CAP) alist[b * CAP + base + j] = lloc[j];
}

__global__ __launch_bounds__(256) void k1b_cls(
    const float* __restrict__ outputs, const float* __restrict__ labels,
    const float* __restrict__ xs_, const float* __restrict__ ys_, const float* __restrict__ st_,
    const int* __restrict__ ctrl, const int* __restrict__ alist,
    float4* __restrict__ blist, float4* __restrict__ glist,
    float2* __restrict__ misc, float* __restrict__ clsterm)
{
    int b = blockIdx.y;
    int i0 = blockIdx.x * 64;
    int n = ctrl[8 + b]; n = n > CAP ? CAP : n;
    if (i0 >= n) return;

    __shared__ float rows[64 * NO];
    __shared__ float lgt[GG * 5];
    __shared__ int   arow[64];
    __shared__ float2 red2[4][64];

    int tid = threadIdx.x;
    int w = tid >> 6, ln = tid & 63;
    for (int t = tid; t < GG * 5; t += 256) lgt[t] = labels[b * GG * 5 + t];

    for (int rr = 0; rr < 16; rr++) {
        int row = i0 + w * 16 + rr;
        if (row < n) {
            int a = alist[b * CAP + row];
            const float* src = outputs + ((size_t)b * AA + a) * NO;
            int rl = w * 16 + rr;
            rows[rl * NO + ln] = src[ln];
            if (ln < NO - 64) rows[rl * NO + 64 + ln] = src[64 + ln];
            if (ln == 0) arow[rl] = a;
        }
    }
    __syncthreads();

    int il = ln;
    int i = i0 + il;
    bool valid = i < n;
    const float* R = rows + il * NO;
    float obj = R[4];

    float s1 = 0.0f, s2 = 0.0f;
    if (valid) {
        int c0 = w * 20;
#pragma unroll 4
        for (int j = 0; j < 20; j++) {
            float x = R[5 + c0 + j];
            float m = __fmul_rn(x, obj);
            float p = __fsqrt_rn(m);
            s1 += __logf(__fsub_rn(1.0f, p));
            s2 += softplus_bce(x);
        }
    }
    red2[w][il] = make_float2(s1, s2);
    __syncthreads();

    if (!valid) return;
    float s1t = red2[0][il].x + red2[1][il].x + red2[2][il].x + red2[3][il].x;
    float s2t = red2[0][il].y + red2[1][il].y + red2[2][il].y + red2[3][il].y;
    float nsl = -s1t;

    if (w == 0) {
        int a = arow[il];
        float stv = st_[a];
        float xc = __fmul_rn(__fadd_rn(xs_[a], 0.5f), stv);
        float yc = __fmul_rn(__fadd_rn(ys_[a], 0.5f), stv);
        float r  = __fmul_rn(1.5f, stv);
        blist[b * CAP + i] = make_float4(R[0], R[1], R[2], R[3]);
        glist[b * CAP + i] = make_float4(xc, yc, r, stv);
        misc[b * CAP + i]  = make_float2(s2t, obj);
    }
#pragma unroll
    for (int gi = 0; gi < 10; gi++) {
        int g = w * 10 + gi;
        int gc = (int)lgt[g * 5];
        float m = __fmul_rn(R[5 + gc], obj);
        float p = __fsqrt_rn(m);
        float term = __fsub_rn(__fmul_rn(0.5f, __logf(m)), __logf(__fsub_rn(1.0f, p)));
        clsterm[((size_t)b * GG + g) * CAP + i] = __fsub_rn(nsl, term);
    }
}

__global__ __launch_bounds__(256) void k2_assign(
    const float* __restrict__ labels,
    int* __restrict__ ctrl,
    const int* __restrict__ alist,
    const float4* __restrict__ blist, const float4* __restrict__ glist,
    const float* __restrict__ clsterm,
    int* __restrict__ matchcnt, int2* __restrict__ wl)
{
    int w = threadIdx.x >> 6, ln = threadIdx.x & 63;
    int pair = blockIdx.x * 4 + w;
    int b = pair / GG, g = pair - b * GG;
    int* cnt   = ctrl + 8;
    int* wlcnt = ctrl + 40;

    const float* L = labels + (b * GG + g) * 5;
    float gx = L[1], gy = L[2], gw = L[3], gh = L[4];
    int n = cnt[b]; n = n > CAP ? CAP : n;

    const float*  ctp = clsterm + ((size_t)b * GG + g) * CAP;
    const float4* bp  = blist + b * CAP;
    const float4* gp  = glist + b * CAP;
    const int*    ap  = alist + b * CAP;

    ull t[10]; float tv[10];
#pragma unroll
    for (int k = 0; k < 10; k++) { t[k] = U64MAX; tv[k] = 0.0f; }

    for (int i = ln; i < n; i += 64) {
        float4 pb = bp[i];
        float4 gm = gp[i];
        float2 ci = cost_iou(gx, gy, gw, gh, pb.x, pb.y, pb.z, pb.w,
                             gm.x, gm.y, gm.z, ctp[i], 1.0f);
        unsigned u = __float_as_uint(ci.x);
        u ^= (u & 0x80000000u) ? 0xFFFFFFFFu : 0x80000000u;
        ull key = ((ull)u << 32) | (unsigned)((ap[i] << 11) | i);
        if (key < t[9]) {
            int p = 0;
#pragma unroll
            for (int k = 0; k < 10; k++) p += (t[k] < key) ? 1 : 0;
#pragma unroll
            for (int k = 9; k >= 1; k--) t[k] = (k > p) ? t[k - 1] : t[k];
#pragma unroll
            for (int k = 0; k < 10; k++) if (k == p) t[k] = key;
        }
        float v = ci.y;
        if (v > tv[9]) {
            int p = 0;
#pragma unroll
            for (int k = 0; k < 10; k++) p += (tv[k] > v) ? 1 : 0;
#pragma unroll
            for (int k = 9; k >= 1; k--) tv[k] = (k > p) ? tv[k - 1] : tv[k];
#pragma unroll
            for (int k = 0; k < 10; k++) if (k == p) tv[k] = v;
        }
    }

    ull mykey = U64MAX;
#pragma unroll
    for (int r = 0; r < 10; r++) {
        ull mn = wave_min_u64(t[0]);
        if (ln == r) mykey = mn;
        bool own = (t[0] == mn);
#pragma unroll
        for (int k = 0; k < 9; k++) t[k] = own ? t[k + 1] : t[k];
        t[9] = own ? U64MAX : t[9];
    }
    float isum = 0.0f;
#pragma unroll
    for (int r = 0; r < 10; r++) {
        float mv = wave_max_f(tv[0]);
        isum += mv;
        ull bal = __ballot(tv[0] == mv);
        int first = (int)__ffsll((long long)bal) - 1;
        bool own = (ln == first);
#pragma unroll
        for (int k = 0; k < 9; k++) tv[k] = own ? tv[k + 1] : tv[k];
        tv[9] = own ? 0.0f : tv[9];
    }

    int dk = (int)isum;
    dk = dk < 1 ? 1 : (dk > 10 ? 10 : dk);
    if (ln < dk && mykey != U64MAX) {
        unsigned low = (unsigned)mykey;
        int a = (int)(low >> 11);
        int i2 = (int)(low & 2047);
        int idx = b * AA + a;
        if (atomicAdd(&matchcnt[idx], 1) == 0) {
            int wp = atomicAdd(wlcnt, 1);
            if (wp < CAPW) wl[wp] = make_int2(idx, (g << 16) | i2);
        }
    }
}

__global__ __launch_bounds__(256) void k4_loss(
    const float* __restrict__ outputs, const float* __restrict__ origin,
    const float* __restrict__ labels,
    const float* __restrict__ xs_, const float* __restrict__ ys_, const float* __restrict__ st_,
    const float4* __restrict__ blist, const float4* __restrict__ glist,
    const float2* __restrict__ misc, const float* __restrict__ clsterm,
    const int* __restrict__ matchcnt,
    const int2* __restrict__ wl, int* __restrict__ ctrl,
    float* __restrict__ out)
{
    float* acc = (float*)ctrl;
    int* wlcnt = ctrl + 40;
    int* fin   = ctrl + 41;

    int tid = threadIdx.x;
    int gid = blockIdx.x * 256 + tid;
    int nw = *wlcnt; nw = nw > CAPW ? CAPW : nw;

    float t_fg = 0.0f, t_iou = 0.0f, t_obj = 0.0f, t_cls = 0.0f, t_l1 = 0.0f;

    for (int i = gid; i < BB * AA; i += K4GRID * 256)
        t_obj += softplus_bce(outputs[(size_t)i * NO + 4]);

    if (gid < nw) {
        int2 e = wl[gid];
        int idx = e.x;
        int b = idx / AA;
        int a = idx - b * AA;
        int ci = e.y & 0xFFFF;
        int g1 = e.y >> 16;
        int mcnt = matchcnt[idx];

        float4 pb = blist[b * CAP + ci];
        float4 gm = glist[b * CAP + ci];
        float2 mo = misc[b * CAP + ci];
        const float* Lb = labels + b * GG * 5;

        int mg;
        if (mcnt == 1) {
            mg = g1;
        } else {
            mg = 0; float best = FLT_MAX;
            for (int g = 0; g < GG; g++) {
                float ct = clsterm[((size_t)b * GG + g) * CAP + ci];
                float2 r = cost_iou(Lb[g * 5 + 1], Lb[g * 5 + 2], Lb[g * 5 + 3], Lb[g * 5 + 4],
                                    pb.x, pb.y, pb.z, pb.w, gm.x, gm.y, gm.z, ct, 1.0f);
                if (r.x < best) { best = r.x; mg = g; }
            }
        }
        t_fg = 1.0f;
        t_obj += -mo.y;
        float gx = Lb[mg * 5 + 1], gy = Lb[mg * 5 + 2], gw = Lb[mg * 5 + 3], gh = Lb[mg * 5 + 4];
        int mcls = (int)Lb[mg * 5];
        float ctm = clsterm[((size_t)b * GG + mg) * CAP + ci];
        float2 r = cost_iou(gx, gy, gw, gh, pb.x, pb.y, pb.z, pb.w, gm.x, gm.y, gm.z, ctm, 1.0f);
        float pred_iou = r.y;
        float tlx = fmaxf(pb.x - pb.z * 0.5f, gx - gw * 0.5f);
        float tly = fmaxf(pb.y - pb.w * 0.5f, gy - gh * 0.5f);
        float brx = fminf(pb.x + pb.z * 0.5f, gx + gw * 0.5f);
        float bry = fminf(pb.y + pb.w * 0.5f, gy + gh * 0.5f);
        float en = (tlx < brx && tly < bry) ? 1.0f : 0.0f;
        float ai = (brx - tlx) * (bry - tly) * en;
        float iou = ai / (pb.z * pb.w + gw * gh - ai + 1e-16f);
        t_iou = 1.0f - iou * iou;
        const float* op = origin + (size_t)idx * 4;
        float stv = st_[a], xsv = xs_[a], ysv = ys_[a];
        t_l1 = fabsf(op[0] - (gx / stv - xsv)) + fabsf(op[1] - (gy / stv - ysv))
             + fabsf(op[2] - logf(gw / stv + 1e-8f)) + fabsf(op[3] - logf(gh / stv + 1e-8f));
        t_cls = mo.x - outputs[(size_t)idx * NO + 5 + mcls] * pred_iou;
    }

    t_fg = wave_sum(t_fg); t_iou = wave_sum(t_iou); t_obj = wave_sum(t_obj);
    t_cls = wave_sum(t_cls); t_l1 = wave_sum(t_l1);
    __shared__ float red[5][4];
    int wv = threadIdx.x >> 6, ln = threadIdx.x & 63;
    if (ln == 0) { red[0][wv] = t_fg; red[1][wv] = t_iou; red[2][wv] = t_obj; red[3][wv] = t_cls; red[4][wv] = t_l1; }
    __syncthreads();
    if (threadIdx.x == 0) {
        atomicAdd(&acc[0], red[0][0] + red[0][1] + red[0][2] + red[0][3]);
        atomicAdd(&acc[1], red[1][0] + red[1][1] + red[1][2] + red[1][3]);
        atomicAdd(&acc[2], red[2][0] + red[2][1] + red[2][2] + red[2][3]);
        atomicAdd(&acc[3], red[3][0] + red[3][1] + red[3][2] + red[3][3]);
        atomicAdd(&acc[4], red[4][0] + red[4][1] + red[4][2] + red[4][3]);
        __threadfence();
        int tkt = atomicAdd(fin, 1);
        if (tkt == (int)gridDim.x - 1) {
            float a0 = atomicAdd(&acc[0], 0.0f);
            float a1 = atomicAdd(&acc[1], 0.0f);
            float a2 = atomicAdd(&acc[2], 0.0f);
            float a3 = atomicAdd(&acc[3], 0.0f);
            float a4 = atomicAdd(&acc[4], 0.0f);
            float nfg = fmaxf(a0, 1.0f);
            float li = 5.0f * a1 / nfg;
            float lo = a2 / nfg;
            float lc = a3 / nfg;
            float ll = a4 / nfg;
            out[0] = li + lo + lc + ll;
            out[1] = li;
            out[2] = lo;
            out[3] = lc;
            out[4] = ll;
            out[5] = nfg / (float)(BB * GG);
        }
    }
}

// ---------- workspace layout (16B-aligned blocks) ----------
static constexpr size_t NBA       = (size_t)BB * AA;
static constexpr size_t OFF_MC    = 256;
static constexpr size_t OFF_ALIST = OFF_MC + NBA * 4;
static constexpr size_t OFF_BL    = OFF_ALIST + (size_t)BB * CAP * 4;
static constexpr size_t OFF_GL    = OFF_BL + (size_t)BB * CAP * 16;
static constexpr size_t OFF_MISC  = OFF_GL + (size_t)BB * CAP * 16;
static constexpr size_t OFF_CT    = OFF_MISC + (size_t)BB * CAP * 8;
static constexpr size_t OFF_WL    = OFF_CT + (size_t)BB * GG * CAP * 4;

extern "C" void kernel_launch(void* const* d_in, const int* in_sizes, int n_in,
                              void* d_out, int out_size, void* d_ws, size_t ws_size,
                              hipStream_t stream)
{
    (void)in_sizes; (void)n_in; (void)out_size; (void)ws_size;
    const float* outputs = (const float*)d_in[0];
    const float* origin  = (const float*)d_in[1];
    const float* labels  = (const float*)d_in[2];
    const float* xs_     = (const float*)d_in[3];
    const float* ys_     = (const float*)d_in[4];
    const float* st_     = (const float*)d_in[5];
    float* out = (float*)d_out;
    char* ws = (char*)d_ws;

    int*    ctrl     = (int*)(ws);
    int*    matchcnt = (int*)(ws + OFF_MC);
    int*    alist    = (int*)(ws + OFF_ALIST);
    float4* blist    = (float4*)(ws + OFF_BL);
    float4* glist    = (float4*)(ws + OFF_GL);
    float2* misc     = (float2*)(ws + OFF_MISC);
    float*  clsterm  = (float*)(ws + OFF_CT);
    int2*   wl       = (int2*)(ws + OFF_WL);

    void* args[] = {
        (void*)&outputs, (void*)&origin, (void*)&labels,
        (void*)&xs_, (void*)&ys_, (void*)&st_,
        (void*)&ctrl, (void*)&matchcnt, (void*)&alist,
        (void*)&blist, (void*)&glist, (void*)&misc, (void*)&clsterm,
        (void*)&wl, (void*)&out
    };
    // cooperative launch used ONLY for the co-residency guarantee; the kernel
    // uses its own lightweight barrier, not cg::grid.sync (130us/sync measured).
    hipError_t err = hipLaunchCooperativeKernel(fused, dim3(NBLK), dim3(256), args, 0, stream);

    if (err != hipSuccess) {
        // legacy 4-kernel fallback (identical math)
        dim3 grid1((AA + 255) / 256, BB);
        k1a_fg<<<grid1, 256, 0, stream>>>(labels, xs_, ys_, st_, ctrl, matchcnt, alist);

        dim3 grid1b(CAP / 64, BB);
        k1b_cls<<<grid1b, 256, 0, stream>>>(outputs, labels, xs_, ys_, st_, ctrl, alist,
                                            blist, glist, misc, clsterm);

        k2_assign<<<BB * GG / 4, 256, 0, stream>>>(labels, ctrl, alist, blist, glist, clsterm,
                                                   matchcnt, wl);

        k4_loss<<<K4GRID, 256, 0, stream>>>(outputs, origin, labels, xs_, ys_, st_,
                                            blist, glist, misc, clsterm, matchcnt, wl,
                                            ctrl, out);
    }
}

// Round 3
// 376.187 us; speedup vs baseline: 1.1687x; 1.0366x over previous
//
#include <hip/hip_runtime.h>
#include <cfloat>

#define BB 32
#define AA 8400
#define GG 40
#define NC 80
#define NO 85
#define CAP 2048    // >= geometric bound ~27 anchors/gt * 40 gts = 1080
#define CAPW 13312  // >= 1280 gts * dk_max 10 = 12800
#define POISON 0xAAAAAAAAu
#define K4GRID 104  // kept for exact phase-4 partial-sum grouping
#define NBLK 320    // fused grid: == phase-3 width; >= K4GRID

typedef unsigned long long ull;
#define U64MAX 0xFFFFFFFFFFFFFFFFull

// ---------- deterministic helpers: explicit _rn ops (no FMA contraction) so every
// call site produces bitwise-identical values ----------

__device__ inline bool dev_in(float gx, float gy, float xc, float yc, float r)
{
    float dl = __fsub_rn(xc, __fsub_rn(gx, r));
    float dr = __fsub_rn(__fadd_rn(gx, r), xc);
    float dt = __fsub_rn(yc, __fsub_rn(gy, r));
    float db = __fsub_rn(__fadd_rn(gy, r), yc);
    return fminf(fminf(dl, dr), fminf(dt, db)) > 0.0f;
}

__device__ inline float2 cost_iou(float gx, float gy, float gw, float gh,
                                  float px, float py, float pw, float ph,
                                  float xc, float yc, float r,
                                  float ct, float fg)
{
    bool in = dev_in(gx, gy, xc, yc, r);
    float gw2 = __fmul_rn(gw, 0.5f), gh2 = __fmul_rn(gh, 0.5f);
    float pw2 = __fmul_rn(pw, 0.5f), ph2 = __fmul_rn(ph, 0.5f);
    float tlx = fmaxf(__fsub_rn(gx, gw2), __fsub_rn(px, pw2));
    float tly = fmaxf(__fsub_rn(gy, gh2), __fsub_rn(py, ph2));
    float brx = fminf(__fadd_rn(gx, gw2), __fadd_rn(px, pw2));
    float bry = fminf(__fadd_rn(gy, gh2), __fadd_rn(py, ph2));
    float en = (tlx < brx && tly < bry) ? 1.0f : 0.0f;
    float ai = __fmul_rn(__fmul_rn(__fsub_rn(brx, tlx), __fsub_rn(bry, tly)), en);
    float ag = __fmul_rn(gw, gh);
    float ap = __fmul_rn(pw, ph);
    float iou = ai / __fsub_rn(__fadd_rn(ag, ap), ai);
    iou = (fg != 0.0f) ? iou : 0.0f;
    float icost = -__logf(__fadd_rn(iou, 1e-8f));
    float cost = __fadd_rn(__fadd_rn(ct, __fmul_rn(3.0f, icost)), in ? 0.0f : 1000000.0f);
    cost = (fg != 0.0f) ? cost : 1000000000.0f;
    return make_float2(cost, iou);
}

__device__ inline float softplus_bce(float x)
{
    return fmaxf(x, 0.0f) + __logf(1.0f + __expf(-fabsf(x)));
}

__device__ inline float wave_sum(float v)
{
#pragma unroll
    for (int o = 32; o > 0; o >>= 1) v += __shfl_down(v, o, 64);
    return v;
}

__device__ inline ull wave_min_u64(ull v)
{
#pragma unroll
    for (int o = 1; o < 64; o <<= 1) {
        ull w = (ull)__shfl_xor((long long)v, o, 64);
        v = w < v ? w : v;
    }
    return v;
}

__device__ inline float wave_max_f(float v)
{
#pragma unroll
    for (int o = 1; o < 64; o <<= 1) v = fmaxf(v, __shfl_xor(v, o, 64));
    return v;
}

// ---------- per-access agent-coherent stores: bypass the XCD L2 so readers on
// other XCDs see the data WITHOUT any release/acquire bulk cache maintenance.
__device__ inline void ast_u32(void* p, unsigned v)
{
    __hip_atomic_store((unsigned*)p, v, __ATOMIC_RELAXED, __HIP_MEMORY_SCOPE_AGENT);
}
__device__ inline void ast_i32(void* p, int v)
{
    __hip_atomic_store((int*)p, v, __ATOMIC_RELAXED, __HIP_MEMORY_SCOPE_AGENT);
}
__device__ inline void ast_f32(float* p, float v)
{
    __hip_atomic_store(p, v, __ATOMIC_RELAXED, __HIP_MEMORY_SCOPE_AGENT);
}
__device__ inline void ast_u64(void* p, ull v)
{
    __hip_atomic_store((ull*)p, v, __ATOMIC_RELAXED, __HIP_MEMORY_SCOPE_AGENT);
}
__device__ inline ull pack_ff(float lo, float hi)
{
    return ((ull)__float_as_uint(hi) << 32) | (ull)__float_as_uint(lo);
}

// ---------- fence-free grid barrier. __syncthreads drains each wave's vmcnt
// (compiler emits s_waitcnt vmcnt(0) before s_barrier), so all agent-coherent
// stores have landed at the coherence point before the leader arrives. No
// release/acquire -> no buffer_wbl2 / buffer_inv bulk L2 maintenance (the ~80us
// per-sync cost measured in R2). Monotonic counter; poison-safe via CAS.
__device__ inline void gbar(int* arr, int target)
{
    __syncthreads();
    if (threadIdx.x == 0) {
        __hip_atomic_fetch_add(arr, 1, __ATOMIC_RELAXED, __HIP_MEMORY_SCOPE_AGENT);
        int guard = 0;
        for (;;) {
            int v = __hip_atomic_load(arr, __ATOMIC_RELAXED, __HIP_MEMORY_SCOPE_AGENT);
            if (v >= target) break;
            __builtin_amdgcn_s_sleep(2);
            if (++guard > (1 << 22)) break;   // safety valve: fail visibly, not hang
        }
    }
    __syncthreads();
}

// ctrl layout (ints): [0..7]=acc(float), [8..39]=cnt[32], [40]=wlcnt, [41]=fin, [56]=bar

// =====================================================================
// FUSED kernel: 4 phases, 3 fence-free grid barriers, math identical to
// the 4-kernel pipeline (k1a / k1b / k2 / k4).
// =====================================================================
__global__ __launch_bounds__(256, 3) void fused(
    const float* __restrict__ outputs, const float* __restrict__ origin,
    const float* __restrict__ labels,
    const float* __restrict__ xs_, const float* __restrict__ ys_, const float* __restrict__ st_,
    int* __restrict__ ctrl, int* __restrict__ matchcnt, int* __restrict__ alist,
    float4* __restrict__ blist, float4* __restrict__ glist,
    float2* __restrict__ misc, float* __restrict__ clsterm,
    int2* __restrict__ wl, float* __restrict__ out)
{
    __shared__ float  s_rows[64 * NO];      // 21.8 KB (phase 2; aliased in 1 & 4)
    __shared__ float  s_lgt[GG * 5];
    __shared__ int    s_arow[64];
    __shared__ float2 s_red2[4][64];
    __shared__ int    s_cnt[2];             // lcnt, sbase

    int tid = threadIdx.x;
    int w = tid >> 6, ln = tid & 63;
    int* cnt = ctrl + 8;
    int* wlcnt = ctrl + 40;
    int* fin   = ctrl + 41;
    int* bar   = ctrl + 56;
    float* acc = (float*)ctrl;
    int nblk = gridDim.x;

    // poison-safe barrier init: EVERY block CASes before its first arrive
    if (tid == 0) atomicCAS((unsigned*)bar, POISON, 0u);

    // ---------------- phase 1: ctrl init + matchcnt zero + fg compaction ----------
    if (blockIdx.x == 0 && tid < 48) atomicCAS((unsigned*)&ctrl[tid], POISON, 0u);
    for (int i = blockIdx.x * 256 + tid; i < BB * AA; i += nblk * 256)
        ast_i32(&matchcnt[i], 0);           // coherent zero: phase-3 atomics read at L3

    const int GX1 = (AA + 255) / 256;       // 33
    int* lloc = (int*)s_rows;               // alias: phase-1 scratch
    for (int vb = blockIdx.x; vb < GX1 * BB; vb += nblk) {
        int bx = vb % GX1, b = vb / GX1;
        if (tid == 0) { atomicCAS((unsigned*)&cnt[b], POISON, 0u); s_cnt[0] = 0; }
        for (int i = tid; i < GG * 5; i += 256) s_lgt[i] = labels[b * GG * 5 + i];
        __syncthreads();

        int a = bx * 256 + tid;
        bool fg = false;
        if (a < AA) {
            float stv = st_[a];
            float xc = __fmul_rn(__fadd_rn(xs_[a], 0.5f), stv);
            float yc = __fmul_rn(__fadd_rn(ys_[a], 0.5f), stv);
            float r  = __fmul_rn(1.5f, stv);
            for (int g = 0; g < GG && !fg; g++)
                fg = dev_in(s_lgt[g * 5 + 1], s_lgt[g * 5 + 2], xc, yc, r);
        }
        ull mk = __ballot(fg);
        int cw = __popcll(mk);
        int wbase = 0;
        if (ln == 0 && cw) wbase = atomicAdd(&s_cnt[0], cw);
        wbase = __shfl(wbase, 0, 64);
        if (fg) lloc[wbase + __popcll(mk & ((1ull << ln) - 1ull))] = a;
        __syncthreads();
        if (tid == 0) s_cnt[1] = atomicAdd(&cnt[b], s_cnt[0]);
        __syncthreads();
        int m = s_cnt[0], base = s_cnt[1];
        for (int j = tid; j < m; j += 256)
            if (base + j < CAP) ast_i32(&alist[b * CAP + base + j], lloc[j]);
        __syncthreads();   // protect shared reuse next virtual block
    }

    gbar(bar, 1 * nblk);

    // ---------------- phase 2: fg rows -> class terms / compacted lists ----------
    const int GX2 = CAP / 64;               // 32
    for (int vb = blockIdx.x; vb < GX2 * BB; vb += nblk) {
        int bx = vb % GX2, b = vb / GX2;
        int i0 = bx * 64;
        int n = __hip_atomic_load(&cnt[b], __ATOMIC_RELAXED, __HIP_MEMORY_SCOPE_AGENT);
        n = n > CAP ? CAP : n;
        if (i0 < n) {                       // block-uniform predicate
            for (int t = tid; t < GG * 5; t += 256) s_lgt[t] = labels[b * GG * 5 + t];
            for (int rr = 0; rr < 16; rr++) {
                int row = i0 + w * 16 + rr;
                if (row < n) {
                    int a = __hip_atomic_load(&alist[b * CAP + row], __ATOMIC_RELAXED,
                                              __HIP_MEMORY_SCOPE_AGENT);
                    const float* src = outputs + ((size_t)b * AA + a) * NO;
                    int rl = w * 16 + rr;
                    s_rows[rl * NO + ln] = src[ln];
                    if (ln < NO - 64) s_rows[rl * NO + 64 + ln] = src[64 + ln];
                    if (ln == 0) s_arow[rl] = a;
                }
            }
            __syncthreads();

            int il = ln;
            int i = i0 + il;
            bool valid = i < n;
            const float* R = s_rows + il * NO;
            float obj = R[4];

            float s1 = 0.0f, s2 = 0.0f;
            if (valid) {
                int c0 = w * 20;
#pragma unroll 4
                for (int j = 0; j < 20; j++) {
                    float x = R[5 + c0 + j];
                    float m = __fmul_rn(x, obj);
                    float p = __fsqrt_rn(m);
                    s1 += __logf(__fsub_rn(1.0f, p));
                    s2 += softplus_bce(x);
                }
            }
            s_red2[w][il] = make_float2(s1, s2);
            __syncthreads();

            if (valid) {
                float s1t = s_red2[0][il].x + s_red2[1][il].x + s_red2[2][il].x + s_red2[3][il].x;
                float s2t = s_red2[0][il].y + s_red2[1][il].y + s_red2[2][il].y + s_red2[3][il].y;
                float nsl = -s1t;

                if (w == 0) {
                    int a = s_arow[il];
                    float stv = st_[a];
                    float xc = __fmul_rn(__fadd_rn(xs_[a], 0.5f), stv);
                    float yc = __fmul_rn(__fadd_rn(ys_[a], 0.5f), stv);
                    float r  = __fmul_rn(1.5f, stv);
                    float4* bl = &blist[b * CAP + i];
                    ast_u64(bl, pack_ff(R[0], R[1]));
                    ast_u64((char*)bl + 8, pack_ff(R[2], R[3]));
                    float4* gl = &glist[b * CAP + i];
                    ast_u64(gl, pack_ff(xc, yc));
                    ast_u64((char*)gl + 8, pack_ff(r, stv));
                    ast_u64(&misc[b * CAP + i], pack_ff(s2t, obj));
                }
#pragma unroll
                for (int gi = 0; gi < 10; gi++) {
                    int g = w * 10 + gi;
                    int gc = (int)s_lgt[g * 5];
                    float m = __fmul_rn(R[5 + gc], obj);
                    float p = __fsqrt_rn(m);
                    float term = __fsub_rn(__fmul_rn(0.5f, __logf(m)), __logf(__fsub_rn(1.0f, p)));
                    ast_f32(&clsterm[((size_t)b * GG + g) * CAP + i], __fsub_rn(nsl, term));
                }
            }
        }
        __syncthreads();   // protect shared reuse next virtual block
    }

    gbar(bar, 2 * nblk);

    // ---------------- phase 3: per-(b,g) SimOTA top-10 assignment -----------------
    // (normal cached loads are safe: first touch of blist/glist/clsterm lines on
    //  any reader XCD happens after the barrier; kernel-start invalidate means no
    //  stale lines can pre-exist.)
    for (int vb = blockIdx.x; vb < (BB * GG) / 4; vb += nblk) {
        int pair = vb * 4 + w;
        int b = pair / GG, g = pair - b * GG;

        const float* L = labels + (b * GG + g) * 5;
        float gx = L[1], gy = L[2], gw = L[3], gh = L[4];
        int n = __hip_atomic_load(&cnt[b], __ATOMIC_RELAXED, __HIP_MEMORY_SCOPE_AGENT);
        n = n > CAP ? CAP : n;

        const float*  ctp = clsterm + ((size_t)b * GG + g) * CAP;
        const float4* bp  = blist + b * CAP;
        const float4* gp  = glist + b * CAP;
        const int*    ap  = alist + b * CAP;

        ull t[10]; float tv[10];
#pragma unroll
        for (int k = 0; k < 10; k++) { t[k] = U64MAX; tv[k] = 0.0f; }

        for (int i = ln; i < n; i += 64) {
            float4 pb = bp[i];
            float4 gm = gp[i];
            float2 ci = cost_iou(gx, gy, gw, gh, pb.x, pb.y, pb.z, pb.w,
                                 gm.x, gm.y, gm.z, ctp[i], 1.0f);
            unsigned u = __float_as_uint(ci.x);
            u ^= (u & 0x80000000u) ? 0xFFFFFFFFu : 0x80000000u;
            ull key = ((ull)u << 32) | (unsigned)((ap[i] << 11) | i);
            if (key < t[9]) {
                int p = 0;
#pragma unroll
                for (int k = 0; k < 10; k++) p += (t[k] < key) ? 1 : 0;
#pragma unroll
                for (int k = 9; k >= 1; k--) t[k] = (k > p) ? t[k - 1] : t[k];
#pragma unroll
                for (int k = 0; k < 10; k++) if (k == p) t[k] = key;
            }
            float v = ci.y;
            if (v > tv[9]) {
                int p = 0;
#pragma unroll
                for (int k = 0; k < 10; k++) p += (tv[k] > v) ? 1 : 0;
#pragma unroll
                for (int k = 9; k >= 1; k--) tv[k] = (k > p) ? tv[k - 1] : tv[k];
#pragma unroll
                for (int k = 0; k < 10; k++) if (k == p) tv[k] = v;
            }
        }

        ull mykey = U64MAX;
#pragma unroll
        for (int r = 0; r < 10; r++) {
            ull mn = wave_min_u64(t[0]);
            if (ln == r) mykey = mn;
            bool own = (t[0] == mn);
#pragma unroll
            for (int k = 0; k < 9; k++) t[k] = own ? t[k + 1] : t[k];
            t[9] = own ? U64MAX : t[9];
        }
        float isum = 0.0f;
#pragma unroll
        for (int r = 0; r < 10; r++) {
            float mv = wave_max_f(tv[0]);
            isum += mv;
            ull bal = __ballot(tv[0] == mv);
            int first = (int)__ffsll((long long)bal) - 1;
            bool own = (ln == first);
#pragma unroll
            for (int k = 0; k < 9; k++) tv[k] = own ? tv[k + 1] : tv[k];
            tv[9] = own ? 0.0f : tv[9];
        }

        int dk = (int)isum;
        dk = dk < 1 ? 1 : (dk > 10 ? 10 : dk);
        if (ln < dk && mykey != U64MAX) {
            unsigned low = (unsigned)mykey;
            int a = (int)(low >> 11);
            int i2 = (int)(low & 2047);
            int idx = b * AA + a;
            if (atomicAdd(&matchcnt[idx], 1) == 0) {
                int wp = atomicAdd(wlcnt, 1);
                if (wp < CAPW)
                    ast_u64(&wl[wp], ((ull)(unsigned)((g << 16) | i2) << 32) | (unsigned)idx);
            }
        }
    }

    gbar(bar, 3 * nblk);

    // ---------------- phase 4: worklist loss + all-anchor obj BCE + finalize ------
    float t_fg = 0.0f, t_iou = 0.0f, t_obj = 0.0f, t_cls = 0.0f, t_l1 = 0.0f;

    if (blockIdx.x < K4GRID) {               // keep exact original partial grouping
        int gid = blockIdx.x * 256 + tid;
        int nw = __hip_atomic_load(wlcnt, __ATOMIC_RELAXED, __HIP_MEMORY_SCOPE_AGENT);
        nw = nw > CAPW ? CAPW : nw;

        for (int i = gid; i < BB * AA; i += K4GRID * 256)
            t_obj += softplus_bce(outputs[(size_t)i * NO + 4]);

        if (gid < nw) {
            int2 e = wl[gid];
            int idx = e.x;
            int b = idx / AA;
            int a = idx - b * AA;
            int ci = e.y & 0xFFFF;
            int g1 = e.y >> 16;
            int mcnt = matchcnt[idx];

            float4 pb = blist[b * CAP + ci];
            float4 gm = glist[b * CAP + ci];
            float2 mo = misc[b * CAP + ci];
            const float* Lb = labels + b * GG * 5;

            int mg;
            if (mcnt == 1) {
                mg = g1;
            } else {
                mg = 0; float best = FLT_MAX;
                for (int g = 0; g < GG; g++) {
                    float ct = clsterm[((size_t)b * GG + g) * CAP + ci];
                    float2 r = cost_iou(Lb[g * 5 + 1], Lb[g * 5 + 2], Lb[g * 5 + 3], Lb[g * 5 + 4],
                                        pb.x, pb.y, pb.z, pb.w, gm.x, gm.y, gm.z, ct, 1.0f);
                    if (r.x < best) { best = r.x; mg = g; }
                }
            }
            t_fg = 1.0f;
            t_obj += -mo.y;
            float gx = Lb[mg * 5 + 1], gy = Lb[mg * 5 + 2], gw = Lb[mg * 5 + 3], gh = Lb[mg * 5 + 4];
            int mcls = (int)Lb[mg * 5];
            float ctm = clsterm[((size_t)b * GG + mg) * CAP + ci];
            float2 r = cost_iou(gx, gy, gw, gh, pb.x, pb.y, pb.z, pb.w, gm.x, gm.y, gm.z, ctm, 1.0f);
            float pred_iou = r.y;
            float tlx = fmaxf(pb.x - pb.z * 0.5f, gx - gw * 0.5f);
            float tly = fmaxf(pb.y - pb.w * 0.5f, gy - gh * 0.5f);
            float brx = fminf(pb.x + pb.z * 0.5f, gx + gw * 0.5f);
            float bry = fminf(pb.y + pb.w * 0.5f, gy + gh * 0.5f);
            float en = (tlx < brx && tly < bry) ? 1.0f : 0.0f;
            float ai = (brx - tlx) * (bry - tly) * en;
            float iou = ai / (pb.z * pb.w + gw * gh - ai + 1e-16f);
            t_iou = 1.0f - iou * iou;
            const float* op = origin + (size_t)idx * 4;
            float stv = st_[a], xsv = xs_[a], ysv = ys_[a];
            t_l1 = fabsf(op[0] - (gx / stv - xsv)) + fabsf(op[1] - (gy / stv - ysv))
                 + fabsf(op[2] - logf(gw / stv + 1e-8f)) + fabsf(op[3] - logf(gh / stv + 1e-8f));
            t_cls = mo.x - outputs[(size_t)idx * NO + 5 + mcls] * pred_iou;
        }
    }

    t_fg = wave_sum(t_fg); t_iou = wave_sum(t_iou); t_obj = wave_sum(t_obj);
    t_cls = wave_sum(t_cls); t_l1 = wave_sum(t_l1);
    float (*red)[4] = reinterpret_cast<float(*)[4]>(s_red2);   // 80 B alias
    if (ln == 0) { red[0][w] = t_fg; red[1][w] = t_iou; red[2][w] = t_obj; red[3][w] = t_cls; red[4][w] = t_l1; }
    __syncthreads();
    if (tid == 0) {
        atomicAdd(&acc[0], red[0][0] + red[0][1] + red[0][2] + red[0][3]);
        atomicAdd(&acc[1], red[1][0] + red[1][1] + red[1][2] + red[1][3]);
        atomicAdd(&acc[2], red[2][0] + red[2][1] + red[2][2] + red[2][3]);
        atomicAdd(&acc[3], red[3][0] + red[3][1] + red[3][2] + red[3][3]);
        atomicAdd(&acc[4], red[4][0] + red[4][1] + red[4][2] + red[4][3]);
        __threadfence();
        int tkt = atomicAdd(fin, 1);
        if (tkt == nblk - 1) {
            float a0 = atomicAdd(&acc[0], 0.0f);
            float a1 = atomicAdd(&acc[1], 0.0f);
            float a2 = atomicAdd(&acc[2], 0.0f);
            float a3 = atomicAdd(&acc[3], 0.0f);
            float a4 = atomicAdd(&acc[4], 0.0f);
            float nfg = fmaxf(a0, 1.0f);
            float li = 5.0f * a1 / nfg;
            float lo = a2 / nfg;
            float lc = a3 / nfg;
            float ll = a4 / nfg;
            out[0] = li + lo + lc + ll;
            out[1] = li;
            out[2] = lo;
            out[3] = lc;
            out[4] = ll;
            out[5] = nfg / (float)(BB * GG);
        }
    }
}

// =====================================================================
// Legacy 4-kernel path (fallback if cooperative launch is unavailable)
// =====================================================================

__global__ __launch_bounds__(256) void k1a_fg(
    const float* __restrict__ labels,
    const float* __restrict__ xs_, const float* __restrict__ ys_, const float* __restrict__ st_,
    int* __restrict__ ctrl, int* __restrict__ matchcnt, int* __restrict__ alist)
{
    __shared__ float lgt[GG * 5];
    __shared__ int   lloc[256];
    __shared__ int   lcnt, sbase;

    int b = blockIdx.y;
    int tid = threadIdx.x, ln = tid & 63;
    int* cnt = ctrl + 8;

    if (tid == 0) atomicCAS((unsigned*)&cnt[b], POISON, 0u);
    if (blockIdx.x == 0 && b == 0 && tid < 48) atomicCAS((unsigned*)&ctrl[tid], POISON, 0u);
    if (tid == 0) lcnt = 0;

    int nb  = gridDim.x * gridDim.y;
    int bid = b * gridDim.x + blockIdx.x;
    for (int i = bid * 256 + tid; i < BB * AA; i += nb * 256) matchcnt[i] = 0;

    for (int i = tid; i < GG * 5; i += 256) lgt[i] = labels[b * GG * 5 + i];
    __syncthreads();

    int a = blockIdx.x * 256 + tid;
    bool fg = false;
    if (a < AA) {
        float stv = st_[a];
        float xc = __fmul_rn(__fadd_rn(xs_[a], 0.5f), stv);
        float yc = __fmul_rn(__fadd_rn(ys_[a], 0.5f), stv);
        float r  = __fmul_rn(1.5f, stv);
        for (int g = 0; g < GG && !fg; g++)
            fg = dev_in(lgt[g * 5 + 1], lgt[g * 5 + 2], xc, yc, r);
    }
    ull mk = __ballot(fg);
    int cw = __popcll(mk);
    int wbase = 0;
    if (ln == 0 && cw) wbase = atomicAdd(&lcnt, cw);
    wbase = __shfl(wbase, 0, 64);
    if (fg) lloc[wbase + __popcll(mk & ((1ull << ln) - 1ull))] = a;
    __syncthreads();
    if (tid == 0) sbase = atomicAdd(&cnt[b], lcnt);
    __syncthreads();
    int m = lcnt, base = sbase;
    for (int j = tid; j < m; j += 256)
        if (base + j < CAP) alist[b * CAP + base + j] = lloc[j];
}

__global__ __launch_bounds__(256) void k1b_cls(
    const float* __restrict__ outputs, const float* __restrict__ labels,
    const float* __restrict__ xs_, const float* __restrict__ ys_, const float* __restrict__ st_,
    const int* __restrict__ ctrl, const int* __restrict__ alist,
    float4* __restrict__ blist, float4* __restrict__ glist,
    float2* __restrict__ misc, float* __restrict__ clsterm)
{
    int b = blockIdx.y;
    int i0 = blockIdx.x * 64;
    int n = ctrl[8 + b]; n = n > CAP ? CAP : n;
    if (i0 >= n) return;

    __shared__ float rows[64 * NO];
    __shared__ float lgt[GG * 5];
    __shared__ int   arow[64];
    __shared__ float2 red2[4][64];

    int tid = threadIdx.x;
    int w = tid >> 6, ln = tid & 63;
    for (int t = tid; t < GG * 5; t += 256) lgt[t] = labels[b * GG * 5 + t];

    for (int rr = 0; rr < 16; rr++) {
        int row = i0 + w * 16 + rr;
        if (row < n) {
            int a = alist[b * CAP + row];
            const float* src = outputs + ((size_t)b * AA + a) * NO;
            int rl = w * 16 + rr;
            rows[rl * NO + ln] = src[ln];
            if (ln < NO - 64) rows[rl * NO + 64 + ln] = src[64 + ln];
            if (ln == 0) arow[rl] = a;
        }
    }
    __syncthreads();

    int il = ln;
    int i = i0 + il;
    bool valid = i < n;
    const float* R = rows + il * NO;
    float obj = R[4];

    float s1 = 0.0f, s2 = 0.0f;
    if (valid) {
        int c0 = w * 20;
#pragma unroll 4
        for (int j = 0; j < 20; j++) {
            float x = R[5 + c0 + j];
            float m = __fmul_rn(x, obj);
            float p = __fsqrt_rn(m);
            s1 += __logf(__fsub_rn(1.0f, p));
            s2 += softplus_bce(x);
        }
    }
    red2[w][il] = make_float2(s1, s2);
    __syncthreads();

    if (!valid) return;
    float s1t = red2[0][il].x + red2[1][il].x + red2[2][il].x + red2[3][il].x;
    float s2t = red2[0][il].y + red2[1][il].y + red2[2][il].y + red2[3][il].y;
    float nsl = -s1t;

    if (w == 0) {
        int a = arow[il];
        float stv = st_[a];
        float xc = __fmul_rn(__fadd_rn(xs_[a], 0.5f), stv);
        float yc = __fmul_rn(__fadd_rn(ys_[a], 0.5f), stv);
        float r  = __fmul_rn(1.5f, stv);
        blist[b * CAP + i] = make_float4(R[0], R[1], R[2], R[3]);
        glist[b * CAP + i] = make_float4(xc, yc, r, stv);
        misc[b * CAP + i]  = make_float2(s2t, obj);
    }
#pragma unroll
    for (int gi = 0; gi < 10; gi++) {
        int g = w * 10 + gi;
        int gc = (int)lgt[g * 5];
        float m = __fmul_rn(R[5 + gc], obj);
        float p = __fsqrt_rn(m);
        float term = __fsub_rn(__fmul_rn(0.5f, __logf(m)), __logf(__fsub_rn(1.0f, p)));
        clsterm[((size_t)b * GG + g) * CAP + i] = __fsub_rn(nsl, term);
    }
}

__global__ __launch_bounds__(256) void k2_assign(
    const float* __restrict__ labels,
    int* __restrict__ ctrl,
    const int* __restrict__ alist,
    const float4* __restrict__ blist, const float4* __restrict__ glist,
    const float* __restrict__ clsterm,
    int* __restrict__ matchcnt, int2* __restrict__ wl)
{
    int w = threadIdx.x >> 6, ln = threadIdx.x & 63;
    int pair = blockIdx.x * 4 + w;
    int b = pair / GG, g = pair - b * GG;
    int* cnt   = ctrl + 8;
    int* wlcnt = ctrl + 40;

    const float* L = labels + (b * GG + g) * 5;
    float gx = L[1], gy = L[2], gw = L[3], gh = L[4];
    int n = cnt[b]; n = n > CAP ? CAP : n;

    const float*  ctp = clsterm + ((size_t)b * GG + g) * CAP;
    const float4* bp  = blist + b * CAP;
    const float4* gp  = glist + b * CAP;
    const int*    ap  = alist + b * CAP;

    ull t[10]; float tv[10];
#pragma unroll
    for (int k = 0; k < 10; k++) { t[k] = U64MAX; tv[k] = 0.0f; }

    for (int i = ln; i < n; i += 64) {
        float4 pb = bp[i];
        float4 gm = gp[i];
        float2 ci = cost_iou(gx, gy, gw, gh, pb.x, pb.y, pb.z, pb.w,
                             gm.x, gm.y, gm.z, ctp[i], 1.0f);
        unsigned u = __float_as_uint(ci.x);
        u ^= (u & 0x80000000u) ? 0xFFFFFFFFu : 0x80000000u;
        ull key = ((ull)u << 32) | (unsigned)((ap[i] << 11) | i);
        if (key < t[9]) {
            int p = 0;
#pragma unroll
            for (int k = 0; k < 10; k++) p += (t[k] < key) ? 1 : 0;
#pragma unroll
            for (int k = 9; k >= 1; k--) t[k] = (k > p) ? t[k - 1] : t[k];
#pragma unroll
            for (int k = 0; k < 10; k++) if (k == p) t[k] = key;
        }
        float v = ci.y;
        if (v > tv[9]) {
            int p = 0;
#pragma unroll
            for (int k = 0; k < 10; k++) p += (tv[k] > v) ? 1 : 0;
#pragma unroll
            for (int k = 9; k >= 1; k--) tv[k] = (k > p) ? tv[k - 1] : tv[k];
#pragma unroll
            for (int k = 0; k < 10; k++) if (k == p) tv[k] = v;
        }
    }

    ull mykey = U64MAX;
#pragma unroll
    for (int r = 0; r < 10; r++) {
        ull mn = wave_min_u64(t[0]);
        if (ln == r) mykey = mn;
        bool own = (t[0] == mn);
#pragma unroll
        for (int k = 0; k < 9; k++) t[k] = own ? t[k + 1] : t[k];
        t[9] = own ? U64MAX : t[9];
    }
    float isum = 0.0f;
#pragma unroll
    for (int r = 0; r < 10; r++) {
        float mv = wave_max_f(tv[0]);
        isum += mv;
        ull bal = __ballot(tv[0] == mv);
        int first = (int)__ffsll((long long)bal) - 1;
        bool own = (ln == first);
#pragma unroll
        for (int k = 0; k < 9; k++) tv[k] = own ? tv[k + 1] : tv[k];
        tv[9] = own ? 0.0f : tv[9];
    }

    int dk = (int)isum;
    dk = dk < 1 ? 1 : (dk > 10 ? 10 : dk);
    if (ln < dk && mykey != U64MAX) {
        unsigned low = (unsigned)mykey;
        int a = (int)(low >> 11);
        int i2 = (int)(low & 2047);
        int idx = b * AA + a;
        if (atomicAdd(&matchcnt[idx], 1) == 0) {
            int wp = atomicAdd(wlcnt, 1);
            if (wp < CAPW) wl[wp] = make_int2(idx, (g << 16) | i2);
        }
    }
}

__global__ __launch_bounds__(256) void k4_loss(
    const float* __restrict__ outputs, const float* __restrict__ origin,
    const float* __restrict__ labels,
    const float* __restrict__ xs_, const float* __restrict__ ys_, const float* __restrict__ st_,
    const float4* __restrict__ blist, const float4* __restrict__ glist,
    const float2* __restrict__ misc, const float* __restrict__ clsterm,
    const int* __restrict__ matchcnt,
    const int2* __restrict__ wl, int* __restrict__ ctrl,
    float* __restrict__ out)
{
    float* acc = (float*)ctrl;
    int* wlcnt = ctrl + 40;
    int* fin   = ctrl + 41;

    int tid = threadIdx.x;
    int gid = blockIdx.x * 256 + tid;
    int nw = *wlcnt; nw = nw > CAPW ? CAPW : nw;

    float t_fg = 0.0f, t_iou = 0.0f, t_obj = 0.0f, t_cls = 0.0f, t_l1 = 0.0f;

    for (int i = gid; i < BB * AA; i += K4GRID * 256)
        t_obj += softplus_bce(outputs[(size_t)i * NO + 4]);

    if (gid < nw) {
        int2 e = wl[gid];
        int idx = e.x;
        int b = idx / AA;
        int a = idx - b * AA;
        int ci = e.y & 0xFFFF;
        int g1 = e.y >> 16;
        int mcnt = matchcnt[idx];

        float4 pb = blist[b * CAP + ci];
        float4 gm = glist[b * CAP + ci];
        float2 mo = misc[b * CAP + ci];
        const float* Lb = labels + b * GG * 5;

        int mg;
        if (mcnt == 1) {
            mg = g1;
        } else {
            mg = 0; float best = FLT_MAX;
            for (int g = 0; g < GG; g++) {
                float ct = clsterm[((size_t)b * GG + g) * CAP + ci];
                float2 r = cost_iou(Lb[g * 5 + 1], Lb[g * 5 + 2], Lb[g * 5 + 3], Lb[g * 5 + 4],
                                    pb.x, pb.y, pb.z, pb.w, gm.x, gm.y, gm.z, ct, 1.0f);
                if (r.x < best) { best = r.x; mg = g; }
            }
        }
        t_fg = 1.0f;
        t_obj += -mo.y;
        float gx = Lb[mg * 5 + 1], gy = Lb[mg * 5 + 2], gw = Lb[mg * 5 + 3], gh = Lb[mg * 5 + 4];
        int mcls = (int)Lb[mg * 5];
        float ctm = clsterm[((size_t)b * GG + mg) * CAP + ci];
        float2 r = cost_iou(gx, gy, gw, gh, pb.x, pb.y, pb.z, pb.w, gm.x, gm.y, gm.z, ctm, 1.0f);
        float pred_iou = r.y;
        float tlx = fmaxf(pb.x - pb.z * 0.5f, gx - gw * 0.5f);
        float tly = fmaxf(pb.y - pb.w * 0.5f, gy - gh * 0.5f);
        float brx = fminf(pb.x + pb.z * 0.5f, gx + gw * 0.5f);
        float bry = fminf(pb.y + pb.w * 0.5f, gy + gh * 0.5f);
        float en = (tlx < brx && tly < bry) ? 1.0f : 0.0f;
        float ai = (brx - tlx) * (bry - tly) * en;
        float iou = ai / (pb.z * pb.w + gw * gh - ai + 1e-16f);
        t_iou = 1.0f - iou * iou;
        const float* op = origin + (size_t)idx * 4;
        float stv = st_[a], xsv = xs_[a], ysv = ys_[a];
        t_l1 = fabsf(op[0] - (gx / stv - xsv)) + fabsf(op[1] - (gy / stv - ysv))
             + fabsf(op[2] - logf(gw / stv + 1e-8f)) + fabsf(op[3] - logf(gh / stv + 1e-8f));
        t_cls = mo.x - outputs[(size_t)idx * NO + 5 + mcls] * pred_iou;
    }

    t_fg = wave_sum(t_fg); t_iou = wave_sum(t_iou); t_obj = wave_sum(t_obj);
    t_cls = wave_sum(t_cls); t_l1 = wave_sum(t_l1);
    __shared__ float red[5][4];
    int wv = threadIdx.x >> 6, ln = threadIdx.x & 63;
    if (ln == 0) { red[0][wv] = t_fg; red[1][wv] = t_iou; red[2][wv] = t_obj; red[3][wv] = t_cls; red[4][wv] = t_l1; }
    __syncthreads();
    if (threadIdx.x == 0) {
        atomicAdd(&acc[0], red[0][0] + red[0][1] + red[0][2] + red[0][3]);
        atomicAdd(&acc[1], red[1][0] + red[1][1] + red[1][2] + red[1][3]);
        atomicAdd(&acc[2], red[2][0] + red[2][1] + red[2][2] + red[2][3]);
        atomicAdd(&acc[3], red[3][0] + red[3][1] + red[3][2] + red[3][3]);
        atomicAdd(&acc[4], red[4][0] + red[4][1] + red[4][2] + red[4][3]);
        __threadfence();
        int tkt = atomicAdd(fin, 1);
        if (tkt == (int)gridDim.x - 1) {
            float a0 = atomicAdd(&acc[0], 0.0f);
            float a1 = atomicAdd(&acc[1], 0.0f);
            float a2 = atomicAdd(&acc[2], 0.0f);
            float a3 = atomicAdd(&acc[3], 0.0f);
            float a4 = atomicAdd(&acc[4], 0.0f);
            float nfg = fmaxf(a0, 1.0f);
            float li = 5.0f * a1 / nfg;
            float lo = a2 / nfg;
            float lc = a3 / nfg;
            float ll = a4 / nfg;
            out[0] = li + lo + lc + ll;
            out[1] = li;
            out[2] = lo;
            out[3] = lc;
            out[4] = ll;
            out[5] = nfg / (float)(BB * GG);
        }
    }
}

// ---------- workspace layout (16B-aligned blocks) ----------
static constexpr size_t NBA       = (size_t)BB * AA;
static constexpr size_t OFF_MC    = 256;
static constexpr size_t OFF_ALIST = OFF_MC + NBA * 4;
static constexpr size_t OFF_BL    = OFF_ALIST + (size_t)BB * CAP * 4;
static constexpr size_t OFF_GL    = OFF_BL + (size_t)BB * CAP * 16;
static constexpr size_t OFF_MISC  = OFF_GL + (size_t)BB * CAP * 16;
static constexpr size_t OFF_CT    = OFF_MISC + (size_t)BB * CAP * 8;
static constexpr size_t OFF_WL    = OFF_CT + (size_t)BB * GG * CAP * 4;

extern "C" void kernel_launch(void* const* d_in, const int* in_sizes, int n_in,
                              void* d_out, int out_size, void* d_ws, size_t ws_size,
                              hipStream_t stream)
{
    (void)in_sizes; (void)n_in; (void)out_size; (void)ws_size;
    const float* outputs = (const float*)d_in[0];
    const float* origin  = (const float*)d_in[1];
    const float* labels  = (const float*)d_in[2];
    const float* xs_     = (const float*)d_in[3];
    const float* ys_     = (const float*)d_in[4];
    const float* st_     = (const float*)d_in[5];
    float* out = (float*)d_out;
    char* ws = (char*)d_ws;

    int*    ctrl     = (int*)(ws);
    int*    matchcnt = (int*)(ws + OFF_MC);
    int*    alist    = (int*)(ws + OFF_ALIST);
    float4* blist    = (float4*)(ws + OFF_BL);
    float4* glist    = (float4*)(ws + OFF_GL);
    float2* misc     = (float2*)(ws + OFF_MISC);
    float*  clsterm  = (float*)(ws + OFF_CT);
    int2*   wl       = (int2*)(ws + OFF_WL);

    void* args[] = {
        (void*)&outputs, (void*)&origin, (void*)&labels,
        (void*)&xs_, (void*)&ys_, (void*)&st_,
        (void*)&ctrl, (void*)&matchcnt, (void*)&alist,
        (void*)&blist, (void*)&glist, (void*)&misc, (void*)&clsterm,
        (void*)&wl, (void*)&out
    };
    // cooperative launch used ONLY for the co-residency guarantee; the kernel
    // uses a fence-free barrier + per-access agent-coherent stores (no bulk
    // L2 writeback/invalidate, which cost ~80us/sync in R2).
    hipError_t err = hipLaunchCooperativeKernel(fused, dim3(NBLK), dim3(256), args, 0, stream);

    if (err != hipSuccess) {
        // legacy 4-kernel fallback (identical math)
        dim3 grid1((AA + 255) / 256, BB);
        k1a_fg<<<grid1, 256, 0, stream>>>(labels, xs_, ys_, st_, ctrl, matchcnt, alist);

        dim3 grid1b(CAP / 64, BB);
        k1b_cls<<<grid1b, 256, 0, stream>>>(outputs, labels, xs_, ys_, st_, ctrl, alist,
                                            blist, glist, misc, clsterm);

        k2_assign<<<BB * GG / 4, 256, 0, stream>>>(labels, ctrl, alist, blist, glist, clsterm,
                                                   matchcnt, wl);

        k4_loss<<<K4GRID, 256, 0, stream>>>(outputs, origin, labels, xs_, ys_, st_,
                                            blist, glist, misc, clsterm, matchcnt, wl,
                                            ctrl, out);
    }
}

// Round 4
// 338.725 us; speedup vs baseline: 1.2980x; 1.1106x over previous
//
#include <hip/hip_runtime.h>
#include <cfloat>

#define BB 32
#define AA 8400
#define GG 40
#define NC 80
#define NO 85
#define CAP 2048    // >= geometric bound ~27 anchors/gt * 40 gts = 1080
#define CAPW 13312  // >= 1280 gts * dk_max 10 = 12800
#define POISON 0xAAAAAAAAu
#define K4GRID 104  // kept for exact phase-4 partial-sum grouping
#define GRP 10      // blocks per image group (10 blk x 4 waves = 40 = GG)
#define NBLK (BB * GRP)   // 320

typedef unsigned long long ull;
#define U64MAX 0xFFFFFFFFFFFFFFFFull

// ---------- deterministic helpers: explicit _rn ops (no FMA contraction) so every
// call site produces bitwise-identical values ----------

__device__ inline bool dev_in(float gx, float gy, float xc, float yc, float r)
{
    float dl = __fsub_rn(xc, __fsub_rn(gx, r));
    float dr = __fsub_rn(__fadd_rn(gx, r), xc);
    float dt = __fsub_rn(yc, __fsub_rn(gy, r));
    float db = __fsub_rn(__fadd_rn(gy, r), yc);
    return fminf(fminf(dl, dr), fminf(dt, db)) > 0.0f;
}

__device__ inline float2 cost_iou(float gx, float gy, float gw, float gh,
                                  float px, float py, float pw, float ph,
                                  float xc, float yc, float r,
                                  float ct, float fg)
{
    bool in = dev_in(gx, gy, xc, yc, r);
    float gw2 = __fmul_rn(gw, 0.5f), gh2 = __fmul_rn(gh, 0.5f);
    float pw2 = __fmul_rn(pw, 0.5f), ph2 = __fmul_rn(ph, 0.5f);
    float tlx = fmaxf(__fsub_rn(gx, gw2), __fsub_rn(px, pw2));
    float tly = fmaxf(__fsub_rn(gy, gh2), __fsub_rn(py, ph2));
    float brx = fminf(__fadd_rn(gx, gw2), __fadd_rn(px, pw2));
    float bry = fminf(__fadd_rn(gy, gh2), __fadd_rn(py, ph2));
    float en = (tlx < brx && tly < bry) ? 1.0f : 0.0f;
    float ai = __fmul_rn(__fmul_rn(__fsub_rn(brx, tlx), __fsub_rn(bry, tly)), en);
    float ag = __fmul_rn(gw, gh);
    float ap = __fmul_rn(pw, ph);
    float iou = ai / __fsub_rn(__fadd_rn(ag, ap), ai);
    iou = (fg != 0.0f) ? iou : 0.0f;
    float icost = -__logf(__fadd_rn(iou, 1e-8f));
    float cost = __fadd_rn(__fadd_rn(ct, __fmul_rn(3.0f, icost)), in ? 0.0f : 1000000.0f);
    cost = (fg != 0.0f) ? cost : 1000000000.0f;
    return make_float2(cost, iou);
}

__device__ inline float softplus_bce(float x)
{
    return fmaxf(x, 0.0f) + __logf(1.0f + __expf(-fabsf(x)));
}

__device__ inline float wave_sum(float v)
{
#pragma unroll
    for (int o = 32; o > 0; o >>= 1) v += __shfl_down(v, o, 64);
    return v;
}

__device__ inline ull wave_min_u64(ull v)
{
#pragma unroll
    for (int o = 1; o < 64; o <<= 1) {
        ull w = (ull)__shfl_xor((long long)v, o, 64);
        v = w < v ? w : v;
    }
    return v;
}

__device__ inline float wave_max_f(float v)
{
#pragma unroll
    for (int o = 1; o < 64; o <<= 1) v = fmaxf(v, __shfl_xor(v, o, 64));
    return v;
}

// ---------- per-access agent-coherent stores: bypass the XCD L2 so readers on
// other XCDs see the data WITHOUT any release/acquire bulk cache maintenance.
__device__ inline void ast_i32(void* p, int v)
{
    __hip_atomic_store((int*)p, v, __ATOMIC_RELAXED, __HIP_MEMORY_SCOPE_AGENT);
}
__device__ inline void ast_f32(float* p, float v)
{
    __hip_atomic_store(p, v, __ATOMIC_RELAXED, __HIP_MEMORY_SCOPE_AGENT);
}
__device__ inline void ast_u64(void* p, ull v)
{
    __hip_atomic_store((ull*)p, v, __ATOMIC_RELAXED, __HIP_MEMORY_SCOPE_AGENT);
}
__device__ inline ull pack_ff(float lo, float hi)
{
    return ((ull)__float_as_uint(hi) << 32) | (ull)__float_as_uint(lo);
}

// ---------- fence-free barrier (monotonic counter, leader poll, no fences).
// __syncthreads drains each wave's vmcnt before s_barrier, so all agent-coherent
// stores are at the coherence point before the leader's arrive.
__device__ inline void gbar(int* arr, int target)
{
    __syncthreads();
    if (threadIdx.x == 0) {
        __hip_atomic_fetch_add(arr, 1, __ATOMIC_RELAXED, __HIP_MEMORY_SCOPE_AGENT);
        int guard = 0;
        for (;;) {
            int v = __hip_atomic_load(arr, __ATOMIC_RELAXED, __HIP_MEMORY_SCOPE_AGENT);
            if (v >= target) break;
            __builtin_amdgcn_s_sleep(1);
            if (++guard > (1 << 22)) break;   // safety valve: fail visibly, not hang
        }
    }
    __syncthreads();
}

// ctrl layout (ints): [0..7]=acc(float), [8..39]=cnt[32], [40]=wlcnt, [41]=fin,
//                     [56]=gridbar, [64..95]=groupbar[32]   (ctrl area = 512 B)

// =====================================================================
// FUSED kernel, per-image group topology:
//   32 groups x 10 blocks. Per group: phase1(b) -> 10-blk bar -> phase2(b)
//   -> 10-blk bar -> phase3(b) [one (b,g) pair per wave] -> objBCE (blk<104)
//   -> ONE grid bar -> worklist loss -> commit.
// Math identical to the k1a/k1b/k2/k4 pipeline.
// =====================================================================
__global__ __launch_bounds__(256, 3) void fused(
    const float* __restrict__ outputs, const float* __restrict__ origin,
    const float* __restrict__ labels,
    const float* __restrict__ xs_, const float* __restrict__ ys_, const float* __restrict__ st_,
    int* __restrict__ ctrl, int* __restrict__ matchcnt, int* __restrict__ alist,
    float4* __restrict__ blist, float4* __restrict__ glist,
    float2* __restrict__ misc, float* __restrict__ clsterm,
    int2* __restrict__ wl, float* __restrict__ out)
{
    __shared__ float  s_rows[64 * NO];      // 21.8 KB (phase 2; aliased in 1)
    __shared__ float  s_lgt[GG * 5];        // this image's labels, loaded once
    __shared__ int    s_arow[64];
    __shared__ float2 s_red2[4][64];
    __shared__ int    s_cnt[2];             // lcnt, sbase

    int tid = threadIdx.x;
    int w = tid >> 6, ln = tid & 63;
    int gb = blockIdx.x / GRP;              // image owned by this block's group
    int gj = blockIdx.x - gb * GRP;         // block index within group (0..9)
    int* cnt   = ctrl + 8;
    int* wlcnt = ctrl + 40;
    int* fin   = ctrl + 41;
    int* gridb = ctrl + 56;
    int* grpb  = ctrl + 64 + gb;
    float* acc = (float*)ctrl;
    int nblk = gridDim.x;

    // ---- poison-safe init: every block CASes every ctrl word it will touch,
    //      BEFORE any use; __syncthreads drains the CASes.
    if (tid == 0) {
        atomicCAS((unsigned*)gridb, POISON, 0u);
        atomicCAS((unsigned*)grpb,  POISON, 0u);
        atomicCAS((unsigned*)&cnt[gb], POISON, 0u);
        atomicCAS((unsigned*)wlcnt, POISON, 0u);
        atomicCAS((unsigned*)fin,   POISON, 0u);
    }
    if (blockIdx.x == 0 && tid < 8) atomicCAS((unsigned*)&ctrl[tid], POISON, 0u);
    __syncthreads();

    // ---------------- phase 1: own-image matchcnt zero + fg compaction ----------
    for (int i = gj * 256 + tid; i < AA; i += GRP * 256)
        ast_i32(&matchcnt[gb * AA + i], 0);

    for (int i = tid; i < GG * 5; i += 256) s_lgt[i] = labels[gb * GG * 5 + i];

    const int GX1 = (AA + 255) / 256;       // 33
    int* lloc = (int*)s_rows;               // alias: phase-1 scratch
    for (int vb = gj; vb < GX1; vb += GRP) {
        if (tid == 0) s_cnt[0] = 0;
        __syncthreads();

        int a = vb * 256 + tid;
        bool fg = false;
        if (a < AA) {
            float stv = st_[a];
            float xc = __fmul_rn(__fadd_rn(xs_[a], 0.5f), stv);
            float yc = __fmul_rn(__fadd_rn(ys_[a], 0.5f), stv);
            float r  = __fmul_rn(1.5f, stv);
            for (int g = 0; g < GG && !fg; g++)
                fg = dev_in(s_lgt[g * 5 + 1], s_lgt[g * 5 + 2], xc, yc, r);
        }
        ull mk = __ballot(fg);
        int cw = __popcll(mk);
        int wbase = 0;
        if (ln == 0 && cw) wbase = atomicAdd(&s_cnt[0], cw);
        wbase = __shfl(wbase, 0, 64);
        if (fg) lloc[wbase + __popcll(mk & ((1ull << ln) - 1ull))] = a;
        __syncthreads();
        if (tid == 0) s_cnt[1] = atomicAdd(&cnt[gb], s_cnt[0]);
        __syncthreads();
        int m = s_cnt[0], base = s_cnt[1];
        for (int j = tid; j < m; j += 256)
            if (base + j < CAP) ast_i32(&alist[gb * CAP + base + j], lloc[j]);
        __syncthreads();   // protect shared reuse next virtual block
    }

    gbar(grpb, 1 * GRP);   // 10-block per-image barrier

    int n = __hip_atomic_load(&cnt[gb], __ATOMIC_RELAXED, __HIP_MEMORY_SCOPE_AGENT);
    n = n > CAP ? CAP : n;

    // ---------------- phase 2: fg rows -> class terms / compacted lists ----------
    const int GX2 = CAP / 64;               // 32
    for (int vb = gj; vb < GX2; vb += GRP) {
        int i0 = vb * 64;
        if (i0 < n) {                       // block-uniform predicate
            for (int rr = 0; rr < 16; rr++) {
                int row = i0 + w * 16 + rr;
                if (row < n) {
                    int a = __hip_atomic_load(&alist[gb * CAP + row], __ATOMIC_RELAXED,
                                              __HIP_MEMORY_SCOPE_AGENT);
                    const float* src = outputs + ((size_t)gb * AA + a) * NO;
                    int rl = w * 16 + rr;
                    s_rows[rl * NO + ln] = src[ln];
                    if (ln < NO - 64) s_rows[rl * NO + 64 + ln] = src[64 + ln];
                    if (ln == 0) s_arow[rl] = a;
                }
            }
            __syncthreads();

            int il = ln;
            int i = i0 + il;
            bool valid = i < n;
            const float* R = s_rows + il * NO;
            float obj = R[4];

            float s1 = 0.0f, s2 = 0.0f;
            if (valid) {
                int c0 = w * 20;
#pragma unroll 4
                for (int j = 0; j < 20; j++) {
                    float x = R[5 + c0 + j];
                    float m = __fmul_rn(x, obj);
                    float p = __fsqrt_rn(m);
                    s1 += __logf(__fsub_rn(1.0f, p));
                    s2 += softplus_bce(x);
                }
            }
            s_red2[w][il] = make_float2(s1, s2);
            __syncthreads();

            if (valid) {
                float s1t = s_red2[0][il].x + s_red2[1][il].x + s_red2[2][il].x + s_red2[3][il].x;
                float s2t = s_red2[0][il].y + s_red2[1][il].y + s_red2[2][il].y + s_red2[3][il].y;
                float nsl = -s1t;

                if (w == 0) {
                    int a = s_arow[il];
                    float stv = st_[a];
                    float xc = __fmul_rn(__fadd_rn(xs_[a], 0.5f), stv);
                    float yc = __fmul_rn(__fadd_rn(ys_[a], 0.5f), stv);
                    float r  = __fmul_rn(1.5f, stv);
                    float4* bl = &blist[gb * CAP + i];
                    ast_u64(bl, pack_ff(R[0], R[1]));
                    ast_u64((char*)bl + 8, pack_ff(R[2], R[3]));
                    float4* gl = &glist[gb * CAP + i];
                    ast_u64(gl, pack_ff(xc, yc));
                    ast_u64((char*)gl + 8, pack_ff(r, stv));
                    ast_u64(&misc[gb * CAP + i], pack_ff(s2t, obj));
                }
#pragma unroll
                for (int gi = 0; gi < 10; gi++) {
                    int g = w * 10 + gi;
                    int gc = (int)s_lgt[g * 5];
                    float m = __fmul_rn(R[5 + gc], obj);
                    float p = __fsqrt_rn(m);
                    float term = __fsub_rn(__fmul_rn(0.5f, __logf(m)), __logf(__fsub_rn(1.0f, p)));
                    ast_f32(&clsterm[((size_t)gb * GG + g) * CAP + i], __fsub_rn(nsl, term));
                }
            }
        }
        __syncthreads();   // protect shared reuse next virtual block
    }

    gbar(grpb, 2 * GRP);   // 10-block per-image barrier

    // ---------------- phase 3: SimOTA top-10, one (gb,g) pair per wave -----------
    {
        int g = gj * 4 + w;                 // 10 blocks x 4 waves = 40 = GG
        float gx = s_lgt[g * 5 + 1], gy = s_lgt[g * 5 + 2];
        float gw = s_lgt[g * 5 + 3], gh = s_lgt[g * 5 + 4];

        const float*  ctp = clsterm + ((size_t)gb * GG + g) * CAP;
        const float4* bp  = blist + gb * CAP;
        const float4* gp  = glist + gb * CAP;
        const int*    ap  = alist + gb * CAP;

        ull t[10]; float tv[10];
#pragma unroll
        for (int k = 0; k < 10; k++) { t[k] = U64MAX; tv[k] = 0.0f; }

        for (int i = ln; i < n; i += 64) {
            float4 pb = bp[i];
            float4 gm = gp[i];
            float2 ci = cost_iou(gx, gy, gw, gh, pb.x, pb.y, pb.z, pb.w,
                                 gm.x, gm.y, gm.z, ctp[i], 1.0f);
            unsigned u = __float_as_uint(ci.x);
            u ^= (u & 0x80000000u) ? 0xFFFFFFFFu : 0x80000000u;
            ull key = ((ull)u << 32) | (unsigned)((ap[i] << 11) | i);
            if (key < t[9]) {
                int p = 0;
#pragma unroll
                for (int k = 0; k < 10; k++) p += (t[k] < key) ? 1 : 0;
#pragma unroll
                for (int k = 9; k >= 1; k--) t[k] = (k > p) ? t[k - 1] : t[k];
#pragma unroll
                for (int k = 0; k < 10; k++) if (k == p) t[k] = key;
            }
            float v = ci.y;
            if (v > tv[9]) {
                int p = 0;
#pragma unroll
                for (int k = 0; k < 10; k++) p += (tv[k] > v) ? 1 : 0;
#pragma unroll
                for (int k = 9; k >= 1; k--) tv[k] = (k > p) ? tv[k - 1] : tv[k];
#pragma unroll
                for (int k = 0; k < 10; k++) if (k == p) tv[k] = v;
            }
        }

        ull mykey = U64MAX;
#pragma unroll
        for (int r = 0; r < 10; r++) {
            ull mn = wave_min_u64(t[0]);
            if (ln == r) mykey = mn;
            bool own = (t[0] == mn);
#pragma unroll
            for (int k = 0; k < 9; k++) t[k] = own ? t[k + 1] : t[k];
            t[9] = own ? U64MAX : t[9];
        }
        float isum = 0.0f;
#pragma unroll
        for (int r = 0; r < 10; r++) {
            float mv = wave_max_f(tv[0]);
            isum += mv;
            ull bal = __ballot(tv[0] == mv);
            int first = (int)__ffsll((long long)bal) - 1;
            bool own = (ln == first);
#pragma unroll
            for (int k = 0; k < 9; k++) tv[k] = own ? tv[k + 1] : tv[k];
            tv[9] = own ? 0.0f : tv[9];
        }

        int dk = (int)isum;
        dk = dk < 1 ? 1 : (dk > 10 ? 10 : dk);
        if (ln < dk && mykey != U64MAX) {
            unsigned low = (unsigned)mykey;
            int a = (int)(low >> 11);
            int i2 = (int)(low & 2047);
            int idx = gb * AA + a;
            if (atomicAdd(&matchcnt[idx], 1) == 0) {
                int wp = atomicAdd(wlcnt, 1);
                if (wp < CAPW)
                    ast_u64(&wl[wp], ((ull)(unsigned)((g << 16) | i2) << 32) | (unsigned)idx);
            }
        }
    }

    // ---------------- barrier-independent all-anchor obj BCE (overlaps stragglers)
    float t_fg = 0.0f, t_iou = 0.0f, t_obj = 0.0f, t_cls = 0.0f, t_l1 = 0.0f;
    int gid = blockIdx.x * 256 + tid;

    if (blockIdx.x < K4GRID) {               // keep exact original partial grouping
        for (int i = gid; i < BB * AA; i += K4GRID * 256)
            t_obj += softplus_bce(outputs[(size_t)i * NO + 4]);
    }

    gbar(gridb, nblk);   // the ONE grid-wide barrier (worklist completeness)

    // ---------------- phase 4: worklist loss + ticket finalize --------------------
    if (blockIdx.x < K4GRID) {
        int nw = __hip_atomic_load(wlcnt, __ATOMIC_RELAXED, __HIP_MEMORY_SCOPE_AGENT);
        nw = nw > CAPW ? CAPW : nw;

        if (gid < nw) {
            int2 e = wl[gid];
            int idx = e.x;
            int b = idx / AA;
            int a = idx - b * AA;
            int ci = e.y & 0xFFFF;
            int g1 = e.y >> 16;
            int mcnt = matchcnt[idx];

            float4 pb = blist[b * CAP + ci];
            float4 gm = glist[b * CAP + ci];
            float2 mo = misc[b * CAP + ci];
            const float* Lb = labels + b * GG * 5;

            int mg;
            if (mcnt == 1) {
                mg = g1;
            } else {
                mg = 0; float best = FLT_MAX;
                for (int g = 0; g < GG; g++) {
                    float ct = clsterm[((size_t)b * GG + g) * CAP + ci];
                    float2 r = cost_iou(Lb[g * 5 + 1], Lb[g * 5 + 2], Lb[g * 5 + 3], Lb[g * 5 + 4],
                                        pb.x, pb.y, pb.z, pb.w, gm.x, gm.y, gm.z, ct, 1.0f);
                    if (r.x < best) { best = r.x; mg = g; }
                }
            }
            t_fg = 1.0f;
            t_obj += -mo.y;
            float gx = Lb[mg * 5 + 1], gy = Lb[mg * 5 + 2], gw = Lb[mg * 5 + 3], gh = Lb[mg * 5 + 4];
            int mcls = (int)Lb[mg * 5];
            float ctm = clsterm[((size_t)b * GG + mg) * CAP + ci];
            float2 r = cost_iou(gx, gy, gw, gh, pb.x, pb.y, pb.z, pb.w, gm.x, gm.y, gm.z, ctm, 1.0f);
            float pred_iou = r.y;
            float tlx = fmaxf(pb.x - pb.z * 0.5f, gx - gw * 0.5f);
            float tly = fmaxf(pb.y - pb.w * 0.5f, gy - gh * 0.5f);
            float brx = fminf(pb.x + pb.z * 0.5f, gx + gw * 0.5f);
            float bry = fminf(pb.y + pb.w * 0.5f, gy + gh * 0.5f);
            float en = (tlx < brx && tly < bry) ? 1.0f : 0.0f;
            float ai = (brx - tlx) * (bry - tly) * en;
            float iou = ai / (pb.z * pb.w + gw * gh - ai + 1e-16f);
            t_iou = 1.0f - iou * iou;
            const float* op = origin + (size_t)idx * 4;
            float stv = st_[a], xsv = xs_[a], ysv = ys_[a];
            t_l1 = fabsf(op[0] - (gx / stv - xsv)) + fabsf(op[1] - (gy / stv - ysv))
                 + fabsf(op[2] - logf(gw / stv + 1e-8f)) + fabsf(op[3] - logf(gh / stv + 1e-8f));
            t_cls = mo.x - outputs[(size_t)idx * NO + 5 + mcls] * pred_iou;
        }
    }

    t_fg = wave_sum(t_fg); t_iou = wave_sum(t_iou); t_obj = wave_sum(t_obj);
    t_cls = wave_sum(t_cls); t_l1 = wave_sum(t_l1);
    float (*red)[4] = reinterpret_cast<float(*)[4]>(s_red2);   // 80 B alias
    if (ln == 0) { red[0][w] = t_fg; red[1][w] = t_iou; red[2][w] = t_obj; red[3][w] = t_cls; red[4][w] = t_l1; }
    __syncthreads();
    if (tid == 0) {
        atomicAdd(&acc[0], red[0][0] + red[0][1] + red[0][2] + red[0][3]);
        atomicAdd(&acc[1], red[1][0] + red[1][1] + red[1][2] + red[1][3]);
        atomicAdd(&acc[2], red[2][0] + red[2][1] + red[2][2] + red[2][3]);
        atomicAdd(&acc[3], red[3][0] + red[3][1] + red[3][2] + red[3][3]);
        atomicAdd(&acc[4], red[4][0] + red[4][1] + red[4][2] + red[4][3]);
        __threadfence();
        int tkt = atomicAdd(fin, 1);
        if (tkt == nblk - 1) {
            float a0 = atomicAdd(&acc[0], 0.0f);
            float a1 = atomicAdd(&acc[1], 0.0f);
            float a2 = atomicAdd(&acc[2], 0.0f);
            float a3 = atomicAdd(&acc[3], 0.0f);
            float a4 = atomicAdd(&acc[4], 0.0f);
            float nfg = fmaxf(a0, 1.0f);
            float li = 5.0f * a1 / nfg;
            float lo = a2 / nfg;
            float lc = a3 / nfg;
            float ll = a4 / nfg;
            out[0] = li + lo + lc + ll;
            out[1] = li;
            out[2] = lo;
            out[3] = lc;
            out[4] = ll;
            out[5] = nfg / (float)(BB * GG);
        }
    }
}

// =====================================================================
// Legacy 4-kernel path (fallback if cooperative launch is unavailable)
// =====================================================================

__global__ __launch_bounds__(256) void k1a_fg(
    const float* __restrict__ labels,
    const float* __restrict__ xs_, const float* __restrict__ ys_, const float* __restrict__ st_,
    int* __restrict__ ctrl, int* __restrict__ matchcnt, int* __restrict__ alist)
{
    __shared__ float lgt[GG * 5];
    __shared__ int   lloc[256];
    __shared__ int   lcnt, sbase;

    int b = blockIdx.y;
    int tid = threadIdx.x, ln = tid & 63;
    int* cnt = ctrl + 8;

    if (tid == 0) atomicCAS((unsigned*)&cnt[b], POISON, 0u);
    if (blockIdx.x == 0 && b == 0 && tid < 48) atomicCAS((unsigned*)&ctrl[tid], POISON, 0u);
    if (tid == 0) lcnt = 0;

    int nb  = gridDim.x * gridDim.y;
    int bid = b * gridDim.x + blockIdx.x;
    for (int i = bid * 256 + tid; i < BB * AA; i += nb * 256) matchcnt[i] = 0;

    for (int i = tid; i < GG * 5; i += 256) lgt[i] = labels[b * GG * 5 + i];
    __syncthreads();

    int a = blockIdx.x * 256 + tid;
    bool fg = false;
    if (a < AA) {
        float stv = st_[a];
        float xc = __fmul_rn(__fadd_rn(xs_[a], 0.5f), stv);
        float yc = __fmul_rn(__fadd_rn(ys_[a], 0.5f), stv);
        float r  = __fmul_rn(1.5f, stv);
        for (int g = 0; g < GG && !fg; g++)
            fg = dev_in(lgt[g * 5 + 1], lgt[g * 5 + 2], xc, yc, r);
    }
    ull mk = __ballot(fg);
    int cw = __popcll(mk);
    int wbase = 0;
    if (ln == 0 && cw) wbase = atomicAdd(&lcnt, cw);
    wbase = __shfl(wbase, 0, 64);
    if (fg) lloc[wbase + __popcll(mk & ((1ull << ln) - 1ull))] = a;
    __syncthreads();
    if (tid == 0) sbase = atomicAdd(&cnt[b], lcnt);
    __syncthreads();
    int m = lcnt, base = sbase;
    for (int j = tid; j < m; j += 256)
        if (base + j < CAP) alist[b * CAP + base + j] = lloc[j];
}

__global__ __launch_bounds__(256) void k1b_cls(
    const float* __restrict__ outputs, const float* __restrict__ labels,
    const float* __restrict__ xs_, const float* __restrict__ ys_, const float* __restrict__ st_,
    const int* __restrict__ ctrl, const int* __restrict__ alist,
    float4* __restrict__ blist, float4* __restrict__ glist,
    float2* __restrict__ misc, float* __restrict__ clsterm)
{
    int b = blockIdx.y;
    int i0 = blockIdx.x * 64;
    int n = ctrl[8 + b]; n = n > CAP ? CAP : n;
    if (i0 >= n) return;

    __shared__ float rows[64 * NO];
    __shared__ float lgt[GG * 5];
    __shared__ int   arow[64];
    __shared__ float2 red2[4][64];

    int tid = threadIdx.x;
    int w = tid >> 6, ln = tid & 63;
    for (int t = tid; t < GG * 5; t += 256) lgt[t] = labels[b * GG * 5 + t];

    for (int rr = 0; rr < 16; rr++) {
        int row = i0 + w * 16 + rr;
        if (row < n) {
            int a = alist[b * CAP + row];
            const float* src = outputs + ((size_t)b * AA + a) * NO;
            int rl = w * 16 + rr;
            rows[rl * NO + ln] = src[ln];
            if (ln < NO - 64) rows[rl * NO + 64 + ln] = src[64 + ln];
            if (ln == 0) arow[rl] = a;
        }
    }
    __syncthreads();

    int il = ln;
    int i = i0 + il;
    bool valid = i < n;
    const float* R = rows + il * NO;
    float obj = R[4];

    float s1 = 0.0f, s2 = 0.0f;
    if (valid) {
        int c0 = w * 20;
#pragma unroll 4
        for (int j = 0; j < 20; j++) {
            float x = R[5 + c0 + j];
            float m = __fmul_rn(x, obj);
            float p = __fsqrt_rn(m);
            s1 += __logf(__fsub_rn(1.0f, p));
            s2 += softplus_bce(x);
        }
    }
    red2[w][il] = make_float2(s1, s2);
    __syncthreads();

    if (!valid) return;
    float s1t = red2[0][il].x + red2[1][il].x + red2[2][il].x + red2[3][il].x;
    float s2t = red2[0][il].y + red2[1][il].y + red2[2][il].y + red2[3][il].y;
    float nsl = -s1t;

    if (w == 0) {
        int a = arow[il];
        float stv = st_[a];
        float xc = __fmul_rn(__fadd_rn(xs_[a], 0.5f), stv);
        float yc = __fmul_rn(__fadd_rn(ys_[a], 0.5f), stv);
        float r  = __fmul_rn(1.5f, stv);
        blist[b * CAP + i] = make_float4(R[0], R[1], R[2], R[3]);
        glist[b * CAP + i] = make_float4(xc, yc, r, stv);
        misc[b * CAP + i]  = make_float2(s2t, obj);
    }
#pragma unroll
    for (int gi = 0; gi < 10; gi++) {
        int g = w * 10 + gi;
        int gc = (int)lgt[g * 5];
        float m = __fmul_rn(R[5 + gc], obj);
        float p = __fsqrt_rn(m);
        float term = __fsub_rn(__fmul_rn(0.5f, __logf(m)), __logf(__fsub_rn(1.0f, p)));
        clsterm[((size_t)b * GG + g) * CAP + i] = __fsub_rn(nsl, term);
    }
}

__global__ __launch_bounds__(256) void k2_assign(
    const float* __restrict__ labels,
    int* __restrict__ ctrl,
    const int* __restrict__ alist,
    const float4* __restrict__ blist, const float4* __restrict__ glist,
    const float* __restrict__ clsterm,
    int* __restrict__ matchcnt, int2* __restrict__ wl)
{
    int w = threadIdx.x >> 6, ln = threadIdx.x & 63;
    int pair = blockIdx.x * 4 + w;
    int b = pair / GG, g = pair - b * GG;
    int* cnt   = ctrl + 8;
    int* wlcnt = ctrl + 40;

    const float* L = labels + (b * GG + g) * 5;
    float gx = L[1], gy = L[2], gw = L[3], gh = L[4];
    int n = cnt[b]; n = n > CAP ? CAP : n;

    const float*  ctp = clsterm + ((size_t)b * GG + g) * CAP;
    const float4* bp  = blist + b * CAP;
    const float4* gp  = glist + b * CAP;
    const int*    ap  = alist + b * CAP;

    ull t[10]; float tv[10];
#pragma unroll
    for (int k = 0; k < 10; k++) { t[k] = U64MAX; tv[k] = 0.0f; }

    for (int i = ln; i < n; i += 64) {
        float4 pb = bp[i];
        float4 gm = gp[i];
        float2 ci = cost_iou(gx, gy, gw, gh, pb.x, pb.y, pb.z, pb.w,
                             gm.x, gm.y, gm.z, ctp[i], 1.0f);
        unsigned u = __float_as_uint(ci.x);
        u ^= (u & 0x80000000u) ? 0xFFFFFFFFu : 0x80000000u;
        ull key = ((ull)u << 32) | (unsigned)((ap[i] << 11) | i);
        if (key < t[9]) {
            int p = 0;
#pragma unroll
            for (int k = 0; k < 10; k++) p += (t[k] < key) ? 1 : 0;
#pragma unroll
            for (int k = 9; k >= 1; k--) t[k] = (k > p) ? t[k - 1] : t[k];
#pragma unroll
            for (int k = 0; k < 10; k++) if (k == p) t[k] = key;
        }
        float v = ci.y;
        if (v > tv[9]) {
            int p = 0;
#pragma unroll
            for (int k = 0; k < 10; k++) p += (tv[k] > v) ? 1 : 0;
#pragma unroll
            for (int k = 9; k >= 1; k--) tv[k] = (k > p) ? tv[k - 1] : tv[k];
#pragma unroll
            for (int k = 0; k < 10; k++) if (k == p) tv[k] = v;
        }
    }

    ull mykey = U64MAX;
#pragma unroll
    for (int r = 0; r < 10; r++) {
        ull mn = wave_min_u64(t[0]);
        if (ln == r) mykey = mn;
        bool own = (t[0] == mn);
#pragma unroll
        for (int k = 0; k < 9; k++) t[k] = own ? t[k + 1] : t[k];
        t[9] = own ? U64MAX : t[9];
    }
    float isum = 0.0f;
#pragma unroll
    for (int r = 0; r < 10; r++) {
        float mv = wave_max_f(tv[0]);
        isum += mv;
        ull bal = __ballot(tv[0] == mv);
        int first = (int)__ffsll((long long)bal) - 1;
        bool own = (ln == first);
#pragma unroll
        for (int k = 0; k < 9; k++) tv[k] = own ? tv[k + 1] : tv[k];
        tv[9] = own ? 0.0f : tv[9];
    }

    int dk = (int)isum;
    dk = dk < 1 ? 1 : (dk > 10 ? 10 : dk);
    if (ln < dk && mykey != U64MAX) {
        unsigned low = (unsigned)mykey;
        int a = (int)(low >> 11);
        int i2 = (int)(low & 2047);
        int idx = b * AA + a;
        if (atomicAdd(&matchcnt[idx], 1) == 0) {
            int wp = atomicAdd(wlcnt, 1);
            if (wp < CAPW) wl[wp] = make_int2(idx, (g << 16) | i2);
        }
    }
}

__global__ __launch_bounds__(256) void k4_loss(
    const float* __restrict__ outputs, const float* __restrict__ origin,
    const float* __restrict__ labels,
    const float* __restrict__ xs_, const float* __restrict__ ys_, const float* __restrict__ st_,
    const float4* __restrict__ blist, const float4* __restrict__ glist,
    const float2* __restrict__ misc, const float* __restrict__ clsterm,
    const int* __restrict__ matchcnt,
    const int2* __restrict__ wl, int* __restrict__ ctrl,
    float* __restrict__ out)
{
    float* acc = (float*)ctrl;
    int* wlcnt = ctrl + 40;
    int* fin   = ctrl + 41;

    int tid = threadIdx.x;
    int gid = blockIdx.x * 256 + tid;
    int nw = *wlcnt; nw = nw > CAPW ? CAPW : nw;

    float t_fg = 0.0f, t_iou = 0.0f, t_obj = 0.0f, t_cls = 0.0f, t_l1 = 0.0f;

    for (int i = gid; i < BB * AA; i += K4GRID * 256)
        t_obj += softplus_bce(outputs[(size_t)i * NO + 4]);

    if (gid < nw) {
        int2 e = wl[gid];
        int idx = e.x;
        int b = idx / AA;
        int a = idx - b * AA;
        int ci = e.y & 0xFFFF;
        int g1 = e.y >> 16;
        int mcnt = matchcnt[idx];

        float4 pb = blist[b * CAP + ci];
        float4 gm = glist[b * CAP + ci];
        float2 mo = misc[b * CAP + ci];
        const float* Lb = labels + b * GG * 5;

        int mg;
        if (mcnt == 1) {
            mg = g1;
        } else {
            mg = 0; float best = FLT_MAX;
            for (int g = 0; g < GG; g++) {
                float ct = clsterm[((size_t)b * GG + g) * CAP + ci];
                float2 r = cost_iou(Lb[g * 5 + 1], Lb[g * 5 + 2], Lb[g * 5 + 3], Lb[g * 5 + 4],
                                    pb.x, pb.y, pb.z, pb.w, gm.x, gm.y, gm.z, ct, 1.0f);
                if (r.x < best) { best = r.x; mg = g; }
            }
        }
        t_fg = 1.0f;
        t_obj += -mo.y;
        float gx = Lb[mg * 5 + 1], gy = Lb[mg * 5 + 2], gw = Lb[mg * 5 + 3], gh = Lb[mg * 5 + 4];
        int mcls = (int)Lb[mg * 5];
        float ctm = clsterm[((size_t)b * GG + mg) * CAP + ci];
        float2 r = cost_iou(gx, gy, gw, gh, pb.x, pb.y, pb.z, pb.w, gm.x, gm.y, gm.z, ctm, 1.0f);
        float pred_iou = r.y;
        float tlx = fmaxf(pb.x - pb.z * 0.5f, gx - gw * 0.5f);
        float tly = fmaxf(pb.y - pb.w * 0.5f, gy - gh * 0.5f);
        float brx = fminf(pb.x + pb.z * 0.5f, gx + gw * 0.5f);
        float bry = fminf(pb.y + pb.w * 0.5f, gy + gh * 0.5f);
        float en = (tlx < brx && tly < bry) ? 1.0f : 0.0f;
        float ai = (brx - tlx) * (bry - tly) * en;
        float iou = ai / (pb.z * pb.w + gw * gh - ai + 1e-16f);
        t_iou = 1.0f - iou * iou;
        const float* op = origin + (size_t)idx * 4;
        float stv = st_[a], xsv = xs_[a], ysv = ys_[a];
        t_l1 = fabsf(op[0] - (gx / stv - xsv)) + fabsf(op[1] - (gy / stv - ysv))
             + fabsf(op[2] - logf(gw / stv + 1e-8f)) + fabsf(op[3] - logf(gh / stv + 1e-8f));
        t_cls = mo.x - outputs[(size_t)idx * NO + 5 + mcls] * pred_iou;
    }

    t_fg = wave_sum(t_fg); t_iou = wave_sum(t_iou); t_obj = wave_sum(t_obj);
    t_cls = wave_sum(t_cls); t_l1 = wave_sum(t_l1);
    __shared__ float red[5][4];
    int wv = threadIdx.x >> 6, ln = threadIdx.x & 63;
    if (ln == 0) { red[0][wv] = t_fg; red[1][wv] = t_iou; red[2][wv] = t_obj; red[3][wv] = t_cls; red[4][wv] = t_l1; }
    __syncthreads();
    if (threadIdx.x == 0) {
        atomicAdd(&acc[0], red[0][0] + red[0][1] + red[0][2] + red[0][3]);
        atomicAdd(&acc[1], red[1][0] + red[1][1] + red[1][2] + red[1][3]);
        atomicAdd(&acc[2], red[2][0] + red[2][1] + red[2][2] + red[2][3]);
        atomicAdd(&acc[3], red[3][0] + red[3][1] + red[3][2] + red[3][3]);
        atomicAdd(&acc[4], red[4][0] + red[4][1] + red[4][2] + red[4][3]);
        __threadfence();
        int tkt = atomicAdd(fin, 1);
        if (tkt == (int)gridDim.x - 1) {
            float a0 = atomicAdd(&acc[0], 0.0f);
            float a1 = atomicAdd(&acc[1], 0.0f);
            float a2 = atomicAdd(&acc[2], 0.0f);
            float a3 = atomicAdd(&acc[3], 0.0f);
            float a4 = atomicAdd(&acc[4], 0.0f);
            float nfg = fmaxf(a0, 1.0f);
            float li = 5.0f * a1 / nfg;
            float lo = a2 / nfg;
            float lc = a3 / nfg;
            float ll = a4 / nfg;
            out[0] = li + lo + lc + ll;
            out[1] = li;
            out[2] = lo;
            out[3] = lc;
            out[4] = ll;
            out[5] = nfg / (float)(BB * GG);
        }
    }
}

// ---------- workspace layout (16B-aligned blocks; ctrl area widened to 512 B) -----
static constexpr size_t NBA       = (size_t)BB * AA;
static constexpr size_t OFF_MC    = 512;
static constexpr size_t OFF_ALIST = OFF_MC + NBA * 4;
static constexpr size_t OFF_BL    = OFF_ALIST + (size_t)BB * CAP * 4;
static constexpr size_t OFF_GL    = OFF_BL + (size_t)BB * CAP * 16;
static constexpr size_t OFF_MISC  = OFF_GL + (size_t)BB * CAP * 16;
static constexpr size_t OFF_CT    = OFF_MISC + (size_t)BB * CAP * 8;
static constexpr size_t OFF_WL    = OFF_CT + (size_t)BB * GG * CAP * 4;

extern "C" void kernel_launch(void* const* d_in, const int* in_sizes, int n_in,
                              void* d_out, int out_size, void* d_ws, size_t ws_size,
                              hipStream_t stream)
{
    (void)in_sizes; (void)n_in; (void)out_size; (void)ws_size;
    const float* outputs = (const float*)d_in[0];
    const float* origin  = (const float*)d_in[1];
    const float* labels  = (const float*)d_in[2];
    const float* xs_     = (const float*)d_in[3];
    const float* ys_     = (const float*)d_in[4];
    const float* st_     = (const float*)d_in[5];
    float* out = (float*)d_out;
    char* ws = (char*)d_ws;

    int*    ctrl     = (int*)(ws);
    int*    matchcnt = (int*)(ws + OFF_MC);
    int*    alist    = (int*)(ws + OFF_ALIST);
    float4* blist    = (float4*)(ws + OFF_BL);
    float4* glist    = (float4*)(ws + OFF_GL);
    float2* misc     = (float2*)(ws + OFF_MISC);
    float*  clsterm  = (float*)(ws + OFF_CT);
    int2*   wl       = (int2*)(ws + OFF_WL);

    void* args[] = {
        (void*)&outputs, (void*)&origin, (void*)&labels,
        (void*)&xs_, (void*)&ys_, (void*)&st_,
        (void*)&ctrl, (void*)&matchcnt, (void*)&alist,
        (void*)&blist, (void*)&glist, (void*)&misc, (void*)&clsterm,
        (void*)&wl, (void*)&out
    };
    // cooperative launch used ONLY for the co-residency guarantee; the kernel
    // uses per-image 10-block barriers + ONE fence-free grid barrier.
    hipError_t err = hipLaunchCooperativeKernel(fused, dim3(NBLK), dim3(256), args, 0, stream);

    if (err != hipSuccess) {
        // legacy 4-kernel fallback (identical math)
        dim3 grid1((AA + 255) / 256, BB);
        k1a_fg<<<grid1, 256, 0, stream>>>(labels, xs_, ys_, st_, ctrl, matchcnt, alist);

        dim3 grid1b(CAP / 64, BB);
        k1b_cls<<<grid1b, 256, 0, stream>>>(outputs, labels, xs_, ys_, st_, ctrl, alist,
                                            blist, glist, misc, clsterm);

        k2_assign<<<BB * GG / 4, 256, 0, stream>>>(labels, ctrl, alist, blist, glist, clsterm,
                                                   matchcnt, wl);

        k4_loss<<<K4GRID, 256, 0, stream>>>(outputs, origin, labels, xs_, ys_, st_,
                                            blist, glist, misc, clsterm, matchcnt, wl,
                                            ctrl, out);
    }
}

// Round 5
// 246.015 us; speedup vs baseline: 1.7871x; 1.3768x over previous
//
#include <hip/hip_runtime.h>
#include <cfloat>

#define BB 32
#define AA 8400
#define GG 40
#define NC 80
#define NO 85
#define CAP 2048    // >= geometric bound ~27 anchors/gt * 40 gts = 1080
#define CAPW 13312  // >= 1280 gts * dk_max 10 = 12800
#define POISON 0xAAAAAAAAu
#define K4GRID 104  // fixed: defines the exact phase-4 partial-sum grouping

typedef unsigned long long ull;
#define U64MAX 0xFFFFFFFFFFFFFFFFull

// ---------- deterministic helpers: explicit _rn ops (no FMA contraction) so every
// call site produces bitwise-identical values ----------

__device__ inline bool dev_in(float gx, float gy, float xc, float yc, float r)
{
    float dl = __fsub_rn(xc, __fsub_rn(gx, r));
    float dr = __fsub_rn(__fadd_rn(gx, r), xc);
    float dt = __fsub_rn(yc, __fsub_rn(gy, r));
    float db = __fsub_rn(__fadd_rn(gy, r), yc);
    return fminf(fminf(dl, dr), fminf(dt, db)) > 0.0f;
}

__device__ inline float2 cost_iou(float gx, float gy, float gw, float gh,
                                  float px, float py, float pw, float ph,
                                  float xc, float yc, float r,
                                  float ct, float fg)
{
    bool in = dev_in(gx, gy, xc, yc, r);
    float gw2 = __fmul_rn(gw, 0.5f), gh2 = __fmul_rn(gh, 0.5f);
    float pw2 = __fmul_rn(pw, 0.5f), ph2 = __fmul_rn(ph, 0.5f);
    float tlx = fmaxf(__fsub_rn(gx, gw2), __fsub_rn(px, pw2));
    float tly = fmaxf(__fsub_rn(gy, gh2), __fsub_rn(py, ph2));
    float brx = fminf(__fadd_rn(gx, gw2), __fadd_rn(px, pw2));
    float bry = fminf(__fadd_rn(gy, gh2), __fadd_rn(py, ph2));
    float en = (tlx < brx && tly < bry) ? 1.0f : 0.0f;
    float ai = __fmul_rn(__fmul_rn(__fsub_rn(brx, tlx), __fsub_rn(bry, tly)), en);
    float ag = __fmul_rn(gw, gh);
    float ap = __fmul_rn(pw, ph);
    float iou = ai / __fsub_rn(__fadd_rn(ag, ap), ai);
    iou = (fg != 0.0f) ? iou : 0.0f;
    float icost = -__logf(__fadd_rn(iou, 1e-8f));
    float cost = __fadd_rn(__fadd_rn(ct, __fmul_rn(3.0f, icost)), in ? 0.0f : 1000000.0f);
    cost = (fg != 0.0f) ? cost : 1000000000.0f;
    return make_float2(cost, iou);
}

__device__ inline float softplus_bce(float x)
{
    return fmaxf(x, 0.0f) + __logf(1.0f + __expf(-fabsf(x)));
}

__device__ inline float wave_sum(float v)
{
#pragma unroll
    for (int o = 32; o > 0; o >>= 1) v += __shfl_down(v, o, 64);
    return v;
}

__device__ inline ull wave_min_u64(ull v)
{
#pragma unroll
    for (int o = 1; o < 64; o <<= 1) {
        ull w = (ull)__shfl_xor((long long)v, o, 64);
        v = w < v ? w : v;
    }
    return v;
}

__device__ inline float wave_max_f(float v)
{
#pragma unroll
    for (int o = 1; o < 64; o <<= 1) v = fmaxf(v, __shfl_xor(v, o, 64));
    return v;
}

// ctrl layout (ints): [0..7]=acc(float), [8..39]=cnt[32], [40]=wlcnt, [41]=fin

// =====================================================================
// K1: merged k1a+k1b. Each block: ctrl init + matchcnt zero + fg-test its
// 256 anchors + compact (atomic base into cnt[b]) + IMMEDIATELY process its
// own fg rows (class terms, compacted lists) from LDS — no alist re-read,
// no second kernel boundary. alist order is nondeterministic but all
// downstream selections are permutation-invariant (keys embed anchor id).
// =====================================================================
__global__ __launch_bounds__(256) void k1_fgcls(
    const float* __restrict__ outputs, const float* __restrict__ labels,
    const float* __restrict__ xs_, const float* __restrict__ ys_, const float* __restrict__ st_,
    int* __restrict__ ctrl, int* __restrict__ matchcnt, int* __restrict__ alist,
    float4* __restrict__ blist, float4* __restrict__ glist,
    float2* __restrict__ misc, float* __restrict__ clsterm)
{
    __shared__ float  rows[64 * NO];   // 21.8 KB
    __shared__ float  lgt[GG * 5];
    __shared__ int    lloc[256];       // this block's fg anchors (separate from rows!)
    __shared__ int    arow[64];
    __shared__ float2 red2[4][64];
    __shared__ int    scnt[2];         // lcnt, base

    int b = blockIdx.y;
    int tid = threadIdx.x, w = tid >> 6, ln = tid & 63;
    int* cnt = ctrl + 8;

    // poison->0 init: 1 CAS/block on this image's counter; block(0,0) covers ctrl[0..47]
    if (tid == 0) atomicCAS((unsigned*)&cnt[b], POISON, 0u);
    if (blockIdx.x == 0 && b == 0 && tid < 48) atomicCAS((unsigned*)&ctrl[tid], POISON, 0u);
    if (tid == 0) scnt[0] = 0;

    int nb  = gridDim.x * gridDim.y;
    int bid = b * gridDim.x + blockIdx.x;
    for (int i = bid * 256 + tid; i < BB * AA; i += nb * 256) matchcnt[i] = 0;

    for (int i = tid; i < GG * 5; i += 256) lgt[i] = labels[b * GG * 5 + i];
    __syncthreads();

    // ---- fg test + block-local compaction ----
    int a = blockIdx.x * 256 + tid;
    bool fg = false;
    float stv = 0.0f, xc = 0.0f, yc = 0.0f, rr_ = 0.0f;
    if (a < AA) {
        stv = st_[a];
        xc = __fmul_rn(__fadd_rn(xs_[a], 0.5f), stv);
        yc = __fmul_rn(__fadd_rn(ys_[a], 0.5f), stv);
        rr_ = __fmul_rn(1.5f, stv);
        for (int g = 0; g < GG && !fg; g++)
            fg = dev_in(lgt[g * 5 + 1], lgt[g * 5 + 2], xc, yc, rr_);
    }
    ull mk = __ballot(fg);
    int cw = __popcll(mk);
    int wbase = 0;
    if (ln == 0 && cw) wbase = atomicAdd(&scnt[0], cw);
    wbase = __shfl(wbase, 0, 64);
    if (fg) lloc[wbase + __popcll(mk & ((1ull << ln) - 1ull))] = a;
    __syncthreads();
    if (tid == 0) scnt[1] = atomicAdd(&cnt[b], scnt[0]);
    __syncthreads();
    int m = scnt[0], base = scnt[1];

    // ---- process this block's own fg rows (formerly k1b) ----
    int nbatch = (m + 63) >> 6;
    for (int bb = 0; bb < nbatch; bb++) {
        // stage 64 rows (16 per wave)
        for (int rr = 0; rr < 16; rr++) {
            int lr = w * 16 + rr;
            int j = bb * 64 + lr;
            if (j < m) {
                int aa = lloc[j];
                const float* src = outputs + ((size_t)b * AA + aa) * NO;
                rows[lr * NO + ln] = src[ln];
                if (ln < NO - 64) rows[lr * NO + 64 + ln] = src[64 + ln];
                if (ln == 0) arow[lr] = aa;
            }
        }
        __syncthreads();

        int il = ln;
        int j = bb * 64 + il;
        bool valid = j < m;
        const float* R = rows + il * NO;
        float obj = R[4];

        float s1 = 0.0f, s2 = 0.0f;
        if (valid) {
            int c0 = w * 20;
#pragma unroll 4
            for (int jj = 0; jj < 20; jj++) {
                float x = R[5 + c0 + jj];
                float mm = __fmul_rn(x, obj);
                float p = __fsqrt_rn(mm);
                s1 += __logf(__fsub_rn(1.0f, p));                       // log1p(-p)
                s2 += softplus_bce(x);                                  // cls BCE base
            }
        }
        red2[w][il] = make_float2(s1, s2);
        __syncthreads();

        if (valid) {
            int i = base + j;
            if (i < CAP) {
                float s1t = red2[0][il].x + red2[1][il].x + red2[2][il].x + red2[3][il].x;
                float s2t = red2[0][il].y + red2[1][il].y + red2[2][il].y + red2[3][il].y;
                float nsl = -s1t;

                if (w == 0) {
                    int aa = arow[il];
                    float stv2 = st_[aa];
                    float xc2 = __fmul_rn(__fadd_rn(xs_[aa], 0.5f), stv2);
                    float yc2 = __fmul_rn(__fadd_rn(ys_[aa], 0.5f), stv2);
                    float r2  = __fmul_rn(1.5f, stv2);
                    alist[b * CAP + i] = aa;
                    blist[b * CAP + i] = make_float4(R[0], R[1], R[2], R[3]);
                    glist[b * CAP + i] = make_float4(xc2, yc2, r2, stv2);
                    misc[b * CAP + i]  = make_float2(s2t, obj);
                }
#pragma unroll
                for (int gi = 0; gi < 10; gi++) {
                    int g = w * 10 + gi;
                    int gc = (int)lgt[g * 5];
                    float mm = __fmul_rn(R[5 + gc], obj);
                    float p = __fsqrt_rn(mm);
                    float term = __fsub_rn(__fmul_rn(0.5f, __logf(mm)), __logf(__fsub_rn(1.0f, p)));
                    clsterm[((size_t)b * GG + g) * CAP + i] = __fsub_rn(nsl, term);  // coalesced in i
                }
            }
        }
        __syncthreads();   // protect rows/red2 reuse next batch
    }
}

// =====================================================================
// K2: SimOTA top-10 assignment — 2 waves per (b,g) pair (2x TLP of the
// 1-wave version), deterministic 20-candidate rank merge in LDS.
// Produces bitwise-identical top-10 keys / isum / dk / commits.
// =====================================================================
__global__ __launch_bounds__(256) void k2_assign(
    const float* __restrict__ labels,
    int* __restrict__ ctrl,
    const int* __restrict__ alist,
    const float4* __restrict__ blist, const float4* __restrict__ glist,
    const float* __restrict__ clsterm,
    int* __restrict__ matchcnt, int2* __restrict__ wl)
{
    __shared__ ull   skey[2][20];
    __shared__ float sval[2][20];

    int w = threadIdx.x >> 6, ln = threadIdx.x & 63;
    int pairLocal = w >> 1;            // 0..1 : two pairs per block
    int half = w & 1;                  // 0..1 : two waves per pair
    int pair = blockIdx.x * 2 + pairLocal;   // < BB*GG = 1280
    int b = pair / GG, g = pair - b * GG;
    int* cnt   = ctrl + 8;
    int* wlcnt = ctrl + 40;

    const float* L = labels + (b * GG + g) * 5;
    float gx = L[1], gy = L[2], gw = L[3], gh = L[4];
    int n = cnt[b]; n = n > CAP ? CAP : n;

    const float*  ctp = clsterm + ((size_t)b * GG + g) * CAP;
    const float4* bp  = blist + b * CAP;
    const float4* gp  = glist + b * CAP;
    const int*    ap  = alist + b * CAP;

    ull t[10]; float tv[10];
#pragma unroll
    for (int k = 0; k < 10; k++) { t[k] = U64MAX; tv[k] = 0.0f; }

    // this wave scans its half: lanes ln + half*64, stride 128
    for (int i = ln + half * 64; i < n; i += 128) {
        float4 pb = bp[i];
        float4 gm = gp[i];
        float2 ci = cost_iou(gx, gy, gw, gh, pb.x, pb.y, pb.z, pb.w,
                             gm.x, gm.y, gm.z, ctp[i], 1.0f);
        unsigned u = __float_as_uint(ci.x);
        u ^= (u & 0x80000000u) ? 0xFFFFFFFFu : 0x80000000u;
        ull key = ((ull)u << 32) | (unsigned)((ap[i] << 11) | i);
        if (key < t[9]) {
            int p = 0;
#pragma unroll
            for (int k = 0; k < 10; k++) p += (t[k] < key) ? 1 : 0;
#pragma unroll
            for (int k = 9; k >= 1; k--) t[k] = (k > p) ? t[k - 1] : t[k];
#pragma unroll
            for (int k = 0; k < 10; k++) if (k == p) t[k] = key;
        }
        float v = ci.y;
        if (v > tv[9]) {
            int p = 0;
#pragma unroll
            for (int k = 0; k < 10; k++) p += (tv[k] > v) ? 1 : 0;
#pragma unroll
            for (int k = 9; k >= 1; k--) tv[k] = (k > p) ? tv[k - 1] : tv[k];
#pragma unroll
            for (int k = 0; k < 10; k++) if (k == p) tv[k] = v;
        }
    }

    // per-wave sorted extraction: lane r<10 ends holding r-th smallest key / r-th largest value
    ull mykey = U64MAX; float myv = 0.0f;
#pragma unroll
    for (int r = 0; r < 10; r++) {
        ull mn = wave_min_u64(t[0]);
        if (ln == r) mykey = mn;
        bool own = (t[0] == mn);
#pragma unroll
        for (int k = 0; k < 9; k++) t[k] = own ? t[k + 1] : t[k];
        t[9] = own ? U64MAX : t[9];
    }
#pragma unroll
    for (int r = 0; r < 10; r++) {
        float mv = wave_max_f(tv[0]);
        if (ln == r) myv = mv;
        ull bal = __ballot(tv[0] == mv);
        int first = (int)__ffsll((long long)bal) - 1;
        bool own = (ln == first);
#pragma unroll
        for (int k = 0; k < 9; k++) tv[k] = own ? tv[k + 1] : tv[k];
        tv[9] = own ? 0.0f : tv[9];
    }

    if (ln < 10) { skey[pairLocal][half * 10 + ln] = mykey; sval[pairLocal][half * 10 + ln] = myv; }
    __syncthreads();

    // deterministic 20-candidate merge (all waves compute; half 0 commits)
    ull  kc = (ln < 20) ? skey[pairLocal][ln] : U64MAX;
    float vc = (ln < 20) ? sval[pairLocal][ln] : -1.0f;

    int krank = 0, vrank = 0;
#pragma unroll
    for (int j = 0; j < 20; j++) {
        ull kj = (ull)__shfl((long long)kc, j, 64);
        float vj = __shfl(vc, j, 64);
        krank += (kj < kc) ? 1 : 0;                                // keys distinct
        vrank += ((vj > vc) || (vj == vc && j < ln)) ? 1 : 0;      // stable by index
    }

    ull mykey2 = U64MAX;
    float isum = 0.0f;
#pragma unroll
    for (int r = 0; r < 10; r++) {
        ull balk = __ballot(ln < 20 && krank == r);
        int srck = (int)__ffsll((long long)balk) - 1;
        ull kr = (ull)__shfl((long long)kc, srck, 64);
        if (ln == r && srck >= 0) mykey2 = kr;

        ull balv = __ballot(ln < 20 && vrank == r);
        int srcv = (int)__ffsll((long long)balv) - 1;
        float vr = __shfl(vc, srcv, 64);
        isum += (srcv >= 0) ? vr : 0.0f;                           // descending order sum
    }

    int dk = (int)isum;
    dk = dk < 1 ? 1 : (dk > 10 ? 10 : dk);
    if (half == 0 && ln < dk && mykey2 != U64MAX) {
        unsigned low = (unsigned)mykey2;
        int a = (int)(low >> 11);
        int i2 = (int)(low & 2047);
        int idx = b * AA + a;
        if (atomicAdd(&matchcnt[idx], 1) == 0) {
            int wp = atomicAdd(wlcnt, 1);
            if (wp < CAPW) wl[wp] = make_int2(idx, (g << 16) | i2);
        }
    }
}

// =====================================================================
// K4: worklist loss + grid-stride all-anchor obj-BCE + ticket finalize.
// obj gather now explicitly batches its 10-11 strided loads into registers
// (same ascending summation order -> bitwise identical) for 11-deep MLP.
// =====================================================================
__global__ __launch_bounds__(256) void k4_loss(
    const float* __restrict__ outputs, const float* __restrict__ origin,
    const float* __restrict__ labels,
    const float* __restrict__ xs_, const float* __restrict__ ys_, const float* __restrict__ st_,
    const float4* __restrict__ blist, const float4* __restrict__ glist,
    const float2* __restrict__ misc, const float* __restrict__ clsterm,
    const int* __restrict__ matchcnt,
    const int2* __restrict__ wl, int* __restrict__ ctrl,
    float* __restrict__ out)
{
    float* acc = (float*)ctrl;
    int* wlcnt = ctrl + 40;
    int* fin   = ctrl + 41;

    int tid = threadIdx.x;
    int gid = blockIdx.x * 256 + tid;
    int nw = *wlcnt; nw = nw > CAPW ? CAPW : nw;

    float t_fg = 0.0f, t_iou = 0.0f, t_obj = 0.0f, t_cls = 0.0f, t_l1 = 0.0f;

    // all-anchor objectness BCE base: batch loads first (11-deep MLP), then
    // sum in the SAME ascending-k order as the original grid-stride loop.
    {
        const int STR = K4GRID * 256;    // 26624
        float xv[11];
        int kmax = 0;
#pragma unroll
        for (int k = 0; k < 11; k++) {
            int idx = gid + k * STR;
            if (idx < BB * AA) { xv[k] = outputs[(size_t)idx * NO + 4]; kmax = k + 1; }
        }
#pragma unroll
        for (int k = 0; k < 11; k++)
            if (k < kmax) t_obj += softplus_bce(xv[k]);
    }

    if (gid < nw) {
        int2 e = wl[gid];
        int idx = e.x;
        int b = idx / AA;
        int a = idx - b * AA;
        int ci = e.y & 0xFFFF;
        int g1 = e.y >> 16;
        int mcnt = matchcnt[idx];

        float4 pb = blist[b * CAP + ci];
        float4 gm = glist[b * CAP + ci];
        float2 mo = misc[b * CAP + ci];
        const float* Lb = labels + b * GG * 5;

        int mg;
        if (mcnt == 1) {
            mg = g1;
        } else {
            mg = 0; float best = FLT_MAX;
            for (int g = 0; g < GG; g++) {
                float ct = clsterm[((size_t)b * GG + g) * CAP + ci];
                float2 r = cost_iou(Lb[g * 5 + 1], Lb[g * 5 + 2], Lb[g * 5 + 3], Lb[g * 5 + 4],
                                    pb.x, pb.y, pb.z, pb.w, gm.x, gm.y, gm.z, ct, 1.0f);
                if (r.x < best) { best = r.x; mg = g; }
            }
        }
        t_fg = 1.0f;
        t_obj += -mo.y;   // BCE(x,1)-BCE(x,0)
        float gx = Lb[mg * 5 + 1], gy = Lb[mg * 5 + 2], gw = Lb[mg * 5 + 3], gh = Lb[mg * 5 + 4];
        int mcls = (int)Lb[mg * 5];
        float ctm = clsterm[((size_t)b * GG + mg) * CAP + ci];
        float2 r = cost_iou(gx, gy, gw, gh, pb.x, pb.y, pb.z, pb.w, gm.x, gm.y, gm.z, ctm, 1.0f);
        float pred_iou = r.y;
        float tlx = fmaxf(pb.x - pb.z * 0.5f, gx - gw * 0.5f);
        float tly = fmaxf(pb.y - pb.w * 0.5f, gy - gh * 0.5f);
        float brx = fminf(pb.x + pb.z * 0.5f, gx + gw * 0.5f);
        float bry = fminf(pb.y + pb.w * 0.5f, gy + gh * 0.5f);
        float en = (tlx < brx && tly < bry) ? 1.0f : 0.0f;
        float ai = (brx - tlx) * (bry - tly) * en;
        float iou = ai / (pb.z * pb.w + gw * gh - ai + 1e-16f);
        t_iou = 1.0f - iou * iou;
        const float* op = origin + (size_t)idx * 4;
        float stv = st_[a], xsv = xs_[a], ysv = ys_[a];
        t_l1 = fabsf(op[0] - (gx / stv - xsv)) + fabsf(op[1] - (gy / stv - ysv))
             + fabsf(op[2] - logf(gw / stv + 1e-8f)) + fabsf(op[3] - logf(gh / stv + 1e-8f));
        t_cls = mo.x - outputs[(size_t)idx * NO + 5 + mcls] * pred_iou;
    }

    t_fg = wave_sum(t_fg); t_iou = wave_sum(t_iou); t_obj = wave_sum(t_obj);
    t_cls = wave_sum(t_cls); t_l1 = wave_sum(t_l1);
    __shared__ float red[5][4];
    int wv = threadIdx.x >> 6, ln = threadIdx.x & 63;
    if (ln == 0) { red[0][wv] = t_fg; red[1][wv] = t_iou; red[2][wv] = t_obj; red[3][wv] = t_cls; red[4][wv] = t_l1; }
    __syncthreads();
    if (threadIdx.x == 0) {
        atomicAdd(&acc[0], red[0][0] + red[0][1] + red[0][2] + red[0][3]);
        atomicAdd(&acc[1], red[1][0] + red[1][1] + red[1][2] + red[1][3]);
        atomicAdd(&acc[2], red[2][0] + red[2][1] + red[2][2] + red[2][3]);
        atomicAdd(&acc[3], red[3][0] + red[3][1] + red[3][2] + red[3][3]);
        atomicAdd(&acc[4], red[4][0] + red[4][1] + red[4][2] + red[4][3]);
        __threadfence();
        int tkt = atomicAdd(fin, 1);
        if (tkt == (int)gridDim.x - 1) {
            float a0 = atomicAdd(&acc[0], 0.0f);
            float a1 = atomicAdd(&acc[1], 0.0f);
            float a2 = atomicAdd(&acc[2], 0.0f);
            float a3 = atomicAdd(&acc[3], 0.0f);
            float a4 = atomicAdd(&acc[4], 0.0f);
            float nfg = fmaxf(a0, 1.0f);
            float li = 5.0f * a1 / nfg;
            float lo = a2 / nfg;
            float lc = a3 / nfg;
            float ll = a4 / nfg;
            out[0] = li + lo + lc + ll;
            out[1] = li;
            out[2] = lo;
            out[3] = lc;
            out[4] = ll;
            out[5] = nfg / (float)(BB * GG);
        }
    }
}

// ---------- workspace layout (16B-aligned blocks) ----------
static constexpr size_t NBA       = (size_t)BB * AA;                 // 268800
static constexpr size_t OFF_MC    = 512;                             // ctrl first
static constexpr size_t OFF_ALIST = OFF_MC + NBA * 4;
static constexpr size_t OFF_BL    = OFF_ALIST + (size_t)BB * CAP * 4;
static constexpr size_t OFF_GL    = OFF_BL + (size_t)BB * CAP * 16;
static constexpr size_t OFF_MISC  = OFF_GL + (size_t)BB * CAP * 16;
static constexpr size_t OFF_CT    = OFF_MISC + (size_t)BB * CAP * 8;
static constexpr size_t OFF_WL    = OFF_CT + (size_t)BB * GG * CAP * 4;
// total = OFF_WL + CAPW*8 ≈ 15 MB

extern "C" void kernel_launch(void* const* d_in, const int* in_sizes, int n_in,
                              void* d_out, int out_size, void* d_ws, size_t ws_size,
                              hipStream_t stream)
{
    (void)in_sizes; (void)n_in; (void)out_size; (void)ws_size;
    const float* outputs = (const float*)d_in[0];
    const float* origin  = (const float*)d_in[1];
    const float* labels  = (const float*)d_in[2];
    const float* xs_     = (const float*)d_in[3];
    const float* ys_     = (const float*)d_in[4];
    const float* st_     = (const float*)d_in[5];
    float* out = (float*)d_out;
    char* ws = (char*)d_ws;

    int*    ctrl     = (int*)(ws);
    int*    matchcnt = (int*)(ws + OFF_MC);
    int*    alist    = (int*)(ws + OFF_ALIST);
    float4* blist    = (float4*)(ws + OFF_BL);
    float4* glist    = (float4*)(ws + OFF_GL);
    float2* misc     = (float2*)(ws + OFF_MISC);
    float*  clsterm  = (float*)(ws + OFF_CT);
    int2*   wl       = (int2*)(ws + OFF_WL);

    // K1: merged fg-compaction + class-term kernel (4.1 waves/SIMD)
    dim3 grid1((AA + 255) / 256, BB);   // 33 x 32
    k1_fgcls<<<grid1, 256, 0, stream>>>(outputs, labels, xs_, ys_, st_,
                                        ctrl, matchcnt, alist,
                                        blist, glist, misc, clsterm);

    // K2: 2 waves per (b,g) pair -> 640 blocks (2.5 waves/SIMD)
    k2_assign<<<BB * GG / 2, 256, 0, stream>>>(labels, ctrl, alist, blist, glist, clsterm,
                                               matchcnt, wl);

    // K4: unchanged partition (K4GRID=104), MLP-batched obj gather
    k4_loss<<<K4GRID, 256, 0, stream>>>(outputs, origin, labels, xs_, ys_, st_,
                                        blist, glist, misc, clsterm, matchcnt, wl,
                                        ctrl, out);
}

// Round 6
// 228.553 us; speedup vs baseline: 1.9237x; 1.0764x over previous
//
#include <hip/hip_runtime.h>
#include <cfloat>

#define BB 32
#define AA 8400
#define GG 40
#define NC 80
#define NO 85
#define CAP 2048    // >= geometric bound ~27 anchors/gt * 40 gts = 1080
#define CAPW 13312  // >= 1280 gts * dk_max 10 = 12800
#define POISON 0xAAAAAAAAu
#define K4GRID 104  // fixed: defines the exact phase-4 partial-sum grouping

typedef unsigned long long ull;
#define U64MAX 0xFFFFFFFFFFFFFFFFull

// ---------- deterministic helpers: explicit _rn ops (no FMA contraction) so every
// call site produces bitwise-identical values ----------

__device__ inline bool dev_in(float gx, float gy, float xc, float yc, float r)
{
    float dl = __fsub_rn(xc, __fsub_rn(gx, r));
    float dr = __fsub_rn(__fadd_rn(gx, r), xc);
    float dt = __fsub_rn(yc, __fsub_rn(gy, r));
    float db = __fsub_rn(__fadd_rn(gy, r), yc);
    return fminf(fminf(dl, dr), fminf(dt, db)) > 0.0f;
}

__device__ inline float2 cost_iou(float gx, float gy, float gw, float gh,
                                  float px, float py, float pw, float ph,
                                  float xc, float yc, float r,
                                  float ct, float fg)
{
    bool in = dev_in(gx, gy, xc, yc, r);
    float gw2 = __fmul_rn(gw, 0.5f), gh2 = __fmul_rn(gh, 0.5f);
    float pw2 = __fmul_rn(pw, 0.5f), ph2 = __fmul_rn(ph, 0.5f);
    float tlx = fmaxf(__fsub_rn(gx, gw2), __fsub_rn(px, pw2));
    float tly = fmaxf(__fsub_rn(gy, gh2), __fsub_rn(py, ph2));
    float brx = fminf(__fadd_rn(gx, gw2), __fadd_rn(px, pw2));
    float bry = fminf(__fadd_rn(gy, gh2), __fadd_rn(py, ph2));
    float en = (tlx < brx && tly < bry) ? 1.0f : 0.0f;
    float ai = __fmul_rn(__fmul_rn(__fsub_rn(brx, tlx), __fsub_rn(bry, tly)), en);
    float ag = __fmul_rn(gw, gh);
    float ap = __fmul_rn(pw, ph);
    float iou = ai / __fsub_rn(__fadd_rn(ag, ap), ai);
    iou = (fg != 0.0f) ? iou : 0.0f;
    float icost = -__logf(__fadd_rn(iou, 1e-8f));
    float cost = __fadd_rn(__fadd_rn(ct, __fmul_rn(3.0f, icost)), in ? 0.0f : 1000000.0f);
    cost = (fg != 0.0f) ? cost : 1000000000.0f;
    return make_float2(cost, iou);
}

__device__ inline float softplus_bce(float x)
{
    return fmaxf(x, 0.0f) + __logf(1.0f + __expf(-fabsf(x)));
}

__device__ inline float wave_sum(float v)
{
#pragma unroll
    for (int o = 32; o > 0; o >>= 1) v += __shfl_down(v, o, 64);
    return v;
}

__device__ inline ull wave_min_u64(ull v)
{
#pragma unroll
    for (int o = 1; o < 64; o <<= 1) {
        ull w = (ull)__shfl_xor((long long)v, o, 64);
        v = w < v ? w : v;
    }
    return v;
}

__device__ inline float wave_max_f(float v)
{
#pragma unroll
    for (int o = 1; o < 64; o <<= 1) v = fmaxf(v, __shfl_xor(v, o, 64));
    return v;
}

// ctrl layout (ints): [0..7]=acc(float), [8..39]=cnt[32], [40]=wlcnt, [41]=fin

// =====================================================================
// K1: fg compaction + class terms, SYNCLESS phase 2.
// Phase 1: fg-test this block's 256 anchors, compact into lloc, atomic
//   base into cnt[b] (same as R5 — alist content identical).
// Phase 2: one 4-lane group owns one row. Lane q computes classes
//   q*20..q*20+19 in the SAME serial order as the old thread (w=q, ln=row);
//   partials combined left-to-right via 4 shfls -> bitwise-identical s1t/s2t.
//   Rows read directly from global (no LDS staging, no __syncthreads) so
//   waves stream independently -> no straggler convoy, high MLP.
// =====================================================================
__global__ __launch_bounds__(256) void k1_fgcls(
    const float* __restrict__ outputs, const float* __restrict__ labels,
    const float* __restrict__ xs_, const float* __restrict__ ys_, const float* __restrict__ st_,
    int* __restrict__ ctrl, int* __restrict__ matchcnt, int* __restrict__ alist,
    float4* __restrict__ blist, float4* __restrict__ glist,
    float2* __restrict__ misc, float* __restrict__ clsterm)
{
    __shared__ float lgt[GG * 5];
    __shared__ int   lloc[256];
    __shared__ int   scnt[2];          // lcnt, base

    int b = blockIdx.y;
    int tid = threadIdx.x, w = tid >> 6, ln = tid & 63;
    int* cnt = ctrl + 8;

    // poison->0 init: 1 CAS/block on this image's counter; block(0,0) covers ctrl[0..47]
    if (tid == 0) atomicCAS((unsigned*)&cnt[b], POISON, 0u);
    if (blockIdx.x == 0 && b == 0 && tid < 48) atomicCAS((unsigned*)&ctrl[tid], POISON, 0u);
    if (tid == 0) scnt[0] = 0;

    int nb  = gridDim.x * gridDim.y;
    int bid = b * gridDim.x + blockIdx.x;
    for (int i = bid * 256 + tid; i < BB * AA; i += nb * 256) matchcnt[i] = 0;

    for (int i = tid; i < GG * 5; i += 256) lgt[i] = labels[b * GG * 5 + i];
    __syncthreads();

    // ---- phase 1: fg test + block-local compaction ----
    int a = blockIdx.x * 256 + tid;
    bool fg = false;
    if (a < AA) {
        float stv = st_[a];
        float xc = __fmul_rn(__fadd_rn(xs_[a], 0.5f), stv);
        float yc = __fmul_rn(__fadd_rn(ys_[a], 0.5f), stv);
        float rr = __fmul_rn(1.5f, stv);
        for (int g = 0; g < GG && !fg; g++)
            fg = dev_in(lgt[g * 5 + 1], lgt[g * 5 + 2], xc, yc, rr);
    }
    ull mk = __ballot(fg);
    int cw = __popcll(mk);
    int wbase = 0;
    if (ln == 0 && cw) wbase = atomicAdd(&scnt[0], cw);
    wbase = __shfl(wbase, 0, 64);
    if (fg) lloc[wbase + __popcll(mk & ((1ull << ln) - 1ull))] = a;
    __syncthreads();
    if (tid == 0) scnt[1] = atomicAdd(&cnt[b], scnt[0]);
    __syncthreads();
    int m = scnt[0], base = scnt[1];

    // ---- phase 2: syncless, 4 lanes per row, 16 rows per wave per pass ----
    int g16 = ln >> 2;                 // row group within wave (0..15)
    int q   = ln & 3;                  // class-quarter (replaces old wave index w)
    int lb  = ln & ~3;                 // group base lane for ordered shfl combine

    for (int p = 0; p * 64 + w * 16 < m; p++) {
        int j = p * 64 + w * 16 + g16;
        bool valid = j < m;
        int aa = valid ? lloc[j] : 0;
        const float* src = outputs + ((size_t)b * AA + aa) * NO;

        float obj = 0.0f, s1 = 0.0f, s2 = 0.0f;
        if (valid) {
            obj = src[4];
            int c0 = q * 20;
#pragma unroll 4
            for (int jj = 0; jj < 20; jj++) {
                float x = src[5 + c0 + jj];
                float mm = __fmul_rn(x, obj);
                float pp = __fsqrt_rn(mm);
                s1 += __logf(__fsub_rn(1.0f, pp));                      // log1p(-p)
                s2 += softplus_bce(x);                                  // cls BCE base
            }
        }
        // left-to-right combine == old red2[0]+red2[1]+red2[2]+red2[3] (bitwise)
        float s1t = __shfl(s1, lb + 0, 64) + __shfl(s1, lb + 1, 64)
                  + __shfl(s1, lb + 2, 64) + __shfl(s1, lb + 3, 64);
        float s2t = __shfl(s2, lb + 0, 64) + __shfl(s2, lb + 1, 64)
                  + __shfl(s2, lb + 2, 64) + __shfl(s2, lb + 3, 64);

        if (valid) {
            int i = base + j;
            if (i < CAP) {
                float nsl = -s1t;
                if (q == 0) {
                    float stv2 = st_[aa];
                    float xc2 = __fmul_rn(__fadd_rn(xs_[aa], 0.5f), stv2);
                    float yc2 = __fmul_rn(__fadd_rn(ys_[aa], 0.5f), stv2);
                    float r2  = __fmul_rn(1.5f, stv2);
                    alist[b * CAP + i] = aa;
                    blist[b * CAP + i] = make_float4(src[0], src[1], src[2], src[3]);
                    glist[b * CAP + i] = make_float4(xc2, yc2, r2, stv2);
                    misc[b * CAP + i]  = make_float2(s2t, obj);
                }
#pragma unroll
                for (int gi = 0; gi < 10; gi++) {
                    int g = q * 10 + gi;                 // same g-partition as old w*10+gi
                    int gc = (int)lgt[g * 5];
                    float mm = __fmul_rn(src[5 + gc], obj);
                    float pp = __fsqrt_rn(mm);
                    float term = __fsub_rn(__fmul_rn(0.5f, __logf(mm)),
                                           __logf(__fsub_rn(1.0f, pp)));
                    clsterm[((size_t)b * GG + g) * CAP + i] = __fsub_rn(nsl, term);
                }
            }
        }
    }
}

// =====================================================================
// K2: SimOTA top-10 assignment — 2 waves per (b,g) pair, deterministic
// 20-candidate rank merge in LDS. Bitwise-identical top-10/isum/dk/commits.
// (unchanged from R5 — passed)
// =====================================================================
__global__ __launch_bounds__(256) void k2_assign(
    const float* __restrict__ labels,
    int* __restrict__ ctrl,
    const int* __restrict__ alist,
    const float4* __restrict__ blist, const float4* __restrict__ glist,
    const float* __restrict__ clsterm,
    int* __restrict__ matchcnt, int2* __restrict__ wl)
{
    __shared__ ull   skey[2][20];
    __shared__ float sval[2][20];

    int w = threadIdx.x >> 6, ln = threadIdx.x & 63;
    int pairLocal = w >> 1;            // 0..1 : two pairs per block
    int half = w & 1;                  // 0..1 : two waves per pair
    int pair = blockIdx.x * 2 + pairLocal;   // < BB*GG = 1280
    int b = pair / GG, g = pair - b * GG;
    int* cnt   = ctrl + 8;
    int* wlcnt = ctrl + 40;

    const float* L = labels + (b * GG + g) * 5;
    float gx = L[1], gy = L[2], gw = L[3], gh = L[4];
    int n = cnt[b]; n = n > CAP ? CAP : n;

    const float*  ctp = clsterm + ((size_t)b * GG + g) * CAP;
    const float4* bp  = blist + b * CAP;
    const float4* gp  = glist + b * CAP;
    const int*    ap  = alist + b * CAP;

    ull t[10]; float tv[10];
#pragma unroll
    for (int k = 0; k < 10; k++) { t[k] = U64MAX; tv[k] = 0.0f; }

    for (int i = ln + half * 64; i < n; i += 128) {
        float4 pb = bp[i];
        float4 gm = gp[i];
        float2 ci = cost_iou(gx, gy, gw, gh, pb.x, pb.y, pb.z, pb.w,
                             gm.x, gm.y, gm.z, ctp[i], 1.0f);
        unsigned u = __float_as_uint(ci.x);
        u ^= (u & 0x80000000u) ? 0xFFFFFFFFu : 0x80000000u;
        ull key = ((ull)u << 32) | (unsigned)((ap[i] << 11) | i);
        if (key < t[9]) {
            int p = 0;
#pragma unroll
            for (int k = 0; k < 10; k++) p += (t[k] < key) ? 1 : 0;
#pragma unroll
            for (int k = 9; k >= 1; k--) t[k] = (k > p) ? t[k - 1] : t[k];
#pragma unroll
            for (int k = 0; k < 10; k++) if (k == p) t[k] = key;
        }
        float v = ci.y;
        if (v > tv[9]) {
            int p = 0;
#pragma unroll
            for (int k = 0; k < 10; k++) p += (tv[k] > v) ? 1 : 0;
#pragma unroll
            for (int k = 9; k >= 1; k--) tv[k] = (k > p) ? tv[k - 1] : tv[k];
#pragma unroll
            for (int k = 0; k < 10; k++) if (k == p) tv[k] = v;
        }
    }

    // per-wave sorted extraction
    ull mykey = U64MAX; float myv = 0.0f;
#pragma unroll
    for (int r = 0; r < 10; r++) {
        ull mn = wave_min_u64(t[0]);
        if (ln == r) mykey = mn;
        bool own = (t[0] == mn);
#pragma unroll
        for (int k = 0; k < 9; k++) t[k] = own ? t[k + 1] : t[k];
        t[9] = own ? U64MAX : t[9];
    }
#pragma unroll
    for (int r = 0; r < 10; r++) {
        float mv = wave_max_f(tv[0]);
        if (ln == r) myv = mv;
        ull bal = __ballot(tv[0] == mv);
        int first = (int)__ffsll((long long)bal) - 1;
        bool own = (ln == first);
#pragma unroll
        for (int k = 0; k < 9; k++) tv[k] = own ? tv[k + 1] : tv[k];
        tv[9] = own ? 0.0f : tv[9];
    }

    if (ln < 10) { skey[pairLocal][half * 10 + ln] = mykey; sval[pairLocal][half * 10 + ln] = myv; }
    __syncthreads();

    // deterministic 20-candidate merge (half 0 commits)
    ull  kc = (ln < 20) ? skey[pairLocal][ln] : U64MAX;
    float vc = (ln < 20) ? sval[pairLocal][ln] : -1.0f;

    int krank = 0, vrank = 0;
#pragma unroll
    for (int j = 0; j < 20; j++) {
        ull kj = (ull)__shfl((long long)kc, j, 64);
        float vj = __shfl(vc, j, 64);
        krank += (kj < kc) ? 1 : 0;                                // keys distinct
        vrank += ((vj > vc) || (vj == vc && j < ln)) ? 1 : 0;      // stable by index
    }

    ull mykey2 = U64MAX;
    float isum = 0.0f;
#pragma unroll
    for (int r = 0; r < 10; r++) {
        ull balk = __ballot(ln < 20 && krank == r);
        int srck = (int)__ffsll((long long)balk) - 1;
        ull kr = (ull)__shfl((long long)kc, srck, 64);
        if (ln == r && srck >= 0) mykey2 = kr;

        ull balv = __ballot(ln < 20 && vrank == r);
        int srcv = (int)__ffsll((long long)balv) - 1;
        float vr = __shfl(vc, srcv, 64);
        isum += (srcv >= 0) ? vr : 0.0f;                           // descending order sum
    }

    int dk = (int)isum;
    dk = dk < 1 ? 1 : (dk > 10 ? 10 : dk);
    if (half == 0 && ln < dk && mykey2 != U64MAX) {
        unsigned low = (unsigned)mykey2;
        int a = (int)(low >> 11);
        int i2 = (int)(low & 2047);
        int idx = b * AA + a;
        if (atomicAdd(&matchcnt[idx], 1) == 0) {
            int wp = atomicAdd(wlcnt, 1);
            if (wp < CAPW) wl[wp] = make_int2(idx, (g << 16) | i2);
        }
    }
}

// =====================================================================
// K4: worklist loss + grid-stride all-anchor obj-BCE (MLP-batched loads,
// same ascending summation order) + ticket finalize. (unchanged from R5)
// =====================================================================
__global__ __launch_bounds__(256) void k4_loss(
    const float* __restrict__ outputs, const float* __restrict__ origin,
    const float* __restrict__ labels,
    const float* __restrict__ xs_, const float* __restrict__ ys_, const float* __restrict__ st_,
    const float4* __restrict__ blist, const float4* __restrict__ glist,
    const float2* __restrict__ misc, const float* __restrict__ clsterm,
    const int* __restrict__ matchcnt,
    const int2* __restrict__ wl, int* __restrict__ ctrl,
    float* __restrict__ out)
{
    float* acc = (float*)ctrl;
    int* wlcnt = ctrl + 40;
    int* fin   = ctrl + 41;

    int tid = threadIdx.x;
    int gid = blockIdx.x * 256 + tid;
    int nw = *wlcnt; nw = nw > CAPW ? CAPW : nw;

    float t_fg = 0.0f, t_iou = 0.0f, t_obj = 0.0f, t_cls = 0.0f, t_l1 = 0.0f;

    {
        const int STR = K4GRID * 256;    // 26624
        float xv[11];
        int kmax = 0;
#pragma unroll
        for (int k = 0; k < 11; k++) {
            int idx = gid + k * STR;
            if (idx < BB * AA) { xv[k] = outputs[(size_t)idx * NO + 4]; kmax = k + 1; }
        }
#pragma unroll
        for (int k = 0; k < 11; k++)
            if (k < kmax) t_obj += softplus_bce(xv[k]);
    }

    if (gid < nw) {
        int2 e = wl[gid];
        int idx = e.x;
        int b = idx / AA;
        int a = idx - b * AA;
        int ci = e.y & 0xFFFF;
        int g1 = e.y >> 16;
        int mcnt = matchcnt[idx];

        float4 pb = blist[b * CAP + ci];
        float4 gm = glist[b * CAP + ci];
        float2 mo = misc[b * CAP + ci];
        const float* Lb = labels + b * GG * 5;

        int mg;
        if (mcnt == 1) {
            mg = g1;
        } else {
            mg = 0; float best = FLT_MAX;
            for (int g = 0; g < GG; g++) {
                float ct = clsterm[((size_t)b * GG + g) * CAP + ci];
                float2 r = cost_iou(Lb[g * 5 + 1], Lb[g * 5 + 2], Lb[g * 5 + 3], Lb[g * 5 + 4],
                                    pb.x, pb.y, pb.z, pb.w, gm.x, gm.y, gm.z, ct, 1.0f);
                if (r.x < best) { best = r.x; mg = g; }
            }
        }
        t_fg = 1.0f;
        t_obj += -mo.y;   // BCE(x,1)-BCE(x,0)
        float gx = Lb[mg * 5 + 1], gy = Lb[mg * 5 + 2], gw = Lb[mg * 5 + 3], gh = Lb[mg * 5 + 4];
        int mcls = (int)Lb[mg * 5];
        float ctm = clsterm[((size_t)b * GG + mg) * CAP + ci];
        float2 r = cost_iou(gx, gy, gw, gh, pb.x, pb.y, pb.z, pb.w, gm.x, gm.y, gm.z, ctm, 1.0f);
        float pred_iou = r.y;
        float tlx = fmaxf(pb.x - pb.z * 0.5f, gx - gw * 0.5f);
        float tly = fmaxf(pb.y - pb.w * 0.5f, gy - gh * 0.5f);
        float brx = fminf(pb.x + pb.z * 0.5f, gx + gw * 0.5f);
        float bry = fminf(pb.y + pb.w * 0.5f, gy + gh * 0.5f);
        float en = (tlx < brx && tly < bry) ? 1.0f : 0.0f;
        float ai = (brx - tlx) * (bry - tly) * en;
        float iou = ai / (pb.z * pb.w + gw * gh - ai + 1e-16f);
        t_iou = 1.0f - iou * iou;
        const float* op = origin + (size_t)idx * 4;
        float stv = st_[a], xsv = xs_[a], ysv = ys_[a];
        t_l1 = fabsf(op[0] - (gx / stv - xsv)) + fabsf(op[1] - (gy / stv - ysv))
             + fabsf(op[2] - logf(gw / stv + 1e-8f)) + fabsf(op[3] - logf(gh / stv + 1e-8f));
        t_cls = mo.x - outputs[(size_t)idx * NO + 5 + mcls] * pred_iou;
    }

    t_fg = wave_sum(t_fg); t_iou = wave_sum(t_iou); t_obj = wave_sum(t_obj);
    t_cls = wave_sum(t_cls); t_l1 = wave_sum(t_l1);
    __shared__ float red[5][4];
    int wv = threadIdx.x >> 6, ln = threadIdx.x & 63;
    if (ln == 0) { red[0][wv] = t_fg; red[1][wv] = t_iou; red[2][wv] = t_obj; red[3][wv] = t_cls; red[4][wv] = t_l1; }
    __syncthreads();
    if (threadIdx.x == 0) {
        atomicAdd(&acc[0], red[0][0] + red[0][1] + red[0][2] + red[0][3]);
        atomicAdd(&acc[1], red[1][0] + red[1][1] + red[1][2] + red[1][3]);
        atomicAdd(&acc[2], red[2][0] + red[2][1] + red[2][2] + red[2][3]);
        atomicAdd(&acc[3], red[3][0] + red[3][1] + red[3][2] + red[3][3]);
        atomicAdd(&acc[4], red[4][0] + red[4][1] + red[4][2] + red[4][3]);
        __threadfence();
        int tkt = atomicAdd(fin, 1);
        if (tkt == (int)gridDim.x - 1) {
            float a0 = atomicAdd(&acc[0], 0.0f);
            float a1 = atomicAdd(&acc[1], 0.0f);
            float a2 = atomicAdd(&acc[2], 0.0f);
            float a3 = atomicAdd(&acc[3], 0.0f);
            float a4 = atomicAdd(&acc[4], 0.0f);
            float nfg = fmaxf(a0, 1.0f);
            float li = 5.0f * a1 / nfg;
            float lo = a2 / nfg;
            float lc = a3 / nfg;
            float ll = a4 / nfg;
            out[0] = li + lo + lc + ll;
            out[1] = li;
            out[2] = lo;
            out[3] = lc;
            out[4] = ll;
            out[5] = nfg / (float)(BB * GG);
        }
    }
}

// ---------- workspace layout (16B-aligned blocks) ----------
static constexpr size_t NBA       = (size_t)BB * AA;                 // 268800
static constexpr size_t OFF_MC    = 512;                             // ctrl first
static constexpr size_t OFF_ALIST = OFF_MC + NBA * 4;
static constexpr size_t OFF_BL    = OFF_ALIST + (size_t)BB * CAP * 4;
static constexpr size_t OFF_GL    = OFF_BL + (size_t)BB * CAP * 16;
static constexpr size_t OFF_MISC  = OFF_GL + (size_t)BB * CAP * 16;
static constexpr size_t OFF_CT    = OFF_MISC + (size_t)BB * CAP * 8;
static constexpr size_t OFF_WL    = OFF_CT + (size_t)BB * GG * CAP * 4;
// total = OFF_WL + CAPW*8 ≈ 15 MB

extern "C" void kernel_launch(void* const* d_in, const int* in_sizes, int n_in,
                              void* d_out, int out_size, void* d_ws, size_t ws_size,
                              hipStream_t stream)
{
    (void)in_sizes; (void)n_in; (void)out_size; (void)ws_size;
    const float* outputs = (const float*)d_in[0];
    const float* origin  = (const float*)d_in[1];
    const float* labels  = (const float*)d_in[2];
    const float* xs_     = (const float*)d_in[3];
    const float* ys_     = (const float*)d_in[4];
    const float* st_     = (const float*)d_in[5];
    float* out = (float*)d_out;
    char* ws = (char*)d_ws;

    int*    ctrl     = (int*)(ws);
    int*    matchcnt = (int*)(ws + OFF_MC);
    int*    alist    = (int*)(ws + OFF_ALIST);
    float4* blist    = (float4*)(ws + OFF_BL);
    float4* glist    = (float4*)(ws + OFF_GL);
    float2* misc     = (float2*)(ws + OFF_MISC);
    float*  clsterm  = (float*)(ws + OFF_CT);
    int2*   wl       = (int2*)(ws + OFF_WL);

    // K1: syncless fg-compaction + class-term kernel
    dim3 grid1((AA + 255) / 256, BB);   // 33 x 32
    k1_fgcls<<<grid1, 256, 0, stream>>>(outputs, labels, xs_, ys_, st_,
                                        ctrl, matchcnt, alist,
                                        blist, glist, misc, clsterm);

    // K2: 2 waves per (b,g) pair -> 640 blocks
    k2_assign<<<BB * GG / 2, 256, 0, stream>>>(labels, ctrl, alist, blist, glist, clsterm,
                                               matchcnt, wl);

    // K4: unchanged partition (K4GRID=104), MLP-batched obj gather
    k4_loss<<<K4GRID, 256, 0, stream>>>(outputs, origin, labels, xs_, ys_, st_,
                                        blist, glist, misc, clsterm, matchcnt, wl,
                                        ctrl, out);
}